// Round 17
// baseline (1518.421 us; speedup 1.0000x reference)
//
#include <hip/hip_runtime.h>

// ============================================================================
// ASTGCN block for MI355X. Dims: B=8, N=2048, FIN=3, T=12, K=3, FC=FT=64.
// bf16 MFMA (16x16x32) for all big GEMMs, fp32 elsewhere.
// GEMM convention: C[m,n] = sum_k A[m,k] * BT[n,k]; A,BT bf16 K-contiguous.
// R4: LDS chunk XOR-swizzle. R10: 3-buffer single-barrier K-loop.
// R11: AF reg-fragment A path. R12: z-fold XCD swizzle for Z=8 P-GEMMs.
// R13: k_h / k_res_ln emit A-fragment layout.  R14: gemm_afb barrier-free
//      LDS-free GEMM (both operands as register fragments).
// R15: occupancy bumps — afb kernels were latency-starved at 2 blocks/CU
//      (Occupancy 18.6%) despite 0 LDS / 92 VGPR. afb -> 4 waves/EU;
//      AF WN1 -> 4; AF WN2 -> 3. No other changes.
// ============================================================================

typedef unsigned short u16;
typedef __bf16 bf16x8 __attribute__((ext_vector_type(8)));
typedef float f32x4 __attribute__((ext_vector_type(4)));
typedef u16 u16x8 __attribute__((ext_vector_type(8)));

__device__ __forceinline__ u16 f2b(float f) {
  union { float f; unsigned u; } v; v.f = f;
  unsigned u = v.u;
  u = u + 0x7FFFu + ((u >> 16) & 1u);   // RNE
  return (u16)(u >> 16);
}
__device__ __forceinline__ float b2f(u16 h) {
  union { unsigned u; float f; } v; v.u = ((unsigned)h) << 16; return v.f;
}
// q(x) = exp(sigmoid(leaky_relu(x, 0.1)))
__device__ __forceinline__ float qfun(float x) {
  float e = x > 0.f ? x : 0.1f * x;
  float s = __builtin_amdgcn_rcpf(1.f + __expf(-e));
  return __expf(s);
}

template <int N> __device__ __forceinline__ void waitvm() {
  if constexpr (N == 0)       asm volatile("s_waitcnt vmcnt(0)" ::: "memory");
  else if constexpr (N == 2)  asm volatile("s_waitcnt vmcnt(2)" ::: "memory");
  else if constexpr (N == 4)  asm volatile("s_waitcnt vmcnt(4)" ::: "memory");
  else if constexpr (N == 6)  asm volatile("s_waitcnt vmcnt(6)" ::: "memory");
  else if constexpr (N == 8)  asm volatile("s_waitcnt vmcnt(8)" ::: "memory");
  else                        asm volatile("s_waitcnt vmcnt(16)" ::: "memory");
}
__device__ __forceinline__ void rawbar() { asm volatile("s_barrier" ::: "memory"); }

#define GLOAD16(g, l) __builtin_amdgcn_global_load_lds( \
    (__attribute__((address_space(1))) void*)(g),       \
    (__attribute__((address_space(3))) void*)(l), 16, 0, 0)

// ---------------------------------------------------------------------------
// Workspace layout (byte offsets). High water: 0x8D40000 (= 148 MB).
// ---------------------------------------------------------------------------
constexpr size_t OFF_LHS     = 0x0;        // f32 [3][3][64]
constexpr size_t OFF_U1U2    = 0x1000;     // f32 [64]
constexpr size_t OFF_BIASBIG = 0x1100;     // f32 [1536]
constexpr size_t OFF_FH      = 0x3000;     // f32 [2][8][2048]
constexpr size_t OFF_GH      = 0x23000;
constexpr size_t OFF_RDH     = 0x43000;
constexpr size_t OFF_FO      = 0x63000;    // f32 [8][2048]
constexpr size_t OFF_GO      = 0x73000;
constexpr size_t OFF_RDO     = 0x83000;
constexpr size_t OFF_LHST    = 0x93000;    // f32 [8][12][2048]
constexpr size_t OFF_RHST    = 0x153000;   // f32 [8][2048][12]
constexpr size_t OFF_PROD    = 0x213000;   // f32 [8][12][12]
constexpr size_t OFF_E       = 0x215000;   // f32 [8][12][12]
constexpr size_t OFF_WCATT   = 0x220000;   // bf16 [768][768] B-FRAG layout
constexpr size_t OFF_WOUTT   = 0x340000;   // bf16 [768][768] K-contiguous
constexpr size_t OFF_WTBIG   = 0x460000;   // bf16 [768][768] tap-expanded, K-contig
constexpr size_t OFF_XCOLT   = 0x580000;   // bf16 [384][2048] (rows 288.. zero)
constexpr size_t OFF_CHEBT   = 0x700000;   // bf16 [3][2048][2048]  -> 0x1F00000
constexpr size_t OFF_C1      = 0x1F00000;  // bf16 [12][2048][384]  -> 0x3100000
constexpr size_t OFF_H       = 0x4300000;  // bf16 frag [1024][24][512] -> 0x5B00000
constexpr size_t OFF_P       = 0x700000;   // bf16 frag [8][128*64][512] -> 0x4700000
constexpr size_t OFF_WHCATT  = 0x5B00000;  // bf16 [8][768][2048]   -> 0x7300000
constexpr size_t OFF_HCAT    = 0x7300000;  // bf16 [16384][768]     -> 0x8B00000
constexpr size_t OFF_WHOUTT  = 0x5B00000;  // reuse (WhcatT dead after G4)
constexpr size_t OFF_GCNB    = 0x7300000;  // bf16 [16384][768] (hcat dead) -> 0x8B00000
constexpr size_t OFF_WBFBIG  = 0x8B00000;  // bf16 [1536][768] B-FRAG layout -> 0x8D40000
constexpr size_t OFF_TCS     = 0x700000;   // bf16 [16384][12][64] (P dead) -> 0x1F00000
constexpr size_t OFF_RESULTB = 0x3700000;  // bf16 frag [1024][24][512] -> 0x4F00000
constexpr size_t WS_NEEDED   = 0x8D40000;

// ---------------------------------------------------------------------------
struct GemmP {
  const u16* A; const u16* BT;
  long sA, sB;            // per-z batch strides (elements)
  int K, lda, ldb;
  int swz, splitK;
  float* Cf; long sCf; int ldcf;
  u16* Cb;  long sCb; int ldcb;
  u16* CbT; int ldcT; long sCbT;
  const float* bias;
  float* outB; float* outF;
};

// ---------------------------------------------------------------------------
// gemm_afb: barrier-free LDS-free GEMM. Block 128x128 (2x2 waves of 64x64).
// Both operands in fragment layout: frag f at base + (tile16*KT + kt)*512 +
// lane*8 (lane = (r&15) + 16*koct). Triple-buffered register sets,
// vmcnt(16)-counted (2 steps in flight).
// EPI: 1 bf16-LDS-transposed   7 final +biasBig -> f32x4 rows
// ---------------------------------------------------------------------------
template <int EPI>
__global__ __launch_bounds__(256, 4) void gemm_afb(GemmP p) {
  __shared__ u16 smem[(EPI == 1) ? 17408 : 16];
  const int tid = threadIdx.x, lane = tid & 63, wid = tid >> 6;
  const int wm = wid >> 1, wn = wid & 1;
  const int z = blockIdx.z;
  int nT = gridDim.x;
  int nwg = nT * gridDim.y;
  int lin = blockIdx.x + nT * blockIdx.y;
  int q8 = nwg >> 3;
  int sw = (lin & 7) * q8 + (lin >> 3);   // XCD-chunked bijection (nwg%8==0)
  long m0 = (long)(sw / nT) * 128;
  long n0 = (long)(sw % nT) * 128;

  const int KT = p.K >> 5;
  const long mstr = (long)KT * 512;
  const u16* aPf = p.A + (long)z * p.sA + ((m0 >> 4) + wm * 4) * mstr + lane * 8;
  const u16* bPf = p.BT + ((n0 >> 4) + wn * 4) * mstr + lane * 8;

  f32x4 acc[4][4];
  f32x4 zero = {0.f, 0.f, 0.f, 0.f};
#pragma unroll
  for (int i = 0; i < 4; ++i)
#pragma unroll
    for (int j = 0; j < 4; ++j) acc[i][j] = zero;

  bf16x8 a0[4], b0[4], a1[4], b1[4], a2[4], b2[4];
  auto LOAD = [&](bf16x8 (&av)[4], bf16x8 (&bv)[4], int s) {
#pragma unroll
    for (int mi = 0; mi < 4; ++mi) av[mi] = *(const bf16x8*)(aPf + mi * mstr + (long)s * 512);
#pragma unroll
    for (int ni = 0; ni < 4; ++ni) bv[ni] = *(const bf16x8*)(bPf + ni * mstr + (long)s * 512);
  };
  auto MM = [&](bf16x8 (&av)[4], bf16x8 (&bv)[4]) {
#pragma unroll
    for (int mi = 0; mi < 4; ++mi)
#pragma unroll
      for (int ni = 0; ni < 4; ++ni)
        acc[mi][ni] = __builtin_amdgcn_mfma_f32_16x16x32_bf16(av[mi], bv[ni], acc[mi][ni], 0, 0, 0);
  };

  LOAD(a0, b0, 0);
  if (KT > 1) LOAD(a1, b1, 1);
  if (KT > 2) LOAD(a2, b2, 2);
  for (int i = 0; i < KT; i += 3) {
    waitvm<16>(); MM(a0, b0);
    if (i + 3 < KT) LOAD(a0, b0, i + 3);
    if (i + 1 < KT) {
      waitvm<16>(); MM(a1, b1);
      if (i + 4 < KT) LOAD(a1, b1, i + 4);
    }
    if (i + 2 < KT) {
      waitvm<16>(); MM(a2, b2);
      if (i + 5 < KT) LOAD(a2, b2, i + 5);
    }
  }

  if constexpr (EPI == 1) {
    // Stage bf16 tile transposed in LDS, coalesced column writes.
    __syncthreads();
#pragma unroll
    for (int mi = 0; mi < 4; ++mi)
#pragma unroll
      for (int ni = 0; ni < 4; ++ni) {
        int cl = wn * 64 + ni * 16 + (lane & 15);
        int mlb = wm * 64 + mi * 16 + ((lane >> 4) << 2);
#pragma unroll
        for (int r = 0; r < 4; ++r)
          smem[cl * 136 + mlb + r] = f2b(acc[mi][ni][r]);
      }
    __syncthreads();
    int c = tid >> 1, half = tid & 1;
    long bat = m0 >> 11;                  // 2048-row batches
    u16* dst = p.CbT + bat * p.sCbT + (long)(n0 + c) * p.ldcT + (m0 & 2047) + half * 64;
    const u16* srcp = &smem[c * 136 + half * 64];
#pragma unroll
    for (int j = 0; j < 64; j += 8)
      *(u16x8*)(dst + j) = *(const u16x8*)(srcp + j);
    return;
  }

  if constexpr (EPI == 7) {
    // In-register 4x4 transpose -> dwordx4 row stores.
    const int q = lane >> 4, g4 = (lane >> 2) & 3, j = lane & 3;
    const int back = ((int)n0 < 768);
    float* obase = (back ? p.outB : p.outF) - (back ? 0 : 768);
#pragma unroll
    for (int mi = 0; mi < 4; ++mi) {
      long rb0 = m0 + wm * 64 + mi * 16 + q * 4;
#pragma unroll
      for (int ni = 0; ni < 4; ++ni) {
        int cb = (int)n0 + wn * 64 + ni * 16 + g4 * 4;
        f32x4 v = acc[mi][ni];
        float bsv = p.bias[cb + j];
        v[0] += bsv; v[1] += bsv; v[2] += bsv; v[3] += bsv;
#pragma unroll
        for (int d = 1; d <= 2; d <<= 1) {
          f32x4 t;
#pragma unroll
          for (int b = 0; b < 4; ++b) t[b] = __shfl_xor(v[b ^ d], d, 64);
#pragma unroll
          for (int b = 0; b < 4; ++b) if ((lane ^ b) & d) v[b] = t[b];
        }
        *(f32x4*)(obase + (rb0 + j) * 768 + cb) = v;
      }
    }
    return;
  }
}

// ---------------------------------------------------------------------------
// Generic MFMA GEMM: 3-buffer single-barrier pipeline; AF mode.
// ---------------------------------------------------------------------------
template <int EPI, int WN, int AF = 0>
__global__ __launch_bounds__(256, (AF ? (WN == 1 ? 4 : 3) : (WN == 1 ? 3 : 2)))
void gemm_bf16(GemmP p) {
  constexpr int BUFU  = AF ? (WN == 1 ? 4096 : 8192) : (WN == 1 ? 8192 : 12288);
  constexpr int SMEMU = 3 * BUFU;
  constexpr int LPWB  = AF ? (WN == 1 ? 2 : 4) : (WN == 1 ? 4 : 6);
  constexpr int WVN   = AF ? (LPWB + 4) : LPWB;
  __shared__ u16 smem[SMEMU];
  const int tid  = threadIdx.x;
  const int lane = tid & 63;
  const int wid  = tid >> 6;
  const int wm = wid >> 1, wn = wid & 1;

  long m0, n0;
  int z = blockIdx.z;
  if (p.swz == 2) {
    int nT = gridDim.x;
    int nwg = nT * gridDim.y;
    long L = (long)blockIdx.z * nwg + blockIdx.x + (long)nT * blockIdx.y;
    z = (int)(L & 7);
    long r = L >> 3;
    m0 = (r / nT) * 128;
    n0 = (r % nT) * (128 * WN);
  } else if (p.swz) {
    int nT = gridDim.x;
    int nwg = nT * gridDim.y;
    int lin = blockIdx.x + nT * blockIdx.y;
    int q = nwg >> 3;
    int swz = (lin & 7) * q + (lin >> 3);
    m0 = (long)(swz / nT) * 128;
    n0 = (long)(swz % nT) * (128 * WN);
  } else {
    m0 = (long)blockIdx.y * 128;
    n0 = (long)blockIdx.x * (128 * WN);
  }

  const int K = p.K;
  long aBase, bBase;
  if (p.splitK) {
    int kz = z >> 2, ch = z & 3;
    aBase = (long)kz * p.sA + (long)ch * 512;
    bBase = (long)ch * 512;
  } else {
    aBase = (long)z * p.sA;
    bBase = (long)z * p.sB;
  }
  const u16* Ab = p.A + aBase + m0 * p.lda;
  const u16* Bb = p.BT + bBase + n0 * p.ldb;

  const int sk = (((lane & 3) ^ ((lane >> 3) & 3))) * 8;
  const u16* aP0 = Ab + (long)(wid * 32 + (lane >> 2)) * p.lda + sk;
  const u16* aP1 = aP0 + (long)16 * p.lda;
  const u16* bP0 = Bb + (long)(wid * 32 * WN + (lane >> 2)) * p.ldb + sk;
  const u16* bP1 = bP0 + (long)16 * p.ldb;
  const u16* bP2 = bP0 + (long)32 * p.ldb;
  const u16* bP3 = bP0 + (long)48 * p.ldb;
  const int aslot = wid * 1024;
  const int bslot = (AF ? 0 : 4096) + wid * (WN == 1 ? 1024 : 2048);

  auto STAGE = [&](int s, int bi) {
    long ko = (long)s * 32;
    u16* base = smem + bi * BUFU;
    if constexpr (!AF) {
      GLOAD16(aP0 + ko, base + aslot);
      GLOAD16(aP1 + ko, base + aslot + 512);
    }
    GLOAD16(bP0 + ko, base + bslot);
    GLOAD16(bP1 + ko, base + bslot + 512);
    if constexpr (WN == 2) {
      GLOAD16(bP2 + ko, base + bslot + 1024);
      GLOAD16(bP3 + ko, base + bslot + 1536);
    }
  };

  f32x4 acc[4][4 * WN];
  f32x4 zero = {0.f, 0.f, 0.f, 0.f};
#pragma unroll
  for (int i = 0; i < 4; ++i)
#pragma unroll
    for (int j = 0; j < 4 * WN; ++j) acc[i][j] = zero;

  const int xorc = (lane >> 1) & 3;
  const int aoff = (wm * 64 + (lane & 15)) * 32 + ((lane >> 4) ^ xorc) * 8;
  const int boff = (AF ? 0 : 4096) + (wn * 64 * WN + (lane & 15)) * 32 + ((lane >> 4) ^ xorc) * 8;

  const int nsteps = K >> 5;
  int cur = 0;

  if constexpr (AF) {
    const long kt512 = (long)(K >> 5) * 512;
    const u16* aPf = p.A + (long)z * p.sA + ((m0 >> 4) + wm * 4) * kt512 + lane * 8;
    bf16x8 avA[4], avB[4];
#pragma unroll
    for (int mi = 0; mi < 4; ++mi) avA[mi] = *(const bf16x8*)(aPf + mi * kt512);
    STAGE(0, 0);
#pragma unroll
    for (int mi = 0; mi < 4; ++mi) avB[mi] = *(const bf16x8*)(aPf + mi * kt512 + 512);
    STAGE(1, 1);
    waitvm<WVN>();
    rawbar();

    auto STEPAF = [&](int i, bf16x8 (&av)[4]) {
      const u16* buf = smem + cur * BUFU;
      bf16x8 bv[4 * WN];
#pragma unroll
      for (int ni = 0; ni < 4 * WN; ++ni) bv[ni] = *(const bf16x8*)&buf[boff + ni * 512];
#pragma unroll
      for (int mi = 0; mi < 4; ++mi)
#pragma unroll
        for (int ni = 0; ni < 4 * WN; ++ni)
          acc[mi][ni] = __builtin_amdgcn_mfma_f32_16x16x32_bf16(av[mi], bv[ni], acc[mi][ni], 0, 0, 0);
      if (i + 1 < nsteps) {
        if (i + 2 < nsteps) {
          STAGE(i + 2, cur == 0 ? 2 : cur - 1);
#pragma unroll
          for (int mi = 0; mi < 4; ++mi)
            av[mi] = *(const bf16x8*)(aPf + mi * kt512 + (long)(i + 2) * 512);
          waitvm<WVN>();
        } else {
          waitvm<0>();
        }
        rawbar();
      }
      cur = (cur == 2) ? 0 : cur + 1;
    };
    for (int i = 0; i < nsteps; i += 2) {
      STEPAF(i, avA);
      if (i + 1 < nsteps) STEPAF(i + 1, avB);
    }
  } else {
    STAGE(0, 0);
    STAGE(1, 1);
    waitvm<WVN>();
    rawbar();
    for (int i = 0; i < nsteps; ++i) {
      const u16* buf = smem + cur * BUFU;
      bf16x8 av[4], bv[4 * WN];
#pragma unroll
      for (int mi = 0; mi < 4; ++mi) av[mi] = *(const bf16x8*)&buf[aoff + mi * 512];
#pragma unroll
      for (int ni = 0; ni < 4 * WN; ++ni) bv[ni] = *(const bf16x8*)&buf[boff + ni * 512];
#pragma unroll
      for (int mi = 0; mi < 4; ++mi)
#pragma unroll
        for (int ni = 0; ni < 4 * WN; ++ni)
          acc[mi][ni] = __builtin_amdgcn_mfma_f32_16x16x32_bf16(av[mi], bv[ni], acc[mi][ni], 0, 0, 0);
      if (i + 1 < nsteps) {
        if (i + 2 < nsteps) {
          STAGE(i + 2, cur == 0 ? 2 : cur - 1);
          waitvm<WVN>();
        } else {
          waitvm<0>();
        }
        rawbar();
      }
      cur = (cur == 2) ? 0 : cur + 1;
    }
  }
  __syncthreads();

  if constexpr (EPI == 1) {
#pragma unroll
    for (int h = 0; h < 2; ++h) {
      if (h == 1) __syncthreads();
      if (WN == 1 || wn == h) {
#pragma unroll
        for (int mi = 0; mi < 4; ++mi)
#pragma unroll
          for (int ni = 0; ni < 4 * WN; ++ni) {
            int cl = (WN == 1 ? wn * 64 : 0) + ni * 16 + (lane & 15);
            int mlb = wm * 64 + mi * 16 + ((lane >> 4) << 2);
#pragma unroll
            for (int r = 0; r < 4; ++r)
              smem[cl * 136 + mlb + r] = f2b(acc[mi][ni][r]);
          }
      }
      __syncthreads();
      int c = tid >> 1, half = tid & 1;
      long bat = m0 >> 11;
      u16* dst = p.CbT + bat * p.sCbT + (long)(n0 + h * 128 + c) * p.ldcT +
                 (m0 & 2047) + half * 64;
      const u16* srcp = &smem[c * 136 + half * 64];
#pragma unroll
      for (int j = 0; j < 64; j += 8)
        *(u16x8*)(dst + j) = *(const u16x8*)(srcp + j);
      if (WN == 1) break;
    }
    return;
  }

#pragma unroll
  for (int mi = 0; mi < 4; ++mi) {
    long rb0 = m0 + wm * 64 + mi * 16 + ((lane >> 4) << 2);
#pragma unroll
    for (int ni = 0; ni < 4 * WN; ++ni) {
      int col = (int)n0 + wn * 64 * WN + ni * 16 + (lane & 15);
#pragma unroll
      for (int r = 0; r < 4; ++r) {
        float v = acc[mi][ni][r];
        long row = rb0 + r;
        if constexpr (EPI == 2) {
          float e = v > 0.f ? v : expm1f(v);
          p.Cb[(long)z * p.sCb + row * p.ldcb + col] = f2b(e);
        } else if constexpr (EPI == 6) {
          p.Cb[row * 768 + col] = f2b(v + p.bias[col & 63]);
        } else if constexpr (EPI == 9) {
          p.Cb[(long)z * p.sCb + row * p.ldcb + col] = f2b(v);
        } else {  // EPI == 8
          p.Cb[(long)z * p.sCb + row * p.ldcb + col] = f2b(fmaxf(v, 0.f));
        }
      }
    }
  }
}

// ---------------------------------------------------------------------------
// Small kernels
// ---------------------------------------------------------------------------
__global__ void k_prep(const float* Gamma, const float* U1, const float* U2,
                       const float* back_b, const float* fore_b,
                       float* lhs, float* u1u2, float* biasBig) {
  int o = threadIdx.x;
  if (o < 64) {
    const float cx[3][3] = {{1.f, 0.86602540378443871f, 0.5f},
                            {1.f, 6.123233995736766e-17f, -1.f},
                            {1.f, -0.86602540378443871f, 0.5f}};
    for (int k = 0; k < 3; ++k)
      for (int i = 0; i < 3; ++i) {
        float s = 0;
        for (int j = 0; j < 3; ++j) s += Gamma[(j * 3 + i) * 64 + o] * cx[j][k];
        lhs[(k * 3 + i) * 64 + o] = s;
      }
    float s = 0;
    for (int g = 0; g < 64; ++g) s += U1[o * 64 + g] * U2[g];
    u1u2[o] = s;
    for (int t = 0; t < 12; ++t) {
      biasBig[o * 12 + t] = back_b[o];
      biasBig[768 + o * 12 + t] = fore_b[o];
    }
  }
}

__global__ void k_convert(const float* W_heads, const float* W_out, const float* time_w,
                          const float* back_w, const float* fore_w, const float* xg,
                          u16* WcatT, u16* WoutT, u16* WtBig, u16* WbfBig, u16* xcolT) {
  const int N1 = 589824, NT = 589824, NBF = 1179648, N5 = 786432;
  const int TOT = 2 * N1 + NT + NBF + N5;
  for (int o = blockIdx.x * 256 + threadIdx.x; o < TOT; o += gridDim.x * 256) {
    if (o < N1) {
      // WcatT in B-FRAG layout: frag f = nf*24+kt, slot ln*8+j.
      int f = o >> 9, s = o & 511;
      int ln = s >> 3, j = s & 7;
      int nf = f / 24, kt = f % 24;
      int dcol = nf * 16 + (ln & 15);
      int kk = kt * 32 + (ln >> 4) * 8 + j;
      int hd = dcol / 384, d = dcol % 384;
      WcatT[o] = f2b(W_heads[((long)hd * 768 + kk) * 384 + d]);
    } else if (o < 2 * N1) {
      int o2 = o - N1; int dcol = o2 / 768, kk = o2 % 768;
      WoutT[o2] = f2b(W_out[kk * 768 + dcol]);
    } else if (o < 2 * N1 + NT) {
      // WtBig[t*64+ft][fc*12+tau] K-contiguous (tap-expanded)
      int o3 = o - 2 * N1; int col = o3 / 768, kk = o3 % 768;
      int t = col >> 6, ft = col & 63, fc = kk / 12, tau = kk % 12;
      int r = tau - t + 1;
      WtBig[o3] = f2b((r >= 0 && r < 3) ? time_w[ft * 192 + fc * 3 + r] : 0.f);
    } else if (o < 2 * N1 + NT + NBF) {
      // WbfBig in B-FRAG layout (1536 cols, 96 nf tiles, 24 kt)
      int o4 = o - 2 * N1 - NT;
      int f = o4 >> 9, s = o4 & 511;
      int ln = s >> 3, j = s & 7;
      int nf = f / 24, kt = f % 24;
      int col = nf * 16 + (ln & 15);
      int kk = kt * 32 + (ln >> 4) * 8 + j;
      int rem = (col < 768) ? col : col - 768;
      int c = rem / 12, tt = rem % 12;
      int fc = kk / 12, tau = kk % 12; int r = tau - tt + 1;
      const float* wsrc = (col < 768) ? back_w : fore_w;
      WbfBig[o4] = f2b((r >= 0 && r < 3) ? wsrc[c * 192 + fc * 3 + r] : 0.f);
    } else {
      int o5 = o - 2 * N1 - NT - NBF; int c = o5 / 2048, n = o5 % 2048;
      float v = 0.f;
      if (c < 288) {
        int b = c / 36, r2 = c % 36, i = r2 / 12, t = r2 % 12;
        v = xg[(long)(b * 2048 + n) * 36 + i * 12 + t];
      }
      xcolT[o5] = f2b(v);
    }
  }
}

// chebT[k][m][n] = bf16(cheb[k][n][m])
__global__ void k_chebT(const float* cheb, u16* chebT) {
  __shared__ float ts[32][33];
  int n0 = blockIdx.x * 32, m0 = blockIdx.y * 32, k = blockIdx.z;
  int c = threadIdx.x & 31, rq = threadIdx.x >> 5;
  const long base = (long)k * 2048 * 2048;
  for (int q = 0; q < 4; ++q) {
    int n = n0 + rq + q * 8;
    ts[rq + q * 8][c] = cheb[base + (long)n * 2048 + m0 + c];
  }
  __syncthreads();
  for (int q = 0; q < 4; ++q) {
    int m = m0 + rq + q * 8;
    chebT[base + (long)m * 2048 + n0 + c] = f2b(ts[c][rq + q * 8]);
  }
}

// h -> A-fragment layout. Block = 16 rows (mf = blockIdx.x, 1024 blocks).
__global__ __launch_bounds__(256) void k_h(const u16* C1, const float* lhs, u16* h) {
  int mf = blockIdx.x;
  int tid = threadIdx.x;
  __shared__ float c1s[16][108];
  __shared__ float ls[576];
  __shared__ u16 outb[12288];
  int b = (mf * 16) >> 11;
  for (int s = tid; s < 1728; s += 256) {
    int row = s / 108, rr = s % 108;
    int kk = rr / 12, t = rr % 12; int k = kk / 3, i = kk % 3;
    int n = (mf * 16 + row) & 2047;
    float acc = 0;
#pragma unroll
    for (int ch = 0; ch < 4; ++ch)
      acc += b2f(C1[((long)(k * 4 + ch) * 2048 + n) * 384 + b * 36 + i * 12 + t]);
    c1s[row][rr] = acc;
  }
  for (int s = tid; s < 576; s += 256) ls[s] = lhs[s];
  __syncthreads();
  for (int row = 0; row < 16; ++row) {
#pragma unroll
    for (int j = 0; j < 3; ++j) {
      int e = j * 256 + tid; int o = e / 12, t = e % 12;
      float s = 0;
#pragma unroll
      for (int kk = 0; kk < 9; ++kk) s += c1s[row][kk * 12 + t] * ls[kk * 64 + o];
      s *= 0.5f;
      outb[row * 768 + e] = f2b(s < 0.f ? 0.f : s);
    }
  }
  __syncthreads();
  for (int q = 0; q < 6; ++q) {
    int idx = q * 256 + tid;
    int kt = idx >> 6, lane = idx & 63;
    int m = lane & 15, koct = lane >> 4;
    *(u16x8*)(h + ((long)mf * 24 + kt) * 512 + lane * 8) =
        *(const u16x8*)&outb[m * 768 + kt * 32 + koct * 8];
  }
}

// f,g from WhT[b][dOff+d][i], a-slices
__global__ __launch_bounds__(256) void k_fg(const u16* WhT, int dOff, int Dlen,
                                            const float* aF, const float* aG,
                                            float* fOut, float* gOut) {
  int b = blockIdx.y;
  int i = blockIdx.x * 256 + threadIdx.x;
  __shared__ float af[768], ag[768];
  for (int s = threadIdx.x; s < Dlen; s += 256) { af[s] = aF[s]; ag[s] = aG[s]; }
  __syncthreads();
  const u16* wp = WhT + ((long)b * 768 + dOff) * 2048 + i;
  float fs = 0, gs = 0;
  for (int d = 0; d < Dlen; ++d) {
    float w = b2f(wp[(long)d * 2048]);
    fs += w * af[d]; gs += w * ag[d];
  }
  fOut[b * 2048 + i] = fs;
  gOut[b * 2048 + i] = gs;
}

// rdenom[b][j] = 1 / sum_i q(f_i + g_j)
__global__ __launch_bounds__(256) void k_denom(const float* f, const float* g, float* rd) {
  int b = blockIdx.y;
  int jl = threadIdx.x & 63, ch = threadIdx.x >> 6;
  int j = blockIdx.x * 64 + jl;
  __shared__ float fl[2048];
  __shared__ float red[256];
  for (int s = threadIdx.x; s < 2048; s += 256) fl[s] = f[b * 2048 + s];
  __syncthreads();
  float gj = g[b * 2048 + j];
  float acc = 0;
  for (int i = ch * 512; i < ch * 512 + 512; ++i) acc += qfun(fl[i] + gj);
  red[threadIdx.x] = acc;
  __syncthreads();
  if (ch == 0) {
    float s = red[jl] + red[jl + 64] + red[jl + 128] + red[jl + 192];
    rd[b * 2048 + j] = 1.f / s;
  }
}

// P' fragment layout writer
__global__ __launch_bounds__(256) void k_Pfrag(const float* f, const float* g,
                                               const float* rd, u16* P) {
  int z = blockIdx.z, mt = blockIdx.y;
  int wid = threadIdx.x >> 6, lane = threadIdx.x & 63;
  int kt = blockIdx.x * 4 + wid;
  const float* fb = f + z * 2048;
  const float* gb = g + z * 2048;
  const float* rb = rd + z * 2048;
  float fv = fb[mt * 16 + (lane & 15)];
  int k0 = kt * 32 + (lane >> 4) * 8;
  float4 g0 = *(const float4*)(gb + k0);
  float4 g1 = *(const float4*)(gb + k0 + 4);
  float4 r0 = *(const float4*)(rb + k0);
  float4 r1 = *(const float4*)(rb + k0 + 4);
  u16x8 o;
  o[0] = f2b(qfun(fv + g0.x) * r0.x);
  o[1] = f2b(qfun(fv + g0.y) * r0.y);
  o[2] = f2b(qfun(fv + g0.z) * r0.z);
  o[3] = f2b(qfun(fv + g0.w) * r0.w);
  o[4] = f2b(qfun(fv + g1.x) * r1.x);
  o[5] = f2b(qfun(fv + g1.y) * r1.y);
  o[6] = f2b(qfun(fv + g1.z) * r1.z);
  o[7] = f2b(qfun(fv + g1.w) * r1.w);
  *(u16x8*)(P + (long)z * 4194304 + ((long)(mt * 64 + kt)) * 512 + lane * 8) = o;
}

// lhs_t[b][t][n], rhs_t[b][n][t] from tc_s[bn][t][f] (bf16)
__global__ void k_temporal(const u16* tc, const float* u1u2, const float* U3g,
                           float* lhs_t, float* rhs_t) {
  __shared__ float uu[64], u3[64];
  int tid = threadIdx.x;
  if (tid < 64) { uu[tid] = u1u2[tid]; u3[tid] = U3g[tid]; }
  __syncthreads();
  int gid = blockIdx.x * 256 + tid;  // < 196608
  const u16* p = tc + (long)gid * 64;
  float s1 = 0, s2 = 0;
#pragma unroll
  for (int c = 0; c < 8; ++c) {
    u16x8 vv = *(const u16x8*)(p + c * 8);
#pragma unroll
    for (int j = 0; j < 8; ++j) {
      float v = b2f(vv[j]);
      s1 += v * uu[c * 8 + j]; s2 += v * u3[c * 8 + j];
    }
  }
  int t = gid % 12; long bn = gid / 12;
  int b = (int)(bn >> 11);
  lhs_t[((long)b * 12 + t) * 2048 + (int)(bn & 2047)] = s1;
  rhs_t[gid] = s2;
}

__global__ void k_prod(const float* lhs_t, const float* rhs_t, float* prod) {
  int bi = blockIdx.x;  // < 1152
  int b = bi / 144; int r = bi % 144; int s = r / 12; int u = r % 12;
  int tid = threadIdx.x;
  float acc = 0;
  const float* lp = lhs_t + ((long)b * 12 + s) * 2048;
  const float* rp = rhs_t + (long)b * 2048 * 12 + u;
  for (int n = tid; n < 2048; n += 256) acc += lp[n] * rp[n * 12];
  __shared__ float red[256];
  red[tid] = acc; __syncthreads();
  for (int st = 128; st > 0; st >>= 1) {
    if (tid < st) red[tid] += red[tid + st];
    __syncthreads();
  }
  if (tid == 0) prod[bi] = red[0];
}

__global__ void k_E(const float* prod, const float* be, const float* Ve, float* E) {
  int b = blockIdx.x; int tid = threadIdx.x;
  __shared__ float S0[144], E1[144], mx[12], dn[12];
  if (tid < 144) {
    float v = prod[b * 144 + tid] + be[tid];
    S0[tid] = 1.f / (1.f + __expf(-v));
  }
  __syncthreads();
  if (tid < 144) {
    int i = tid / 12, t = tid % 12;
    float a = 0;
    for (int s = 0; s < 12; ++s) a += Ve[i * 12 + s] * S0[s * 12 + t];
    E1[tid] = a;
  }
  __syncthreads();
  if (tid < 12) {
    float m = -1e30f;
    for (int i = 0; i < 12; ++i) m = fmaxf(m, E1[i * 12 + tid]);
    float d = 0;
    for (int i = 0; i < 12; ++i) d += __expf(E1[i * 12 + tid] - m);
    mx[tid] = m; dn[tid] = d;
  }
  __syncthreads();
  if (tid < 144) {
    int t = tid % 12;
    E[b * 144 + tid] = __expf(E1[tid] - mx[t]) / dn[t];
  }
}

// tcn + residual + relu + layernorm(channel) -> resultB in A-fragment layout.
__global__ __launch_bounds__(256) void k_res_ln(const u16* tc, const float* E,
                                                const float* xg, const float* res_w,
                                                const float* res_b, const float* ln_g,
                                                const float* ln_b, u16* result) {
  int mf = blockIdx.x; int tid = threadIdx.x;
  int b = (mf * 16) >> 11;
  __shared__ float Eb[144], rw[192], rb[64], lg[64], lb[64];
  __shared__ float tcb[768], zl[768], xl[36], mu[12], rs[12];
  __shared__ u16 outb[12288];
  if (tid < 144) Eb[tid] = E[b * 144 + tid];
  if (tid < 192) rw[tid] = res_w[tid];
  if (tid < 64) { rb[tid] = res_b[tid]; lg[tid] = ln_g[tid]; lb[tid] = ln_b[tid]; }
  for (int r = 0; r < 16; ++r) {
    long bn = (long)mf * 16 + r;
    __syncthreads();
    for (int s = tid; s < 768; s += 256) tcb[s] = b2f(tc[bn * 768 + s]);
    if (tid < 36) xl[tid] = xg[bn * 36 + tid];
    __syncthreads();
    float z[3];
#pragma unroll
    for (int q = 0; q < 3; ++q) {
      int idx = tid + q * 256; int f = idx / 12, s = idx % 12;
      float tcn = 0;
#pragma unroll
      for (int t = 0; t < 12; ++t) tcn += tcb[t * 64 + f] * Eb[t * 12 + s];
      float xr = rb[f];
#pragma unroll
      for (int i = 0; i < 3; ++i) xr += rw[f * 3 + i] * xl[i * 12 + s];
      float v = xr + tcn;
      v = v > 0.f ? v : 0.f;
      z[q] = v; zl[idx] = v;
    }
    __syncthreads();
    if (tid < 12) {
      float m = 0, m2 = 0;
      for (int f = 0; f < 64; ++f) { float v = zl[f * 12 + tid]; m += v; m2 += v * v; }
      m *= (1.f / 64.f); m2 *= (1.f / 64.f);
      mu[tid] = m;
      float var = m2 - m * m;
      rs[tid] = rsqrtf((var > 0.f ? var : 0.f) + 1e-5f);
    }
    __syncthreads();
#pragma unroll
    for (int q = 0; q < 3; ++q) {
      int idx = tid + q * 256; int f = idx / 12, s = idx % 12;
      outb[r * 768 + idx] = f2b((z[q] - mu[s]) * rs[s] * lg[f] + lb[f]);
    }
  }
  __syncthreads();
  for (int q = 0; q < 6; ++q) {
    int idx = q * 256 + tid;
    int kt = idx >> 6, lane = idx & 63;
    int m = lane & 15, koct = lane >> 4;
    *(u16x8*)(result + ((long)mf * 24 + kt) * 512 + lane * 8) =
        *(const u16x8*)&outb[m * 768 + kt * 32 + koct * 8];
  }
}

__global__ void k_sentinel(float* out, long n) {
  long i = (long)blockIdx.x * 256 + threadIdx.x;
  if (i < n) out[i] = 12345.0f;
}

// ---------------------------------------------------------------------------
// Launcher
// ---------------------------------------------------------------------------
extern "C" void kernel_launch(void* const* d_in, const int* in_sizes, int n_in,
                              void* d_out, int out_size, void* d_ws, size_t ws_size,
                              hipStream_t stream) {
  (void)in_sizes; (void)n_in;
  const float* x       = (const float*)d_in[0];
  const float* cheb    = (const float*)d_in[1];
  const float* Gamma   = (const float*)d_in[2];
  const float* W_heads = (const float*)d_in[3];
  const float* a_heads = (const float*)d_in[4];
  const float* W_out   = (const float*)d_in[5];
  const float* a_out   = (const float*)d_in[6];
  const float* U1      = (const float*)d_in[7];
  const float* U2      = (const float*)d_in[8];
  const float* U3      = (const float*)d_in[9];
  const float* be      = (const float*)d_in[10];
  const float* Ve      = (const float*)d_in[11];
  const float* time_w  = (const float*)d_in[12];
  const float* time_b  = (const float*)d_in[13];
  const float* res_w   = (const float*)d_in[14];
  const float* res_b   = (const float*)d_in[15];
  const float* back_w  = (const float*)d_in[16];
  const float* back_b  = (const float*)d_in[17];
  const float* fore_w  = (const float*)d_in[18];
  const float* fore_b  = (const float*)d_in[19];
  const float* ln_g    = (const float*)d_in[20];
  const float* ln_b    = (const float*)d_in[21];
  float* out = (float*)d_out;

  if (ws_size < WS_NEEDED) {
    k_sentinel<<<(out_size + 255) / 256, 256, 0, stream>>>(out, out_size);
    return;
  }

  char* ws = (char*)d_ws;
  float* lhs     = (float*)(ws + OFF_LHS);
  float* u1u2    = (float*)(ws + OFF_U1U2);
  float* biasBig = (float*)(ws + OFF_BIASBIG);
  float* fH      = (float*)(ws + OFF_FH);
  float* gH      = (float*)(ws + OFF_GH);
  float* rdH     = (float*)(ws + OFF_RDH);
  float* fO      = (float*)(ws + OFF_FO);
  float* gO      = (float*)(ws + OFF_GO);
  float* rdO     = (float*)(ws + OFF_RDO);
  float* lhs_t   = (float*)(ws + OFF_LHST);
  float* rhs_t   = (float*)(ws + OFF_RHST);
  float* prod    = (float*)(ws + OFF_PROD);
  float* Ebuf    = (float*)(ws + OFF_E);
  u16* WcatT   = (u16*)(ws + OFF_WCATT);
  u16* WoutT   = (u16*)(ws + OFF_WOUTT);
  u16* WtBig   = (u16*)(ws + OFF_WTBIG);
  u16* WbfBig  = (u16*)(ws + OFF_WBFBIG);
  u16* xcolT   = (u16*)(ws + OFF_XCOLT);
  u16* chebT   = (u16*)(ws + OFF_CHEBT);
  u16* C1      = (u16*)(ws + OFF_C1);
  u16* hbuf    = (u16*)(ws + OFF_H);
  u16* Pbuf    = (u16*)(ws + OFF_P);
  u16* WhcatT  = (u16*)(ws + OFF_WHCATT);
  u16* hcat    = (u16*)(ws + OFF_HCAT);
  u16* WhoutT  = (u16*)(ws + OFF_WHOUTT);
  u16* gcnB    = (u16*)(ws + OFF_GCNB);
  u16* tcsB    = (u16*)(ws + OFF_TCS);
  u16* resultB = (u16*)(ws + OFF_RESULTB);

  // --- prep ---
  k_prep<<<1, 64, 0, stream>>>(Gamma, U1, U2, back_b, fore_b, lhs, u1u2, biasBig);
  k_convert<<<2048, 256, 0, stream>>>(W_heads, W_out, time_w, back_w, fore_w, x,
                                      WcatT, WoutT, WtBig, WbfBig, xcolT);
  k_chebT<<<dim3(64, 64, 3), 256, 0, stream>>>(cheb, chebT);

  // --- G1: C1 partials (bf16) = chebT @ xcolT^T, split-K x4 ---
  {
    GemmP p{}; p.A = chebT; p.BT = xcolT; p.sA = 2048L * 2048; p.sB = 0;
    p.K = 512; p.lda = 2048; p.ldb = 2048; p.splitK = 1; p.swz = 1;
    p.Cb = C1; p.sCb = 2048L * 384; p.ldcb = 384;
    gemm_bf16<9, 1><<<dim3(3, 16, 12), 256, 0, stream>>>(p);
  }
  k_h<<<1024, 256, 0, stream>>>(C1, lhs, hbuf);

  // --- G2: Wh_cat (AFB: frag A x frag B, barrier-free; transposed out) ---
  {
    GemmP p{}; p.A = hbuf; p.BT = WcatT; p.sA = 0; p.K = 768;
    p.CbT = WhcatT; p.ldcT = 2048; p.sCbT = 768L * 2048;
    gemm_afb<1><<<dim3(6, 128, 1), 256, 0, stream>>>(p);
  }
  // f,g per head
  k_fg<<<dim3(8, 8), 256, 0, stream>>>(WhcatT, 0, 384, a_heads, a_heads + 384, fH, gH);
  k_fg<<<dim3(8, 8), 256, 0, stream>>>(WhcatT, 384, 384, a_heads + 768, a_heads + 1152,
                                       fH + 16384, gH + 16384);
  // heads: denom, P' frags, att GEMM (A-frag reg path, z-fold swizzle)
  for (int hd = 0; hd < 2; ++hd) {
    const float* f = fH + hd * 16384; const float* g = gH + hd * 16384;
    float* rd = rdH + hd * 16384;
    k_denom<<<dim3(32, 8), 256, 0, stream>>>(f, g, rd);
    k_Pfrag<<<dim3(16, 128, 8), 256, 0, stream>>>(f, g, rd, Pbuf);
    GemmP p{}; p.A = Pbuf; p.BT = WhcatT + (long)hd * 384 * 2048;
    p.sA = 2048L * 2048; p.sB = 768L * 2048;
    p.K = 2048; p.lda = 2048; p.ldb = 2048; p.swz = 2;
    p.Cb = hcat + hd * 384; p.sCb = 2048L * 768; p.ldcb = 768;
    gemm_bf16<2, 1, 1><<<dim3(3, 16, 8), 256, 0, stream>>>(p);
  }

  // --- G5: Wh_out (LDS-transposed out, non-AF) ---
  {
    GemmP p{}; p.A = hcat; p.BT = WoutT; p.sA = 0; p.sB = 0;
    p.K = 768; p.lda = 768; p.ldb = 768; p.swz = 1;
    p.CbT = WhoutT; p.ldcT = 2048; p.sCbT = 768L * 2048;
    gemm_bf16<1, 2><<<dim3(3, 128, 1), 256, 0, stream>>>(p);
  }
  k_fg<<<dim3(8, 8), 256, 0, stream>>>(WhoutT, 0, 768, a_out, a_out + 768, fO, gO);
  k_denom<<<dim3(32, 8), 256, 0, stream>>>(fO, gO, rdO);
  k_Pfrag<<<dim3(16, 128, 8), 256, 0, stream>>>(fO, gO, rdO, Pbuf);
  // --- G6: out attention (A-frag reg path, z-fold), relu -> gcnB ---
  {
    GemmP p{}; p.A = Pbuf; p.BT = WhoutT; p.sA = 2048L * 2048; p.sB = 768L * 2048;
    p.K = 2048; p.lda = 2048; p.ldb = 2048; p.swz = 2;
    p.Cb = gcnB; p.sCb = 2048L * 768; p.ldcb = 768;
    gemm_bf16<8, 2, 1><<<dim3(3, 16, 8), 256, 0, stream>>>(p);
  }

  // --- temporal conv as dense GEMM (tap-expanded weights) -> tcsB bf16 ---
  {
    GemmP p{}; p.A = gcnB; p.BT = WtBig; p.sA = 0; p.sB = 0;
    p.K = 768; p.lda = 768; p.ldb = 768; p.swz = 1;
    p.Cb = tcsB; p.bias = time_b;
    gemm_bf16<6, 2><<<dim3(3, 128, 1), 256, 0, stream>>>(p);
  }

  // --- temporal attention ---
  k_temporal<<<768, 256, 0, stream>>>(tcsB, u1u2, U3, lhs_t, rhs_t);
  k_prod<<<1152, 256, 0, stream>>>(lhs_t, rhs_t, prod);
  k_E<<<8, 256, 0, stream>>>(prod, be, Ve, Ebuf);

  // --- residual + LN -> resultB fragments ---
  k_res_ln<<<1024, 256, 0, stream>>>(tcsB, Ebuf, x, res_w, res_b, ln_g, ln_b, resultB);

  // --- backcast / forecast convs: AFB barrier-free GEMM, coalesced writes ---
  {
    GemmP p{}; p.A = resultB; p.BT = WbfBig; p.sA = 0; p.K = 768;
    p.bias = biasBig; p.outB = out; p.outF = out + 12582912L;
    gemm_afb<7><<<dim3(12, 128, 1), 256, 0, stream>>>(p);
  }
}

// Round 18
// 703.385 us; speedup vs baseline: 2.1587x; 2.1587x over previous
//
#include <hip/hip_runtime.h>

// ============================================================================
// ASTGCN block for MI355X. Dims: B=8, N=2048, FIN=3, T=12, K=3, FC=FT=64.
// bf16 MFMA (16x16x32) for all big GEMMs, fp32 elsewhere.
// GEMM convention: C[m,n] = sum_k A[m,k] * BT[n,k]; A,BT bf16 K-contiguous.
// R4: LDS chunk XOR-swizzle. R7: WN template, bf16 C1, EPI7 reg-transpose.
// R10: 3-buffer single-barrier depth-2 K-loop (integer buffer index).
// R16: REVERT to the R10 configuration (best measured, 698 us). Subsequent
//      branches (AF frags R11, z-fold R12, frag producers R13, barrier-free
//      afb R14, occupancy bump R15 -> VGPR-64 scratch spill) all netted <= 0.
// ============================================================================

typedef unsigned short u16;
typedef __bf16 bf16x8 __attribute__((ext_vector_type(8)));
typedef float f32x4 __attribute__((ext_vector_type(4)));
typedef u16 u16x8 __attribute__((ext_vector_type(8)));

__device__ __forceinline__ u16 f2b(float f) {
  union { float f; unsigned u; } v; v.f = f;
  unsigned u = v.u;
  u = u + 0x7FFFu + ((u >> 16) & 1u);   // RNE
  return (u16)(u >> 16);
}
__device__ __forceinline__ float b2f(u16 h) {
  union { unsigned u; float f; } v; v.u = ((unsigned)h) << 16; return v.f;
}
// q(x) = exp(sigmoid(leaky_relu(x, 0.1)))
__device__ __forceinline__ float qfun(float x) {
  float e = x > 0.f ? x : 0.1f * x;
  float s = __builtin_amdgcn_rcpf(1.f + __expf(-e));
  return __expf(s);
}

template <int N> __device__ __forceinline__ void waitvm() {
  if constexpr (N == 0)      asm volatile("s_waitcnt vmcnt(0)" ::: "memory");
  else if constexpr (N == 4) asm volatile("s_waitcnt vmcnt(4)" ::: "memory");
  else                       asm volatile("s_waitcnt vmcnt(6)" ::: "memory");
}
__device__ __forceinline__ void rawbar() { asm volatile("s_barrier" ::: "memory"); }

#define GLOAD16(g, l) __builtin_amdgcn_global_load_lds( \
    (__attribute__((address_space(1))) void*)(g),       \
    (__attribute__((address_space(3))) void*)(l), 16, 0, 0)

// ---------------------------------------------------------------------------
// Workspace layout (byte offsets). High water: 0x8D40000 (= 148 MB).
// ---------------------------------------------------------------------------
constexpr size_t OFF_LHS     = 0x0;        // f32 [3][3][64]
constexpr size_t OFF_U1U2    = 0x1000;     // f32 [64]
constexpr size_t OFF_BIASBIG = 0x1100;     // f32 [1536]
constexpr size_t OFF_FH      = 0x3000;     // f32 [2][8][2048]
constexpr size_t OFF_GH      = 0x23000;
constexpr size_t OFF_RDH     = 0x43000;
constexpr size_t OFF_FO      = 0x63000;    // f32 [8][2048]
constexpr size_t OFF_GO      = 0x73000;
constexpr size_t OFF_RDO     = 0x83000;
constexpr size_t OFF_LHST    = 0x93000;    // f32 [8][12][2048]
constexpr size_t OFF_RHST    = 0x153000;   // f32 [8][2048][12]
constexpr size_t OFF_PROD    = 0x213000;   // f32 [8][12][12]
constexpr size_t OFF_E       = 0x215000;   // f32 [8][12][12]
constexpr size_t OFF_WCATT   = 0x220000;   // bf16 [768][768]
constexpr size_t OFF_WOUTT   = 0x340000;   // bf16 [768][768]
constexpr size_t OFF_WTBIG   = 0x460000;   // bf16 [768][768] tap-expanded time_w
constexpr size_t OFF_XCOLT   = 0x580000;   // bf16 [384][2048] (rows 288.. zero)
constexpr size_t OFF_CHEBT   = 0x700000;   // bf16 [3][2048][2048]  -> 0x1F00000
constexpr size_t OFF_C1      = 0x1F00000;  // bf16 [12][2048][384]  -> 0x3100000
constexpr size_t OFF_H       = 0x4300000;  // bf16 [16384][768]     -> 0x5B00000
constexpr size_t OFF_P       = 0x700000;   // bf16 [8][2048][2048] (cheb/C1/h dead) -> 0x4700000
constexpr size_t OFF_WHCATT  = 0x5B00000;  // bf16 [8][768][2048]   -> 0x7300000
constexpr size_t OFF_HCAT    = 0x7300000;  // bf16 [16384][768]     -> 0x8B00000
constexpr size_t OFF_WHOUTT  = 0x5B00000;  // reuse (WhcatT dead after G4)
constexpr size_t OFF_GCNB    = 0x7300000;  // bf16 [16384][768] (hcat dead) -> 0x8B00000
constexpr size_t OFF_WBFBIG  = 0x8B00000;  // bf16 [1536][768] tap-expanded back|fore -> 0x8D40000
constexpr size_t OFF_TCS     = 0x700000;   // bf16 [16384][12][64] (P dead) -> 0x1F00000
constexpr size_t OFF_RESULTB = 0x3700000;  // bf16 [16384][768]     -> 0x4F00000
constexpr size_t WS_NEEDED   = 0x8D40000;

// ---------------------------------------------------------------------------
// Generic MFMA GEMM. Block tile 128 x (128*WN), BK=32, 256 thr (4 waves,
// 2x2 wave grid, wave tile 64 x (64*WN)). 3-buffer LDS + chunk XOR-swizzle +
// single-barrier depth-2 counted-vmcnt pipeline.
// EPI: 1 bf16-LDS-transposed-per-2048batch   2 elu->bf16
//      6 time-conv +time_b[col&63] -> bf16   7 final +biasBig -> f32x4 rows
//      8 relu->bf16                          9 plain bf16 (C1 partials)
// ---------------------------------------------------------------------------
struct GemmP {
  const u16* A; const u16* BT;
  long sA, sB;            // per-z batch strides (elements)
  int K, lda, ldb;
  int swz, splitK;
  float* Cf; long sCf; int ldcf;
  u16* Cb;  long sCb; int ldcb;
  u16* CbT; int ldcT; long sCbT;
  const float* bias;
  float* outB; float* outF;
};

template <int EPI, int WN>
__global__ __launch_bounds__(256, (WN == 1 ? 3 : 2)) void gemm_bf16(GemmP p) {
  constexpr int BUFU  = (WN == 1) ? 8192 : 12288;   // u16 per K-step buffer
  constexpr int SMEMU = 3 * BUFU;                   // 3 buffers (EPI1 17408 fits)
  constexpr int LPW   = (WN == 1) ? 4 : 6;          // loads per wave per stage
  __shared__ u16 smem[SMEMU];
  const int tid  = threadIdx.x;
  const int lane = tid & 63;
  const int wid  = tid >> 6;
  const int wm = wid >> 1, wn = wid & 1;
  const int z = blockIdx.z;

  long m0, n0;
  if (p.swz) {
    int nT = gridDim.x;
    int nwg = nT * gridDim.y;
    int lin = blockIdx.x + nT * blockIdx.y;
    int q = nwg >> 3;                       // nwg % 8 == 0 guaranteed by caller
    int swz = (lin & 7) * q + (lin >> 3);   // XCD-chunked bijection
    m0 = (long)(swz / nT) * 128;
    n0 = (long)(swz % nT) * (128 * WN);
  } else {
    m0 = (long)blockIdx.y * 128;
    n0 = (long)blockIdx.x * (128 * WN);
  }

  const int K = p.K;
  long aBase, bBase;
  if (p.splitK) {
    int kz = z >> 2, ch = z & 3;
    aBase = (long)kz * p.sA + (long)ch * 512;
    bBase = (long)ch * 512;
  } else {
    aBase = (long)z * p.sA;
    bBase = (long)z * p.sB;
  }
  const u16* Ab = p.A + aBase + m0 * p.lda;
  const u16* Bb = p.BT + bBase + n0 * p.ldb;

  // staging: A 128 rows -> 32/wave; B 128*WN rows -> 32*WN/wave.
  // source k-chunk pre-swizzled so swizzled ds_reads see the right data.
  const int sk = (((lane & 3) ^ ((lane >> 3) & 3))) * 8;
  const u16* aP0 = Ab + (long)(wid * 32 + (lane >> 2)) * p.lda + sk;
  const u16* aP1 = aP0 + (long)16 * p.lda;
  const u16* bP0 = Bb + (long)(wid * 32 * WN + (lane >> 2)) * p.ldb + sk;
  const u16* bP1 = bP0 + (long)16 * p.ldb;
  const u16* bP2 = bP0 + (long)32 * p.ldb;
  const u16* bP3 = bP0 + (long)48 * p.ldb;
  const int aslot = wid * 1024;
  const int bslot = 4096 + wid * (WN == 1 ? 1024 : 2048);

  auto STAGE = [&](int s, int bi) {
    long ko = (long)s * 32;
    u16* base = smem + bi * BUFU;
    GLOAD16(aP0 + ko, base + aslot);
    GLOAD16(aP1 + ko, base + aslot + 512);
    GLOAD16(bP0 + ko, base + bslot);
    GLOAD16(bP1 + ko, base + bslot + 512);
    if constexpr (WN == 2) {
      GLOAD16(bP2 + ko, base + bslot + 1024);
      GLOAD16(bP3 + ko, base + bslot + 1536);
    }
  };

  f32x4 acc[4][4 * WN];
  f32x4 zero = {0.f, 0.f, 0.f, 0.f};
#pragma unroll
  for (int i = 0; i < 4; ++i)
#pragma unroll
    for (int j = 0; j < 4 * WN; ++j) acc[i][j] = zero;

  // fragment-read offsets (chunk XOR matches the pre-swizzled source)
  const int xorc = (lane >> 1) & 3;
  const int aoff = (wm * 64 + (lane & 15)) * 32 + ((lane >> 4) ^ xorc) * 8;
  const int boff = 4096 + (wn * 64 * WN + (lane & 15)) * 32 + ((lane >> 4) ^ xorc) * 8;

  const int nsteps = K >> 5;   // >= 2 at all call sites

  // prologue: stage tiles 0,1; wait tile 0 (tile 1's LPW stay in flight)
  STAGE(0, 0);
  STAGE(1, 1);
  waitvm<LPW>();
  rawbar();

  // Single-barrier steady state. Invariant entering step i: stage_i landed,
  // stage_{i+1} in flight. STAGE(i+2) targets buffer (cur+2)%3 == (cur-1)%3,
  // whose reads finished before the step-(i-1) barrier (MFMA reg deps force
  // each wave's own lgkm drain before its MFMAs -> before its barrier).
  int cur = 0;
  for (int i = 0; i < nsteps; ++i) {
    const u16* buf = smem + cur * BUFU;
    bf16x8 av[4], bv[4 * WN];
#pragma unroll
    for (int mi = 0; mi < 4; ++mi) av[mi] = *(const bf16x8*)&buf[aoff + mi * 512];
#pragma unroll
    for (int ni = 0; ni < 4 * WN; ++ni) bv[ni] = *(const bf16x8*)&buf[boff + ni * 512];
#pragma unroll
    for (int mi = 0; mi < 4; ++mi)
#pragma unroll
      for (int ni = 0; ni < 4 * WN; ++ni)
        acc[mi][ni] = __builtin_amdgcn_mfma_f32_16x16x32_bf16(av[mi], bv[ni], acc[mi][ni], 0, 0, 0);
    if (i + 1 < nsteps) {
      if (i + 2 < nsteps) {
        STAGE(i + 2, cur == 0 ? 2 : cur - 1);   // (cur+2)%3
        waitvm<LPW>();                          // stage i+1 landed
      } else {
        waitvm<0>();
      }
      rawbar();
    }
    cur = (cur == 2) ? 0 : cur + 1;
  }
  __syncthreads();  // drain before epilogue smem reuse (EPI1)

  if constexpr (EPI == 1) {
    // Per 128-col half: stage bf16 transposed in LDS, coalesced column writes.
#pragma unroll
    for (int h = 0; h < 2; ++h) {
      if (h == 1) __syncthreads();
      if (WN == 1 || wn == h) {
#pragma unroll
        for (int mi = 0; mi < 4; ++mi)
#pragma unroll
          for (int ni = 0; ni < 4 * WN; ++ni) {
            int cl = (WN == 1 ? wn * 64 : 0) + ni * 16 + (lane & 15);
            int mlb = wm * 64 + mi * 16 + ((lane >> 4) << 2);
#pragma unroll
            for (int r = 0; r < 4; ++r)
              smem[cl * 136 + mlb + r] = f2b(acc[mi][ni][r]);
          }
      }
      __syncthreads();
      int c = tid >> 1, half = tid & 1;
      long bat = m0 >> 11;                  // 2048-row batches
      u16* dst = p.CbT + bat * p.sCbT + (long)(n0 + h * 128 + c) * p.ldcT +
                 (m0 & 2047) + half * 64;
      const u16* srcp = &smem[c * 136 + half * 64];
#pragma unroll
      for (int j = 0; j < 64; j += 8)
        *(u16x8*)(dst + j) = *(const u16x8*)(srcp + j);
      if (WN == 1) break;                   // WN=1 tile is only 128 cols
    }
    return;
  }

  if constexpr (EPI == 7) {
    // In-register 4x4 transpose (lanes 4g..4g+3) -> dwordx4 row stores.
    const int q = lane >> 4, g4 = (lane >> 2) & 3, j = lane & 3;
    const int back = ((int)n0 < 768);
    float* obase = (back ? p.outB : p.outF) - (back ? 0 : 768);
#pragma unroll
    for (int mi = 0; mi < 4; ++mi) {
      long rb0 = m0 + wm * 64 + mi * 16 + q * 4;
#pragma unroll
      for (int ni = 0; ni < 4 * WN; ++ni) {
        int cb = (int)n0 + wn * 64 * WN + ni * 16 + g4 * 4;
        f32x4 v = acc[mi][ni];
        float bsv = p.bias[cb + j];
        v[0] += bsv; v[1] += bsv; v[2] += bsv; v[3] += bsv;
#pragma unroll
        for (int d = 1; d <= 2; d <<= 1) {
          f32x4 t;
#pragma unroll
          for (int b = 0; b < 4; ++b) t[b] = __shfl_xor(v[b ^ d], d, 64);
#pragma unroll
          for (int b = 0; b < 4; ++b) if ((lane ^ b) & d) v[b] = t[b];
        }
        *(f32x4*)(obase + (rb0 + j) * 768 + cb) = v;
      }
    }
    return;
  }

#pragma unroll
  for (int mi = 0; mi < 4; ++mi) {
    long rb0 = m0 + wm * 64 + mi * 16 + ((lane >> 4) << 2);
#pragma unroll
    for (int ni = 0; ni < 4 * WN; ++ni) {
      int col = (int)n0 + wn * 64 * WN + ni * 16 + (lane & 15);
#pragma unroll
      for (int r = 0; r < 4; ++r) {
        float v = acc[mi][ni][r];
        long row = rb0 + r;
        if constexpr (EPI == 2) {
          float e = v > 0.f ? v : expm1f(v);
          p.Cb[(long)z * p.sCb + row * p.ldcb + col] = f2b(e);
        } else if constexpr (EPI == 6) {
          p.Cb[row * 768 + col] = f2b(v + p.bias[col & 63]);
        } else if constexpr (EPI == 9) {
          p.Cb[(long)z * p.sCb + row * p.ldcb + col] = f2b(v);
        } else {  // EPI == 8: relu -> bf16
          p.Cb[(long)z * p.sCb + row * p.ldcb + col] = f2b(fmaxf(v, 0.f));
        }
      }
    }
  }
}

// ---------------------------------------------------------------------------
// Small kernels
// ---------------------------------------------------------------------------
__global__ void k_prep(const float* Gamma, const float* U1, const float* U2,
                       const float* back_b, const float* fore_b,
                       float* lhs, float* u1u2, float* biasBig) {
  int o = threadIdx.x;
  if (o < 64) {
    const float cx[3][3] = {{1.f, 0.86602540378443871f, 0.5f},
                            {1.f, 6.123233995736766e-17f, -1.f},
                            {1.f, -0.86602540378443871f, 0.5f}};
    for (int k = 0; k < 3; ++k)
      for (int i = 0; i < 3; ++i) {
        float s = 0;
        for (int j = 0; j < 3; ++j) s += Gamma[(j * 3 + i) * 64 + o] * cx[j][k];
        lhs[(k * 3 + i) * 64 + o] = s;
      }
    float s = 0;
    for (int g = 0; g < 64; ++g) s += U1[o * 64 + g] * U2[g];
    u1u2[o] = s;
    for (int t = 0; t < 12; ++t) {
      biasBig[o * 12 + t] = back_b[o];
      biasBig[768 + o * 12 + t] = fore_b[o];
    }
  }
}

__global__ void k_convert(const float* W_heads, const float* W_out, const float* time_w,
                          const float* back_w, const float* fore_w, const float* xg,
                          u16* WcatT, u16* WoutT, u16* WtBig, u16* WbfBig, u16* xcolT) {
  const int N1 = 589824, NT = 589824, NBF = 1179648, N5 = 786432;
  const int TOT = 2 * N1 + NT + NBF + N5;
  for (int o = blockIdx.x * 256 + threadIdx.x; o < TOT; o += gridDim.x * 256) {
    if (o < N1) {
      int dcol = o / 768, kk = o % 768;
      int hd = dcol / 384, d = dcol % 384;
      WcatT[o] = f2b(W_heads[((long)hd * 768 + kk) * 384 + d]);
    } else if (o < 2 * N1) {
      int o2 = o - N1; int dcol = o2 / 768, kk = o2 % 768;
      WoutT[o2] = f2b(W_out[kk * 768 + dcol]);
    } else if (o < 2 * N1 + NT) {
      // WtBig[t*64+ft][fc*12+tau] = time_w[ft][fc][tau-t+1] (0 outside taps)
      int o3 = o - 2 * N1; int col = o3 / 768, kk = o3 % 768;
      int t = col >> 6, ft = col & 63, fc = kk / 12, tau = kk % 12;
      int r = tau - t + 1;
      WtBig[o3] = f2b((r >= 0 && r < 3) ? time_w[ft * 192 + fc * 3 + r] : 0.f);
    } else if (o < 2 * N1 + NT + NBF) {
      // WbfBig[half*768 + c*12+t][fc*12+tau] = (back|fore)_w[c][fc][tau-t+1]
      int o4 = o - 2 * N1 - NT; int col = o4 / 768, kk = o4 % 768;
      int rem = (col < 768) ? col : col - 768;
      int c = rem / 12, tt = rem % 12;
      int fc = kk / 12, tau = kk % 12; int r = tau - tt + 1;
      const float* wsrc = (col < 768) ? back_w : fore_w;
      WbfBig[o4] = f2b((r >= 0 && r < 3) ? wsrc[c * 192 + fc * 3 + r] : 0.f);
    } else {
      int o5 = o - 2 * N1 - NT - NBF; int c = o5 / 2048, n = o5 % 2048;
      float v = 0.f;
      if (c < 288) {
        int b = c / 36, r2 = c % 36, i = r2 / 12, t = r2 % 12;
        v = xg[(long)(b * 2048 + n) * 36 + i * 12 + t];
      }
      xcolT[o5] = f2b(v);
    }
  }
}

// chebT[k][m][n] = bf16(cheb[k][n][m])
__global__ void k_chebT(const float* cheb, u16* chebT) {
  __shared__ float ts[32][33];
  int n0 = blockIdx.x * 32, m0 = blockIdx.y * 32, k = blockIdx.z;
  int c = threadIdx.x & 31, rq = threadIdx.x >> 5;  // rq 0..7
  const long base = (long)k * 2048 * 2048;
  for (int q = 0; q < 4; ++q) {
    int n = n0 + rq + q * 8;
    ts[rq + q * 8][c] = cheb[base + (long)n * 2048 + m0 + c];
  }
  __syncthreads();
  for (int q = 0; q < 4; ++q) {
    int m = m0 + rq + q * 8;
    chebT[base + (long)m * 2048 + n0 + c] = f2b(ts[c][rq + q * 8]);
  }
}

// h[bn][o*12+t] = bf16(relu(0.5 * sum_{k,i,ch} C1p[k*4+ch][n][b*36+i*12+t] * lhs[k][i][o]))
__global__ __launch_bounds__(256) void k_h(const u16* C1, const float* lhs, u16* h) {
  int bn = blockIdx.x; int b = bn >> 11, n = bn & 2047;
  int tid = threadIdx.x;
  __shared__ float c1s[108], ls[576];
  if (tid < 108) {
    int kk = tid / 12, t = tid % 12; int k = kk / 3, i = kk % 3;
    float s = 0;
#pragma unroll
    for (int ch = 0; ch < 4; ++ch)
      s += b2f(C1[((long)(k * 4 + ch) * 2048 + n) * 384 + b * 36 + i * 12 + t]);
    c1s[tid] = s;
  }
  for (int s = tid; s < 576; s += 256) ls[s] = lhs[s];
  __syncthreads();
  for (int q = 0; q < 3; ++q) {
    int idx = tid + q * 256; int o = idx / 12, t = idx % 12;
    float s = 0;
#pragma unroll
    for (int kk = 0; kk < 9; ++kk) s += c1s[kk * 12 + t] * ls[kk * 64 + o];
    s *= 0.5f;
    if (s < 0.f) s = 0.f;
    h[(long)bn * 768 + idx] = f2b(s);
  }
}

// f,g from WhT[b][dOff+d][i], a-slices
__global__ __launch_bounds__(256) void k_fg(const u16* WhT, int dOff, int Dlen,
                                            const float* aF, const float* aG,
                                            float* fOut, float* gOut) {
  int b = blockIdx.y;
  int i = blockIdx.x * 256 + threadIdx.x;
  __shared__ float af[768], ag[768];
  for (int s = threadIdx.x; s < Dlen; s += 256) { af[s] = aF[s]; ag[s] = aG[s]; }
  __syncthreads();
  const u16* wp = WhT + ((long)b * 768 + dOff) * 2048 + i;
  float fs = 0, gs = 0;
  for (int d = 0; d < Dlen; ++d) {
    float w = b2f(wp[(long)d * 2048]);
    fs += w * af[d]; gs += w * ag[d];
  }
  fOut[b * 2048 + i] = fs;
  gOut[b * 2048 + i] = gs;
}

// rdenom[b][j] = 1 / sum_i q(f_i + g_j)
__global__ __launch_bounds__(256) void k_denom(const float* f, const float* g, float* rd) {
  int b = blockIdx.y;
  int jl = threadIdx.x & 63, ch = threadIdx.x >> 6;
  int j = blockIdx.x * 64 + jl;
  __shared__ float fl[2048];
  __shared__ float red[256];
  for (int s = threadIdx.x; s < 2048; s += 256) fl[s] = f[b * 2048 + s];
  __syncthreads();
  float gj = g[b * 2048 + j];
  float acc = 0;
  for (int i = ch * 512; i < ch * 512 + 512; ++i) acc += qfun(fl[i] + gj);
  red[threadIdx.x] = acc;
  __syncthreads();
  if (ch == 0) {
    float s = red[jl] + red[jl + 64] + red[jl + 128] + red[jl + 192];
    rd[b * 2048 + j] = 1.f / s;
  }
}

// P[b][i][j] = bf16(q(f_i+g_j) * rdenom_j)
__global__ __launch_bounds__(256) void k_P(const float* f, const float* g,
                                           const float* rd, u16* P) {
  int j = blockIdx.x * 256 + threadIdx.x;
  int i0 = blockIdx.y * 16;
  int b = blockIdx.z;
  __shared__ float fl[16];
  if (threadIdx.x < 16) fl[threadIdx.x] = f[b * 2048 + i0 + threadIdx.x];
  __syncthreads();
  float gj = g[b * 2048 + j], rj = rd[b * 2048 + j];
  u16* Pp = P + ((long)b * 2048 + i0) * 2048 + j;
#pragma unroll
  for (int ii = 0; ii < 16; ++ii) Pp[(long)ii * 2048] = f2b(qfun(fl[ii] + gj) * rj);
}

// lhs_t[b][t][n], rhs_t[b][n][t] from tc_s[bn][t][f] (bf16)
__global__ void k_temporal(const u16* tc, const float* u1u2, const float* U3g,
                           float* lhs_t, float* rhs_t) {
  __shared__ float uu[64], u3[64];
  int tid = threadIdx.x;
  if (tid < 64) { uu[tid] = u1u2[tid]; u3[tid] = U3g[tid]; }
  __syncthreads();
  int gid = blockIdx.x * 256 + tid;  // < 196608
  const u16* p = tc + (long)gid * 64;
  float s1 = 0, s2 = 0;
#pragma unroll
  for (int c = 0; c < 8; ++c) {
    u16x8 vv = *(const u16x8*)(p + c * 8);
#pragma unroll
    for (int j = 0; j < 8; ++j) {
      float v = b2f(vv[j]);
      s1 += v * uu[c * 8 + j]; s2 += v * u3[c * 8 + j];
    }
  }
  int t = gid % 12; long bn = gid / 12;
  int b = (int)(bn >> 11);
  lhs_t[((long)b * 12 + t) * 2048 + (int)(bn & 2047)] = s1;
  rhs_t[gid] = s2;
}

__global__ void k_prod(const float* lhs_t, const float* rhs_t, float* prod) {
  int bi = blockIdx.x;  // < 1152
  int b = bi / 144; int r = bi % 144; int s = r / 12; int u = r % 12;
  int tid = threadIdx.x;
  float acc = 0;
  const float* lp = lhs_t + ((long)b * 12 + s) * 2048;
  const float* rp = rhs_t + (long)b * 2048 * 12 + u;
  for (int n = tid; n < 2048; n += 256) acc += lp[n] * rp[n * 12];
  __shared__ float red[256];
  red[tid] = acc; __syncthreads();
  for (int st = 128; st > 0; st >>= 1) {
    if (tid < st) red[tid] += red[tid + st];
    __syncthreads();
  }
  if (tid == 0) prod[bi] = red[0];
}

__global__ void k_E(const float* prod, const float* be, const float* Ve, float* E) {
  int b = blockIdx.x; int tid = threadIdx.x;
  __shared__ float S0[144], E1[144], mx[12], dn[12];
  if (tid < 144) {
    float v = prod[b * 144 + tid] + be[tid];
    S0[tid] = 1.f / (1.f + __expf(-v));
  }
  __syncthreads();
  if (tid < 144) {
    int i = tid / 12, t = tid % 12;
    float a = 0;
    for (int s = 0; s < 12; ++s) a += Ve[i * 12 + s] * S0[s * 12 + t];
    E1[tid] = a;
  }
  __syncthreads();
  if (tid < 12) {
    float m = -1e30f;
    for (int i = 0; i < 12; ++i) m = fmaxf(m, E1[i * 12 + tid]);
    float d = 0;
    for (int i = 0; i < 12; ++i) d += __expf(E1[i * 12 + tid] - m);
    mx[tid] = m; dn[tid] = d;
  }
  __syncthreads();
  if (tid < 144) {
    int t = tid % 12;
    E[b * 144 + tid] = __expf(E1[tid] - mx[t]) / dn[t];
  }
}

// tcn + residual + relu + layernorm(channel) -> resultB bf16 [bn][f*12+t]
__global__ __launch_bounds__(256) void k_res_ln(const u16* tc, const float* E,
                                                const float* xg, const float* res_w,
                                                const float* res_b, const float* ln_g,
                                                const float* ln_b, u16* result) {
  int bn = blockIdx.x; int b = bn >> 11;
  int tid = threadIdx.x;
  __shared__ float tcb[768], Eb[144], xl[36], rw[192], rb[64], lg[64], lb[64], zl[768], mu[12], rs[12];
  for (int s = tid; s < 768; s += 256) tcb[s] = b2f(tc[(long)bn * 768 + s]);
  if (tid < 144) Eb[tid] = E[b * 144 + tid];
  if (tid < 36) xl[tid] = xg[(long)bn * 36 + tid];
  if (tid >= 64 && tid < 256) { int q = tid - 64; if (q < 192) rw[q] = res_w[q]; }
  if (tid < 64) { rb[tid] = res_b[tid]; lg[tid] = ln_g[tid]; lb[tid] = ln_b[tid]; }
  __syncthreads();
  float z[3];
#pragma unroll
  for (int q = 0; q < 3; ++q) {
    int idx = tid + q * 256; int f = idx / 12, s = idx % 12;
    float tcn = 0;
#pragma unroll
    for (int t = 0; t < 12; ++t) tcn += tcb[t * 64 + f] * Eb[t * 12 + s];
    float xr = rb[f];
#pragma unroll
    for (int i = 0; i < 3; ++i) xr += rw[f * 3 + i] * xl[i * 12 + s];
    float v = xr + tcn;
    v = v > 0.f ? v : 0.f;
    z[q] = v; zl[idx] = v;
  }
  __syncthreads();
  if (tid < 12) {
    float m = 0, m2 = 0;
    for (int f = 0; f < 64; ++f) { float v = zl[f * 12 + tid]; m += v; m2 += v * v; }
    m *= (1.f / 64.f); m2 *= (1.f / 64.f);
    mu[tid] = m;
    float var = m2 - m * m;
    rs[tid] = rsqrtf((var > 0.f ? var : 0.f) + 1e-5f);
  }
  __syncthreads();
#pragma unroll
  for (int q = 0; q < 3; ++q) {
    int idx = tid + q * 256; int f = idx / 12, s = idx % 12;
    result[(long)bn * 768 + idx] = f2b((z[q] - mu[s]) * rs[s] * lg[f] + lb[f]);
  }
}

__global__ void k_sentinel(float* out, long n) {
  long i = (long)blockIdx.x * 256 + threadIdx.x;
  if (i < n) out[i] = 12345.0f;
}

// ---------------------------------------------------------------------------
// Launcher
// ---------------------------------------------------------------------------
extern "C" void kernel_launch(void* const* d_in, const int* in_sizes, int n_in,
                              void* d_out, int out_size, void* d_ws, size_t ws_size,
                              hipStream_t stream) {
  (void)in_sizes; (void)n_in;
  const float* x       = (const float*)d_in[0];
  const float* cheb    = (const float*)d_in[1];
  const float* Gamma   = (const float*)d_in[2];
  const float* W_heads = (const float*)d_in[3];
  const float* a_heads = (const float*)d_in[4];
  const float* W_out   = (const float*)d_in[5];
  const float* a_out   = (const float*)d_in[6];
  const float* U1      = (const float*)d_in[7];
  const float* U2      = (const float*)d_in[8];
  const float* U3      = (const float*)d_in[9];
  const float* be      = (const float*)d_in[10];
  const float* Ve      = (const float*)d_in[11];
  const float* time_w  = (const float*)d_in[12];
  const float* time_b  = (const float*)d_in[13];
  const float* res_w   = (const float*)d_in[14];
  const float* res_b   = (const float*)d_in[15];
  const float* back_w  = (const float*)d_in[16];
  const float* back_b  = (const float*)d_in[17];
  const float* fore_w  = (const float*)d_in[18];
  const float* fore_b  = (const float*)d_in[19];
  const float* ln_g    = (const float*)d_in[20];
  const float* ln_b    = (const float*)d_in[21];
  float* out = (float*)d_out;

  if (ws_size < WS_NEEDED) {  // distinctive failure signature (absmax ~12345)
    k_sentinel<<<(out_size + 255) / 256, 256, 0, stream>>>(out, out_size);
    return;
  }

  char* ws = (char*)d_ws;
  float* lhs     = (float*)(ws + OFF_LHS);
  float* u1u2    = (float*)(ws + OFF_U1U2);
  float* biasBig = (float*)(ws + OFF_BIASBIG);
  float* fH      = (float*)(ws + OFF_FH);
  float* gH      = (float*)(ws + OFF_GH);
  float* rdH     = (float*)(ws + OFF_RDH);
  float* fO      = (float*)(ws + OFF_FO);
  float* gO      = (float*)(ws + OFF_GO);
  float* rdO     = (float*)(ws + OFF_RDO);
  float* lhs_t   = (float*)(ws + OFF_LHST);
  float* rhs_t   = (float*)(ws + OFF_RHST);
  float* prod    = (float*)(ws + OFF_PROD);
  float* Ebuf    = (float*)(ws + OFF_E);
  u16* WcatT   = (u16*)(ws + OFF_WCATT);
  u16* WoutT   = (u16*)(ws + OFF_WOUTT);
  u16* WtBig   = (u16*)(ws + OFF_WTBIG);
  u16* WbfBig  = (u16*)(ws + OFF_WBFBIG);
  u16* xcolT   = (u16*)(ws + OFF_XCOLT);
  u16* chebT   = (u16*)(ws + OFF_CHEBT);
  u16* C1      = (u16*)(ws + OFF_C1);
  u16* hbuf    = (u16*)(ws + OFF_H);
  u16* Pbuf    = (u16*)(ws + OFF_P);
  u16* WhcatT  = (u16*)(ws + OFF_WHCATT);
  u16* hcat    = (u16*)(ws + OFF_HCAT);
  u16* WhoutT  = (u16*)(ws + OFF_WHOUTT);
  u16* gcnB    = (u16*)(ws + OFF_GCNB);
  u16* tcsB    = (u16*)(ws + OFF_TCS);
  u16* resultB = (u16*)(ws + OFF_RESULTB);

  // --- prep ---
  k_prep<<<1, 64, 0, stream>>>(Gamma, U1, U2, back_b, fore_b, lhs, u1u2, biasBig);
  k_convert<<<2048, 256, 0, stream>>>(W_heads, W_out, time_w, back_w, fore_w, x,
                                      WcatT, WoutT, WtBig, WbfBig, xcolT);
  k_chebT<<<dim3(64, 64, 3), 256, 0, stream>>>(cheb, chebT);

  // --- G1: C1 partials (bf16) = chebT @ xcolT^T, split-K x4 (z=k*4+ch, K=512) ---
  {
    GemmP p{}; p.A = chebT; p.BT = xcolT; p.sA = 2048L * 2048; p.sB = 0;
    p.K = 512; p.lda = 2048; p.ldb = 2048; p.splitK = 1; p.swz = 1;
    p.Cb = C1; p.sCb = 2048L * 384; p.ldcb = 384;
    gemm_bf16<9, 1><<<dim3(3, 16, 12), 256, 0, stream>>>(p);
  }
  k_h<<<16384, 256, 0, stream>>>(C1, lhs, hbuf);

  // --- G2: Wh_cat (LDS-transposed out) ---
  {
    GemmP p{}; p.A = hbuf; p.BT = WcatT; p.sA = 0; p.sB = 0;
    p.K = 768; p.lda = 768; p.ldb = 768; p.swz = 1;
    p.CbT = WhcatT; p.ldcT = 2048; p.sCbT = 768L * 2048;
    gemm_bf16<1, 2><<<dim3(3, 128, 1), 256, 0, stream>>>(p);
  }
  // f,g per head
  k_fg<<<dim3(8, 8), 256, 0, stream>>>(WhcatT, 0, 384, a_heads, a_heads + 384, fH, gH);
  k_fg<<<dim3(8, 8), 256, 0, stream>>>(WhcatT, 384, 384, a_heads + 768, a_heads + 1152,
                                       fH + 16384, gH + 16384);
  // heads: denom, P, att GEMM (elu -> hcat half)
  for (int hd = 0; hd < 2; ++hd) {
    const float* f = fH + hd * 16384; const float* g = gH + hd * 16384;
    float* rd = rdH + hd * 16384;
    k_denom<<<dim3(32, 8), 256, 0, stream>>>(f, g, rd);
    k_P<<<dim3(8, 128, 8), 256, 0, stream>>>(f, g, rd, Pbuf);
    GemmP p{}; p.A = Pbuf; p.BT = WhcatT + (long)hd * 384 * 2048;
    p.sA = 2048L * 2048; p.sB = 768L * 2048;
    p.K = 2048; p.lda = 2048; p.ldb = 2048; p.swz = 1;
    p.Cb = hcat + hd * 384; p.sCb = 2048L * 768; p.ldcb = 768;
    gemm_bf16<2, 1><<<dim3(3, 16, 8), 256, 0, stream>>>(p);
  }

  // --- G5: Wh_out (LDS-transposed out) ---
  {
    GemmP p{}; p.A = hcat; p.BT = WoutT; p.sA = 0; p.sB = 0;
    p.K = 768; p.lda = 768; p.ldb = 768; p.swz = 1;
    p.CbT = WhoutT; p.ldcT = 2048; p.sCbT = 768L * 2048;
    gemm_bf16<1, 2><<<dim3(3, 128, 1), 256, 0, stream>>>(p);
  }
  k_fg<<<dim3(8, 8), 256, 0, stream>>>(WhoutT, 0, 768, a_out, a_out + 768, fO, gO);
  k_denom<<<dim3(32, 8), 256, 0, stream>>>(fO, gO, rdO);
  k_P<<<dim3(8, 128, 8), 256, 0, stream>>>(fO, gO, rdO, Pbuf);
  // --- G6: out attention, relu -> gcnB bf16 ---
  {
    GemmP p{}; p.A = Pbuf; p.BT = WhoutT; p.sA = 2048L * 2048; p.sB = 768L * 2048;
    p.K = 2048; p.lda = 2048; p.ldb = 2048; p.swz = 1;
    p.Cb = gcnB; p.sCb = 2048L * 768; p.ldcb = 768;
    gemm_bf16<8, 2><<<dim3(3, 16, 8), 256, 0, stream>>>(p);
  }

  // --- temporal conv as dense GEMM (tap-expanded weights) -> tcsB bf16 ---
  {
    GemmP p{}; p.A = gcnB; p.BT = WtBig; p.sA = 0; p.sB = 0;
    p.K = 768; p.lda = 768; p.ldb = 768; p.swz = 1;
    p.Cb = tcsB; p.bias = time_b;
    gemm_bf16<6, 2><<<dim3(3, 128, 1), 256, 0, stream>>>(p);
  }

  // --- temporal attention ---
  k_temporal<<<768, 256, 0, stream>>>(tcsB, u1u2, U3, lhs_t, rhs_t);
  k_prod<<<1152, 256, 0, stream>>>(lhs_t, rhs_t, prod);
  k_E<<<8, 256, 0, stream>>>(prod, be, Ve, Ebuf);

  // --- residual + LN -> bf16 ---
  k_res_ln<<<16384, 256, 0, stream>>>(tcsB, Ebuf, x, res_w, res_b, ln_g, ln_b, resultB);

  // --- backcast / forecast convs as one dense GEMM, vectorized row writes ---
  {
    GemmP p{}; p.A = resultB; p.BT = WbfBig; p.sA = 0; p.sB = 0;
    p.K = 768; p.lda = 768; p.ldb = 768; p.swz = 1;
    p.bias = biasBig; p.outB = out; p.outF = out + 12582912L;
    gemm_bf16<7, 2><<<dim3(6, 128, 1), 256, 0, stream>>>(p);
  }
}

// Round 19
// 702.841 us; speedup vs baseline: 2.1604x; 1.0008x over previous
//
#include <hip/hip_runtime.h>

// ============================================================================
// ASTGCN block for MI355X. Dims: B=8, N=2048, FIN=3, T=12, K=3, FC=FT=64.
// bf16 MFMA (16x16x32) for all big GEMMs, fp32 elsewhere.
// GEMM convention: C[m,n] = sum_k A[m,k] * BT[n,k]; A,BT bf16 K-contiguous.
// R4: LDS chunk XOR-swizzle. R7: WN template, bf16 C1, EPI7 reg-transpose.
// R10: 3-buffer single-barrier depth-2 K-loop (integer buffer index).
// R16: REVERT to the R10 configuration (best measured, 698 us). Subsequent
//      branches (AF frags R11, z-fold R12, frag producers R13, barrier-free
//      afb R14, occupancy bump R15 -> VGPR-64 scratch spill) all netted <= 0.
// ============================================================================

typedef unsigned short u16;
typedef __bf16 bf16x8 __attribute__((ext_vector_type(8)));
typedef float f32x4 __attribute__((ext_vector_type(4)));
typedef u16 u16x8 __attribute__((ext_vector_type(8)));

__device__ __forceinline__ u16 f2b(float f) {
  union { float f; unsigned u; } v; v.f = f;
  unsigned u = v.u;
  u = u + 0x7FFFu + ((u >> 16) & 1u);   // RNE
  return (u16)(u >> 16);
}
__device__ __forceinline__ float b2f(u16 h) {
  union { unsigned u; float f; } v; v.u = ((unsigned)h) << 16; return v.f;
}
// q(x) = exp(sigmoid(leaky_relu(x, 0.1)))
__device__ __forceinline__ float qfun(float x) {
  float e = x > 0.f ? x : 0.1f * x;
  float s = __builtin_amdgcn_rcpf(1.f + __expf(-e));
  return __expf(s);
}

template <int N> __device__ __forceinline__ void waitvm() {
  if constexpr (N == 0)      asm volatile("s_waitcnt vmcnt(0)" ::: "memory");
  else if constexpr (N == 4) asm volatile("s_waitcnt vmcnt(4)" ::: "memory");
  else                       asm volatile("s_waitcnt vmcnt(6)" ::: "memory");
}
__device__ __forceinline__ void rawbar() { asm volatile("s_barrier" ::: "memory"); }

#define GLOAD16(g, l) __builtin_amdgcn_global_load_lds( \
    (__attribute__((address_space(1))) void*)(g),       \
    (__attribute__((address_space(3))) void*)(l), 16, 0, 0)

// ---------------------------------------------------------------------------
// Workspace layout (byte offsets). High water: 0x8D40000 (= 148 MB).
// ---------------------------------------------------------------------------
constexpr size_t OFF_LHS     = 0x0;        // f32 [3][3][64]
constexpr size_t OFF_U1U2    = 0x1000;     // f32 [64]
constexpr size_t OFF_BIASBIG = 0x1100;     // f32 [1536]
constexpr size_t OFF_FH      = 0x3000;     // f32 [2][8][2048]
constexpr size_t OFF_GH      = 0x23000;
constexpr size_t OFF_RDH     = 0x43000;
constexpr size_t OFF_FO      = 0x63000;    // f32 [8][2048]
constexpr size_t OFF_GO      = 0x73000;
constexpr size_t OFF_RDO     = 0x83000;
constexpr size_t OFF_LHST    = 0x93000;    // f32 [8][12][2048]
constexpr size_t OFF_RHST    = 0x153000;   // f32 [8][2048][12]
constexpr size_t OFF_PROD    = 0x213000;   // f32 [8][12][12]
constexpr size_t OFF_E       = 0x215000;   // f32 [8][12][12]
constexpr size_t OFF_WCATT   = 0x220000;   // bf16 [768][768]
constexpr size_t OFF_WOUTT   = 0x340000;   // bf16 [768][768]
constexpr size_t OFF_WTBIG   = 0x460000;   // bf16 [768][768] tap-expanded time_w
constexpr size_t OFF_XCOLT   = 0x580000;   // bf16 [384][2048] (rows 288.. zero)
constexpr size_t OFF_CHEBT   = 0x700000;   // bf16 [3][2048][2048]  -> 0x1F00000
constexpr size_t OFF_C1      = 0x1F00000;  // bf16 [12][2048][384]  -> 0x3100000
constexpr size_t OFF_H       = 0x4300000;  // bf16 [16384][768]     -> 0x5B00000
constexpr size_t OFF_P       = 0x700000;   // bf16 [8][2048][2048] (cheb/C1/h dead) -> 0x4700000
constexpr size_t OFF_WHCATT  = 0x5B00000;  // bf16 [8][768][2048]   -> 0x7300000
constexpr size_t OFF_HCAT    = 0x7300000;  // bf16 [16384][768]     -> 0x8B00000
constexpr size_t OFF_WHOUTT  = 0x5B00000;  // reuse (WhcatT dead after G4)
constexpr size_t OFF_GCNB    = 0x7300000;  // bf16 [16384][768] (hcat dead) -> 0x8B00000
constexpr size_t OFF_WBFBIG  = 0x8B00000;  // bf16 [1536][768] tap-expanded back|fore -> 0x8D40000
constexpr size_t OFF_TCS     = 0x700000;   // bf16 [16384][12][64] (P dead) -> 0x1F00000
constexpr size_t OFF_RESULTB = 0x3700000;  // bf16 [16384][768]     -> 0x4F00000
constexpr size_t WS_NEEDED   = 0x8D40000;

// ---------------------------------------------------------------------------
// Generic MFMA GEMM. Block tile 128 x (128*WN), BK=32, 256 thr (4 waves,
// 2x2 wave grid, wave tile 64 x (64*WN)). 3-buffer LDS + chunk XOR-swizzle +
// single-barrier depth-2 counted-vmcnt pipeline.
// EPI: 1 bf16-LDS-transposed-per-2048batch   2 elu->bf16
//      6 time-conv +time_b[col&63] -> bf16   7 final +biasBig -> f32x4 rows
//      8 relu->bf16                          9 plain bf16 (C1 partials)
// ---------------------------------------------------------------------------
struct GemmP {
  const u16* A; const u16* BT;
  long sA, sB;            // per-z batch strides (elements)
  int K, lda, ldb;
  int swz, splitK;
  float* Cf; long sCf; int ldcf;
  u16* Cb;  long sCb; int ldcb;
  u16* CbT; int ldcT; long sCbT;
  const float* bias;
  float* outB; float* outF;
};

template <int EPI, int WN>
__global__ __launch_bounds__(256, (WN == 1 ? 3 : 2)) void gemm_bf16(GemmP p) {
  constexpr int BUFU  = (WN == 1) ? 8192 : 12288;   // u16 per K-step buffer
  constexpr int SMEMU = 3 * BUFU;                   // 3 buffers (EPI1 17408 fits)
  constexpr int LPW   = (WN == 1) ? 4 : 6;          // loads per wave per stage
  __shared__ u16 smem[SMEMU];
  const int tid  = threadIdx.x;
  const int lane = tid & 63;
  const int wid  = tid >> 6;
  const int wm = wid >> 1, wn = wid & 1;
  const int z = blockIdx.z;

  long m0, n0;
  if (p.swz) {
    int nT = gridDim.x;
    int nwg = nT * gridDim.y;
    int lin = blockIdx.x + nT * blockIdx.y;
    int q = nwg >> 3;                       // nwg % 8 == 0 guaranteed by caller
    int swz = (lin & 7) * q + (lin >> 3);   // XCD-chunked bijection
    m0 = (long)(swz / nT) * 128;
    n0 = (long)(swz % nT) * (128 * WN);
  } else {
    m0 = (long)blockIdx.y * 128;
    n0 = (long)blockIdx.x * (128 * WN);
  }

  const int K = p.K;
  long aBase, bBase;
  if (p.splitK) {
    int kz = z >> 2, ch = z & 3;
    aBase = (long)kz * p.sA + (long)ch * 512;
    bBase = (long)ch * 512;
  } else {
    aBase = (long)z * p.sA;
    bBase = (long)z * p.sB;
  }
  const u16* Ab = p.A + aBase + m0 * p.lda;
  const u16* Bb = p.BT + bBase + n0 * p.ldb;

  // staging: A 128 rows -> 32/wave; B 128*WN rows -> 32*WN/wave.
  // source k-chunk pre-swizzled so swizzled ds_reads see the right data.
  const int sk = (((lane & 3) ^ ((lane >> 3) & 3))) * 8;
  const u16* aP0 = Ab + (long)(wid * 32 + (lane >> 2)) * p.lda + sk;
  const u16* aP1 = aP0 + (long)16 * p.lda;
  const u16* bP0 = Bb + (long)(wid * 32 * WN + (lane >> 2)) * p.ldb + sk;
  const u16* bP1 = bP0 + (long)16 * p.ldb;
  const u16* bP2 = bP0 + (long)32 * p.ldb;
  const u16* bP3 = bP0 + (long)48 * p.ldb;
  const int aslot = wid * 1024;
  const int bslot = 4096 + wid * (WN == 1 ? 1024 : 2048);

  auto STAGE = [&](int s, int bi) {
    long ko = (long)s * 32;
    u16* base = smem + bi * BUFU;
    GLOAD16(aP0 + ko, base + aslot);
    GLOAD16(aP1 + ko, base + aslot + 512);
    GLOAD16(bP0 + ko, base + bslot);
    GLOAD16(bP1 + ko, base + bslot + 512);
    if constexpr (WN == 2) {
      GLOAD16(bP2 + ko, base + bslot + 1024);
      GLOAD16(bP3 + ko, base + bslot + 1536);
    }
  };

  f32x4 acc[4][4 * WN];
  f32x4 zero = {0.f, 0.f, 0.f, 0.f};
#pragma unroll
  for (int i = 0; i < 4; ++i)
#pragma unroll
    for (int j = 0; j < 4 * WN; ++j) acc[i][j] = zero;

  // fragment-read offsets (chunk XOR matches the pre-swizzled source)
  const int xorc = (lane >> 1) & 3;
  const int aoff = (wm * 64 + (lane & 15)) * 32 + ((lane >> 4) ^ xorc) * 8;
  const int boff = 4096 + (wn * 64 * WN + (lane & 15)) * 32 + ((lane >> 4) ^ xorc) * 8;

  const int nsteps = K >> 5;   // >= 2 at all call sites

  // prologue: stage tiles 0,1; wait tile 0 (tile 1's LPW stay in flight)
  STAGE(0, 0);
  STAGE(1, 1);
  waitvm<LPW>();
  rawbar();

  // Single-barrier steady state. Invariant entering step i: stage_i landed,
  // stage_{i+1} in flight. STAGE(i+2) targets buffer (cur+2)%3 == (cur-1)%3,
  // whose reads finished before the step-(i-1) barrier (MFMA reg deps force
  // each wave's own lgkm drain before its MFMAs -> before its barrier).
  int cur = 0;
  for (int i = 0; i < nsteps; ++i) {
    const u16* buf = smem + cur * BUFU;
    bf16x8 av[4], bv[4 * WN];
#pragma unroll
    for (int mi = 0; mi < 4; ++mi) av[mi] = *(const bf16x8*)&buf[aoff + mi * 512];
#pragma unroll
    for (int ni = 0; ni < 4 * WN; ++ni) bv[ni] = *(const bf16x8*)&buf[boff + ni * 512];
#pragma unroll
    for (int mi = 0; mi < 4; ++mi)
#pragma unroll
      for (int ni = 0; ni < 4 * WN; ++ni)
        acc[mi][ni] = __builtin_amdgcn_mfma_f32_16x16x32_bf16(av[mi], bv[ni], acc[mi][ni], 0, 0, 0);
    if (i + 1 < nsteps) {
      if (i + 2 < nsteps) {
        STAGE(i + 2, cur == 0 ? 2 : cur - 1);   // (cur+2)%3
        waitvm<LPW>();                          // stage i+1 landed
      } else {
        waitvm<0>();
      }
      rawbar();
    }
    cur = (cur == 2) ? 0 : cur + 1;
  }
  __syncthreads();  // drain before epilogue smem reuse (EPI1)

  if constexpr (EPI == 1) {
    // Per 128-col half: stage bf16 transposed in LDS, coalesced column writes.
#pragma unroll
    for (int h = 0; h < 2; ++h) {
      if (h == 1) __syncthreads();
      if (WN == 1 || wn == h) {
#pragma unroll
        for (int mi = 0; mi < 4; ++mi)
#pragma unroll
          for (int ni = 0; ni < 4 * WN; ++ni) {
            int cl = (WN == 1 ? wn * 64 : 0) + ni * 16 + (lane & 15);
            int mlb = wm * 64 + mi * 16 + ((lane >> 4) << 2);
#pragma unroll
            for (int r = 0; r < 4; ++r)
              smem[cl * 136 + mlb + r] = f2b(acc[mi][ni][r]);
          }
      }
      __syncthreads();
      int c = tid >> 1, half = tid & 1;
      long bat = m0 >> 11;                  // 2048-row batches
      u16* dst = p.CbT + bat * p.sCbT + (long)(n0 + h * 128 + c) * p.ldcT +
                 (m0 & 2047) + half * 64;
      const u16* srcp = &smem[c * 136 + half * 64];
#pragma unroll
      for (int j = 0; j < 64; j += 8)
        *(u16x8*)(dst + j) = *(const u16x8*)(srcp + j);
      if (WN == 1) break;                   // WN=1 tile is only 128 cols
    }
    return;
  }

  if constexpr (EPI == 7) {
    // In-register 4x4 transpose (lanes 4g..4g+3) -> dwordx4 row stores.
    const int q = lane >> 4, g4 = (lane >> 2) & 3, j = lane & 3;
    const int back = ((int)n0 < 768);
    float* obase = (back ? p.outB : p.outF) - (back ? 0 : 768);
#pragma unroll
    for (int mi = 0; mi < 4; ++mi) {
      long rb0 = m0 + wm * 64 + mi * 16 + q * 4;
#pragma unroll
      for (int ni = 0; ni < 4 * WN; ++ni) {
        int cb = (int)n0 + wn * 64 * WN + ni * 16 + g4 * 4;
        f32x4 v = acc[mi][ni];
        float bsv = p.bias[cb + j];
        v[0] += bsv; v[1] += bsv; v[2] += bsv; v[3] += bsv;
#pragma unroll
        for (int d = 1; d <= 2; d <<= 1) {
          f32x4 t;
#pragma unroll
          for (int b = 0; b < 4; ++b) t[b] = __shfl_xor(v[b ^ d], d, 64);
#pragma unroll
          for (int b = 0; b < 4; ++b) if ((lane ^ b) & d) v[b] = t[b];
        }
        *(f32x4*)(obase + (rb0 + j) * 768 + cb) = v;
      }
    }
    return;
  }

#pragma unroll
  for (int mi = 0; mi < 4; ++mi) {
    long rb0 = m0 + wm * 64 + mi * 16 + ((lane >> 4) << 2);
#pragma unroll
    for (int ni = 0; ni < 4 * WN; ++ni) {
      int col = (int)n0 + wn * 64 * WN + ni * 16 + (lane & 15);
#pragma unroll
      for (int r = 0; r < 4; ++r) {
        float v = acc[mi][ni][r];
        long row = rb0 + r;
        if constexpr (EPI == 2) {
          float e = v > 0.f ? v : expm1f(v);
          p.Cb[(long)z * p.sCb + row * p.ldcb + col] = f2b(e);
        } else if constexpr (EPI == 6) {
          p.Cb[row * 768 + col] = f2b(v + p.bias[col & 63]);
        } else if constexpr (EPI == 9) {
          p.Cb[(long)z * p.sCb + row * p.ldcb + col] = f2b(v);
        } else {  // EPI == 8: relu -> bf16
          p.Cb[(long)z * p.sCb + row * p.ldcb + col] = f2b(fmaxf(v, 0.f));
        }
      }
    }
  }
}

// ---------------------------------------------------------------------------
// Small kernels
// ---------------------------------------------------------------------------
__global__ void k_prep(const float* Gamma, const float* U1, const float* U2,
                       const float* back_b, const float* fore_b,
                       float* lhs, float* u1u2, float* biasBig) {
  int o = threadIdx.x;
  if (o < 64) {
    const float cx[3][3] = {{1.f, 0.86602540378443871f, 0.5f},
                            {1.f, 6.123233995736766e-17f, -1.f},
                            {1.f, -0.86602540378443871f, 0.5f}};
    for (int k = 0; k < 3; ++k)
      for (int i = 0; i < 3; ++i) {
        float s = 0;
        for (int j = 0; j < 3; ++j) s += Gamma[(j * 3 + i) * 64 + o] * cx[j][k];
        lhs[(k * 3 + i) * 64 + o] = s;
      }
    float s = 0;
    for (int g = 0; g < 64; ++g) s += U1[o * 64 + g] * U2[g];
    u1u2[o] = s;
    for (int t = 0; t < 12; ++t) {
      biasBig[o * 12 + t] = back_b[o];
      biasBig[768 + o * 12 + t] = fore_b[o];
    }
  }
}

__global__ void k_convert(const float* W_heads, const float* W_out, const float* time_w,
                          const float* back_w, const float* fore_w, const float* xg,
                          u16* WcatT, u16* WoutT, u16* WtBig, u16* WbfBig, u16* xcolT) {
  const int N1 = 589824, NT = 589824, NBF = 1179648, N5 = 786432;
  const int TOT = 2 * N1 + NT + NBF + N5;
  for (int o = blockIdx.x * 256 + threadIdx.x; o < TOT; o += gridDim.x * 256) {
    if (o < N1) {
      int dcol = o / 768, kk = o % 768;
      int hd = dcol / 384, d = dcol % 384;
      WcatT[o] = f2b(W_heads[((long)hd * 768 + kk) * 384 + d]);
    } else if (o < 2 * N1) {
      int o2 = o - N1; int dcol = o2 / 768, kk = o2 % 768;
      WoutT[o2] = f2b(W_out[kk * 768 + dcol]);
    } else if (o < 2 * N1 + NT) {
      // WtBig[t*64+ft][fc*12+tau] = time_w[ft][fc][tau-t+1] (0 outside taps)
      int o3 = o - 2 * N1; int col = o3 / 768, kk = o3 % 768;
      int t = col >> 6, ft = col & 63, fc = kk / 12, tau = kk % 12;
      int r = tau - t + 1;
      WtBig[o3] = f2b((r >= 0 && r < 3) ? time_w[ft * 192 + fc * 3 + r] : 0.f);
    } else if (o < 2 * N1 + NT + NBF) {
      // WbfBig[half*768 + c*12+t][fc*12+tau] = (back|fore)_w[c][fc][tau-t+1]
      int o4 = o - 2 * N1 - NT; int col = o4 / 768, kk = o4 % 768;
      int rem = (col < 768) ? col : col - 768;
      int c = rem / 12, tt = rem % 12;
      int fc = kk / 12, tau = kk % 12; int r = tau - tt + 1;
      const float* wsrc = (col < 768) ? back_w : fore_w;
      WbfBig[o4] = f2b((r >= 0 && r < 3) ? wsrc[c * 192 + fc * 3 + r] : 0.f);
    } else {
      int o5 = o - 2 * N1 - NT - NBF; int c = o5 / 2048, n = o5 % 2048;
      float v = 0.f;
      if (c < 288) {
        int b = c / 36, r2 = c % 36, i = r2 / 12, t = r2 % 12;
        v = xg[(long)(b * 2048 + n) * 36 + i * 12 + t];
      }
      xcolT[o5] = f2b(v);
    }
  }
}

// chebT[k][m][n] = bf16(cheb[k][n][m])
__global__ void k_chebT(const float* cheb, u16* chebT) {
  __shared__ float ts[32][33];
  int n0 = blockIdx.x * 32, m0 = blockIdx.y * 32, k = blockIdx.z;
  int c = threadIdx.x & 31, rq = threadIdx.x >> 5;  // rq 0..7
  const long base = (long)k * 2048 * 2048;
  for (int q = 0; q < 4; ++q) {
    int n = n0 + rq + q * 8;
    ts[rq + q * 8][c] = cheb[base + (long)n * 2048 + m0 + c];
  }
  __syncthreads();
  for (int q = 0; q < 4; ++q) {
    int m = m0 + rq + q * 8;
    chebT[base + (long)m * 2048 + n0 + c] = f2b(ts[c][rq + q * 8]);
  }
}

// h[bn][o*12+t] = bf16(relu(0.5 * sum_{k,i,ch} C1p[k*4+ch][n][b*36+i*12+t] * lhs[k][i][o]))
__global__ __launch_bounds__(256) void k_h(const u16* C1, const float* lhs, u16* h) {
  int bn = blockIdx.x; int b = bn >> 11, n = bn & 2047;
  int tid = threadIdx.x;
  __shared__ float c1s[108], ls[576];
  if (tid < 108) {
    int kk = tid / 12, t = tid % 12; int k = kk / 3, i = kk % 3;
    float s = 0;
#pragma unroll
    for (int ch = 0; ch < 4; ++ch)
      s += b2f(C1[((long)(k * 4 + ch) * 2048 + n) * 384 + b * 36 + i * 12 + t]);
    c1s[tid] = s;
  }
  for (int s = tid; s < 576; s += 256) ls[s] = lhs[s];
  __syncthreads();
  for (int q = 0; q < 3; ++q) {
    int idx = tid + q * 256; int o = idx / 12, t = idx % 12;
    float s = 0;
#pragma unroll
    for (int kk = 0; kk < 9; ++kk) s += c1s[kk * 12 + t] * ls[kk * 64 + o];
    s *= 0.5f;
    if (s < 0.f) s = 0.f;
    h[(long)bn * 768 + idx] = f2b(s);
  }
}

// f,g from WhT[b][dOff+d][i], a-slices
__global__ __launch_bounds__(256) void k_fg(const u16* WhT, int dOff, int Dlen,
                                            const float* aF, const float* aG,
                                            float* fOut, float* gOut) {
  int b = blockIdx.y;
  int i = blockIdx.x * 256 + threadIdx.x;
  __shared__ float af[768], ag[768];
  for (int s = threadIdx.x; s < Dlen; s += 256) { af[s] = aF[s]; ag[s] = aG[s]; }
  __syncthreads();
  const u16* wp = WhT + ((long)b * 768 + dOff) * 2048 + i;
  float fs = 0, gs = 0;
  for (int d = 0; d < Dlen; ++d) {
    float w = b2f(wp[(long)d * 2048]);
    fs += w * af[d]; gs += w * ag[d];
  }
  fOut[b * 2048 + i] = fs;
  gOut[b * 2048 + i] = gs;
}

// rdenom[b][j] = 1 / sum_i q(f_i + g_j)
__global__ __launch_bounds__(256) void k_denom(const float* f, const float* g, float* rd) {
  int b = blockIdx.y;
  int jl = threadIdx.x & 63, ch = threadIdx.x >> 6;
  int j = blockIdx.x * 64 + jl;
  __shared__ float fl[2048];
  __shared__ float red[256];
  for (int s = threadIdx.x; s < 2048; s += 256) fl[s] = f[b * 2048 + s];
  __syncthreads();
  float gj = g[b * 2048 + j];
  float acc = 0;
  for (int i = ch * 512; i < ch * 512 + 512; ++i) acc += qfun(fl[i] + gj);
  red[threadIdx.x] = acc;
  __syncthreads();
  if (ch == 0) {
    float s = red[jl] + red[jl + 64] + red[jl + 128] + red[jl + 192];
    rd[b * 2048 + j] = 1.f / s;
  }
}

// P[b][i][j] = bf16(q(f_i+g_j) * rdenom_j)
__global__ __launch_bounds__(256) void k_P(const float* f, const float* g,
                                           const float* rd, u16* P) {
  int j = blockIdx.x * 256 + threadIdx.x;
  int i0 = blockIdx.y * 16;
  int b = blockIdx.z;
  __shared__ float fl[16];
  if (threadIdx.x < 16) fl[threadIdx.x] = f[b * 2048 + i0 + threadIdx.x];
  __syncthreads();
  float gj = g[b * 2048 + j], rj = rd[b * 2048 + j];
  u16* Pp = P + ((long)b * 2048 + i0) * 2048 + j;
#pragma unroll
  for (int ii = 0; ii < 16; ++ii) Pp[(long)ii * 2048] = f2b(qfun(fl[ii] + gj) * rj);
}

// lhs_t[b][t][n], rhs_t[b][n][t] from tc_s[bn][t][f] (bf16)
__global__ void k_temporal(const u16* tc, const float* u1u2, const float* U3g,
                           float* lhs_t, float* rhs_t) {
  __shared__ float uu[64], u3[64];
  int tid = threadIdx.x;
  if (tid < 64) { uu[tid] = u1u2[tid]; u3[tid] = U3g[tid]; }
  __syncthreads();
  int gid = blockIdx.x * 256 + tid;  // < 196608
  const u16* p = tc + (long)gid * 64;
  float s1 = 0, s2 = 0;
#pragma unroll
  for (int c = 0; c < 8; ++c) {
    u16x8 vv = *(const u16x8*)(p + c * 8);
#pragma unroll
    for (int j = 0; j < 8; ++j) {
      float v = b2f(vv[j]);
      s1 += v * uu[c * 8 + j]; s2 += v * u3[c * 8 + j];
    }
  }
  int t = gid % 12; long bn = gid / 12;
  int b = (int)(bn >> 11);
  lhs_t[((long)b * 12 + t) * 2048 + (int)(bn & 2047)] = s1;
  rhs_t[gid] = s2;
}

__global__ void k_prod(const float* lhs_t, const float* rhs_t, float* prod) {
  int bi = blockIdx.x;  // < 1152
  int b = bi / 144; int r = bi % 144; int s = r / 12; int u = r % 12;
  int tid = threadIdx.x;
  float acc = 0;
  const float* lp = lhs_t + ((long)b * 12 + s) * 2048;
  const float* rp = rhs_t + (long)b * 2048 * 12 + u;
  for (int n = tid; n < 2048; n += 256) acc += lp[n] * rp[n * 12];
  __shared__ float red[256];
  red[tid] = acc; __syncthreads();
  for (int st = 128; st > 0; st >>= 1) {
    if (tid < st) red[tid] += red[tid + st];
    __syncthreads();
  }
  if (tid == 0) prod[bi] = red[0];
}

__global__ void k_E(const float* prod, const float* be, const float* Ve, float* E) {
  int b = blockIdx.x; int tid = threadIdx.x;
  __shared__ float S0[144], E1[144], mx[12], dn[12];
  if (tid < 144) {
    float v = prod[b * 144 + tid] + be[tid];
    S0[tid] = 1.f / (1.f + __expf(-v));
  }
  __syncthreads();
  if (tid < 144) {
    int i = tid / 12, t = tid % 12;
    float a = 0;
    for (int s = 0; s < 12; ++s) a += Ve[i * 12 + s] * S0[s * 12 + t];
    E1[tid] = a;
  }
  __syncthreads();
  if (tid < 12) {
    float m = -1e30f;
    for (int i = 0; i < 12; ++i) m = fmaxf(m, E1[i * 12 + tid]);
    float d = 0;
    for (int i = 0; i < 12; ++i) d += __expf(E1[i * 12 + tid] - m);
    mx[tid] = m; dn[tid] = d;
  }
  __syncthreads();
  if (tid < 144) {
    int t = tid % 12;
    E[b * 144 + tid] = __expf(E1[tid] - mx[t]) / dn[t];
  }
}

// tcn + residual + relu + layernorm(channel) -> resultB bf16 [bn][f*12+t]
__global__ __launch_bounds__(256) void k_res_ln(const u16* tc, const float* E,
                                                const float* xg, const float* res_w,
                                                const float* res_b, const float* ln_g,
                                                const float* ln_b, u16* result) {
  int bn = blockIdx.x; int b = bn >> 11;
  int tid = threadIdx.x;
  __shared__ float tcb[768], Eb[144], xl[36], rw[192], rb[64], lg[64], lb[64], zl[768], mu[12], rs[12];
  for (int s = tid; s < 768; s += 256) tcb[s] = b2f(tc[(long)bn * 768 + s]);
  if (tid < 144) Eb[tid] = E[b * 144 + tid];
  if (tid < 36) xl[tid] = xg[(long)bn * 36 + tid];
  if (tid >= 64 && tid < 256) { int q = tid - 64; if (q < 192) rw[q] = res_w[q]; }
  if (tid < 64) { rb[tid] = res_b[tid]; lg[tid] = ln_g[tid]; lb[tid] = ln_b[tid]; }
  __syncthreads();
  float z[3];
#pragma unroll
  for (int q = 0; q < 3; ++q) {
    int idx = tid + q * 256; int f = idx / 12, s = idx % 12;
    float tcn = 0;
#pragma unroll
    for (int t = 0; t < 12; ++t) tcn += tcb[t * 64 + f] * Eb[t * 12 + s];
    float xr = rb[f];
#pragma unroll
    for (int i = 0; i < 3; ++i) xr += rw[f * 3 + i] * xl[i * 12 + s];
    float v = xr + tcn;
    v = v > 0.f ? v : 0.f;
    z[q] = v; zl[idx] = v;
  }
  __syncthreads();
  if (tid < 12) {
    float m = 0, m2 = 0;
    for (int f = 0; f < 64; ++f) { float v = zl[f * 12 + tid]; m += v; m2 += v * v; }
    m *= (1.f / 64.f); m2 *= (1.f / 64.f);
    mu[tid] = m;
    float var = m2 - m * m;
    rs[tid] = rsqrtf((var > 0.f ? var : 0.f) + 1e-5f);
  }
  __syncthreads();
#pragma unroll
  for (int q = 0; q < 3; ++q) {
    int idx = tid + q * 256; int f = idx / 12, s = idx % 12;
    result[(long)bn * 768 + idx] = f2b((z[q] - mu[s]) * rs[s] * lg[f] + lb[f]);
  }
}

__global__ void k_sentinel(float* out, long n) {
  long i = (long)blockIdx.x * 256 + threadIdx.x;
  if (i < n) out[i] = 12345.0f;
}

// ---------------------------------------------------------------------------
// Launcher
// ---------------------------------------------------------------------------
extern "C" void kernel_launch(void* const* d_in, const int* in_sizes, int n_in,
                              void* d_out, int out_size, void* d_ws, size_t ws_size,
                              hipStream_t stream) {
  (void)in_sizes; (void)n_in;
  const float* x       = (const float*)d_in[0];
  const float* cheb    = (const float*)d_in[1];
  const float* Gamma   = (const float*)d_in[2];
  const float* W_heads = (const float*)d_in[3];
  const float* a_heads = (const float*)d_in[4];
  const float* W_out   = (const float*)d_in[5];
  const float* a_out   = (const float*)d_in[6];
  const float* U1      = (const float*)d_in[7];
  const float* U2      = (const float*)d_in[8];
  const float* U3      = (const float*)d_in[9];
  const float* be      = (const float*)d_in[10];
  const float* Ve      = (const float*)d_in[11];
  const float* time_w  = (const float*)d_in[12];
  const float* time_b  = (const float*)d_in[13];
  const float* res_w   = (const float*)d_in[14];
  const float* res_b   = (const float*)d_in[15];
  const float* back_w  = (const float*)d_in[16];
  const float* back_b  = (const float*)d_in[17];
  const float* fore_w  = (const float*)d_in[18];
  const float* fore_b  = (const float*)d_in[19];
  const float* ln_g    = (const float*)d_in[20];
  const float* ln_b    = (const float*)d_in[21];
  float* out = (float*)d_out;

  if (ws_size < WS_NEEDED) {  // distinctive failure signature (absmax ~12345)
    k_sentinel<<<(out_size + 255) / 256, 256, 0, stream>>>(out, out_size);
    return;
  }

  char* ws = (char*)d_ws;
  float* lhs     = (float*)(ws + OFF_LHS);
  float* u1u2    = (float*)(ws + OFF_U1U2);
  float* biasBig = (float*)(ws + OFF_BIASBIG);
  float* fH      = (float*)(ws + OFF_FH);
  float* gH      = (float*)(ws + OFF_GH);
  float* rdH     = (float*)(ws + OFF_RDH);
  float* fO      = (float*)(ws + OFF_FO);
  float* gO      = (float*)(ws + OFF_GO);
  float* rdO     = (float*)(ws + OFF_RDO);
  float* lhs_t   = (float*)(ws + OFF_LHST);
  float* rhs_t   = (float*)(ws + OFF_RHST);
  float* prod    = (float*)(ws + OFF_PROD);
  float* Ebuf    = (float*)(ws + OFF_E);
  u16* WcatT   = (u16*)(ws + OFF_WCATT);
  u16* WoutT   = (u16*)(ws + OFF_WOUTT);
  u16* WtBig   = (u16*)(ws + OFF_WTBIG);
  u16* WbfBig  = (u16*)(ws + OFF_WBFBIG);
  u16* xcolT   = (u16*)(ws + OFF_XCOLT);
  u16* chebT   = (u16*)(ws + OFF_CHEBT);
  u16* C1      = (u16*)(ws + OFF_C1);
  u16* hbuf    = (u16*)(ws + OFF_H);
  u16* Pbuf    = (u16*)(ws + OFF_P);
  u16* WhcatT  = (u16*)(ws + OFF_WHCATT);
  u16* hcat    = (u16*)(ws + OFF_HCAT);
  u16* WhoutT  = (u16*)(ws + OFF_WHOUTT);
  u16* gcnB    = (u16*)(ws + OFF_GCNB);
  u16* tcsB    = (u16*)(ws + OFF_TCS);
  u16* resultB = (u16*)(ws + OFF_RESULTB);

  // --- prep ---
  k_prep<<<1, 64, 0, stream>>>(Gamma, U1, U2, back_b, fore_b, lhs, u1u2, biasBig);
  k_convert<<<2048, 256, 0, stream>>>(W_heads, W_out, time_w, back_w, fore_w, x,
                                      WcatT, WoutT, WtBig, WbfBig, xcolT);
  k_chebT<<<dim3(64, 64, 3), 256, 0, stream>>>(cheb, chebT);

  // --- G1: C1 partials (bf16) = chebT @ xcolT^T, split-K x4 (z=k*4+ch, K=512) ---
  {
    GemmP p{}; p.A = chebT; p.BT = xcolT; p.sA = 2048L * 2048; p.sB = 0;
    p.K = 512; p.lda = 2048; p.ldb = 2048; p.splitK = 1; p.swz = 1;
    p.Cb = C1; p.sCb = 2048L * 384; p.ldcb = 384;
    gemm_bf16<9, 1><<<dim3(3, 16, 12), 256, 0, stream>>>(p);
  }
  k_h<<<16384, 256, 0, stream>>>(C1, lhs, hbuf);

  // --- G2: Wh_cat (LDS-transposed out) ---
  {
    GemmP p{}; p.A = hbuf; p.BT = WcatT; p.sA = 0; p.sB = 0;
    p.K = 768; p.lda = 768; p.ldb = 768; p.swz = 1;
    p.CbT = WhcatT; p.ldcT = 2048; p.sCbT = 768L * 2048;
    gemm_bf16<1, 2><<<dim3(3, 128, 1), 256, 0, stream>>>(p);
  }
  // f,g per head
  k_fg<<<dim3(8, 8), 256, 0, stream>>>(WhcatT, 0, 384, a_heads, a_heads + 384, fH, gH);
  k_fg<<<dim3(8, 8), 256, 0, stream>>>(WhcatT, 384, 384, a_heads + 768, a_heads + 1152,
                                       fH + 16384, gH + 16384);
  // heads: denom, P, att GEMM (elu -> hcat half)
  for (int hd = 0; hd < 2; ++hd) {
    const float* f = fH + hd * 16384; const float* g = gH + hd * 16384;
    float* rd = rdH + hd * 16384;
    k_denom<<<dim3(32, 8), 256, 0, stream>>>(f, g, rd);
    k_P<<<dim3(8, 128, 8), 256, 0, stream>>>(f, g, rd, Pbuf);
    GemmP p{}; p.A = Pbuf; p.BT = WhcatT + (long)hd * 384 * 2048;
    p.sA = 2048L * 2048; p.sB = 768L * 2048;
    p.K = 2048; p.lda = 2048; p.ldb = 2048; p.swz = 1;
    p.Cb = hcat + hd * 384; p.sCb = 2048L * 768; p.ldcb = 768;
    gemm_bf16<2, 1><<<dim3(3, 16, 8), 256, 0, stream>>>(p);
  }

  // --- G5: Wh_out (LDS-transposed out) ---
  {
    GemmP p{}; p.A = hcat; p.BT = WoutT; p.sA = 0; p.sB = 0;
    p.K = 768; p.lda = 768; p.ldb = 768; p.swz = 1;
    p.CbT = WhoutT; p.ldcT = 2048; p.sCbT = 768L * 2048;
    gemm_bf16<1, 2><<<dim3(3, 128, 1), 256, 0, stream>>>(p);
  }
  k_fg<<<dim3(8, 8), 256, 0, stream>>>(WhoutT, 0, 768, a_out, a_out + 768, fO, gO);
  k_denom<<<dim3(32, 8), 256, 0, stream>>>(fO, gO, rdO);
  k_P<<<dim3(8, 128, 8), 256, 0, stream>>>(fO, gO, rdO, Pbuf);
  // --- G6: out attention, relu -> gcnB bf16 ---
  {
    GemmP p{}; p.A = Pbuf; p.BT = WhoutT; p.sA = 2048L * 2048; p.sB = 768L * 2048;
    p.K = 2048; p.lda = 2048; p.ldb = 2048; p.swz = 1;
    p.Cb = gcnB; p.sCb = 2048L * 768; p.ldcb = 768;
    gemm_bf16<8, 2><<<dim3(3, 16, 8), 256, 0, stream>>>(p);
  }

  // --- temporal conv as dense GEMM (tap-expanded weights) -> tcsB bf16 ---
  {
    GemmP p{}; p.A = gcnB; p.BT = WtBig; p.sA = 0; p.sB = 0;
    p.K = 768; p.lda = 768; p.ldb = 768; p.swz = 1;
    p.Cb = tcsB; p.bias = time_b;
    gemm_bf16<6, 2><<<dim3(3, 128, 1), 256, 0, stream>>>(p);
  }

  // --- temporal attention ---
  k_temporal<<<768, 256, 0, stream>>>(tcsB, u1u2, U3, lhs_t, rhs_t);
  k_prod<<<1152, 256, 0, stream>>>(lhs_t, rhs_t, prod);
  k_E<<<8, 256, 0, stream>>>(prod, be, Ve, Ebuf);

  // --- residual + LN -> bf16 ---
  k_res_ln<<<16384, 256, 0, stream>>>(tcsB, Ebuf, x, res_w, res_b, ln_g, ln_b, resultB);

  // --- backcast / forecast convs as one dense GEMM, vectorized row writes ---
  {
    GemmP p{}; p.A = resultB; p.BT = WbfBig; p.sA = 0; p.sB = 0;
    p.K = 768; p.lda = 768; p.ldb = 768; p.swz = 1;
    p.bias = biasBig; p.outB = out; p.outF = out + 12582912L;
    gemm_bf16<7, 2><<<dim3(6, 128, 1), 256, 0, stream>>>(p);
  }
}

// Round 20
// 702.803 us; speedup vs baseline: 2.1605x; 1.0001x over previous
//
#include <hip/hip_runtime.h>

// ============================================================================
// ASTGCN block for MI355X. Dims: B=8, N=2048, FIN=3, T=12, K=3, FC=FT=64.
// bf16 MFMA (16x16x32) for all big GEMMs, fp32 elsewhere.
// GEMM convention: C[m,n] = sum_k A[m,k] * BT[n,k]; A,BT bf16 K-contiguous.
// R10: 3-buffer single-barrier depth-2 K-loop (best general GEMM, 698us).
// R20: surgical composition of individually-proven pieces:
//      - gemm_afb (R14, lb(256,2), 92 VGPR no-spill) for G2 + final GEMM
//        (final GEMM measured 71 -> 65.6us in R14's counters)
//      - WcatT/WbfBig emitted in B-frag layout (R14 k_convert, proven)
//      - k_h / k_res_ln keep R10 one-row-per-block structure; only the store
//        ADDRESS is remapped to A-frag layout (same scalar-store count).
// ============================================================================

typedef unsigned short u16;
typedef __bf16 bf16x8 __attribute__((ext_vector_type(8)));
typedef float f32x4 __attribute__((ext_vector_type(4)));
typedef u16 u16x8 __attribute__((ext_vector_type(8)));

__device__ __forceinline__ u16 f2b(float f) {
  union { float f; unsigned u; } v; v.f = f;
  unsigned u = v.u;
  u = u + 0x7FFFu + ((u >> 16) & 1u);   // RNE
  return (u16)(u >> 16);
}
__device__ __forceinline__ float b2f(u16 h) {
  union { unsigned u; float f; } v; v.u = ((unsigned)h) << 16; return v.f;
}
// q(x) = exp(sigmoid(leaky_relu(x, 0.1)))
__device__ __forceinline__ float qfun(float x) {
  float e = x > 0.f ? x : 0.1f * x;
  float s = __builtin_amdgcn_rcpf(1.f + __expf(-e));
  return __expf(s);
}

template <int N> __device__ __forceinline__ void waitvm() {
  if constexpr (N == 0)      asm volatile("s_waitcnt vmcnt(0)" ::: "memory");
  else if constexpr (N == 4) asm volatile("s_waitcnt vmcnt(4)" ::: "memory");
  else if constexpr (N == 6) asm volatile("s_waitcnt vmcnt(6)" ::: "memory");
  else                       asm volatile("s_waitcnt vmcnt(16)" ::: "memory");
}
__device__ __forceinline__ void rawbar() { asm volatile("s_barrier" ::: "memory"); }

#define GLOAD16(g, l) __builtin_amdgcn_global_load_lds( \
    (__attribute__((address_space(1))) void*)(g),       \
    (__attribute__((address_space(3))) void*)(l), 16, 0, 0)

// ---------------------------------------------------------------------------
// Workspace layout (byte offsets). High water: 0x8D40000 (= 148 MB).
// ---------------------------------------------------------------------------
constexpr size_t OFF_LHS     = 0x0;        // f32 [3][3][64]
constexpr size_t OFF_U1U2    = 0x1000;     // f32 [64]
constexpr size_t OFF_BIASBIG = 0x1100;     // f32 [1536]
constexpr size_t OFF_FH      = 0x3000;     // f32 [2][8][2048]
constexpr size_t OFF_GH      = 0x23000;
constexpr size_t OFF_RDH     = 0x43000;
constexpr size_t OFF_FO      = 0x63000;    // f32 [8][2048]
constexpr size_t OFF_GO      = 0x73000;
constexpr size_t OFF_RDO     = 0x83000;
constexpr size_t OFF_LHST    = 0x93000;    // f32 [8][12][2048]
constexpr size_t OFF_RHST    = 0x153000;   // f32 [8][2048][12]
constexpr size_t OFF_PROD    = 0x213000;   // f32 [8][12][12]
constexpr size_t OFF_E       = 0x215000;   // f32 [8][12][12]
constexpr size_t OFF_WCATT   = 0x220000;   // bf16 [768][768] B-FRAG layout
constexpr size_t OFF_WOUTT   = 0x340000;   // bf16 [768][768] K-contiguous
constexpr size_t OFF_WTBIG   = 0x460000;   // bf16 [768][768] tap-expanded, K-contig
constexpr size_t OFF_XCOLT   = 0x580000;   // bf16 [384][2048] (rows 288.. zero)
constexpr size_t OFF_CHEBT   = 0x700000;   // bf16 [3][2048][2048]  -> 0x1F00000
constexpr size_t OFF_C1      = 0x1F00000;  // bf16 [12][2048][384]  -> 0x3100000
constexpr size_t OFF_H       = 0x4300000;  // bf16 A-frag [1024][24][512] -> 0x5B00000
constexpr size_t OFF_P       = 0x700000;   // bf16 [8][2048][2048] (cheb/C1/h dead) -> 0x4700000
constexpr size_t OFF_WHCATT  = 0x5B00000;  // bf16 [8][768][2048]   -> 0x7300000
constexpr size_t OFF_HCAT    = 0x7300000;  // bf16 [16384][768]     -> 0x8B00000
constexpr size_t OFF_WHOUTT  = 0x5B00000;  // reuse (WhcatT dead after G4)
constexpr size_t OFF_GCNB    = 0x7300000;  // bf16 [16384][768] (hcat dead) -> 0x8B00000
constexpr size_t OFF_WBFBIG  = 0x8B00000;  // bf16 [1536][768] B-FRAG layout -> 0x8D40000
constexpr size_t OFF_TCS     = 0x700000;   // bf16 [16384][12][64] (P dead) -> 0x1F00000
constexpr size_t OFF_RESULTB = 0x3700000;  // bf16 A-frag [1024][24][512] -> 0x4F00000
constexpr size_t WS_NEEDED   = 0x8D40000;

// ---------------------------------------------------------------------------
struct GemmP {
  const u16* A; const u16* BT;
  long sA, sB;            // per-z batch strides (elements)
  int K, lda, ldb;
  int swz, splitK;
  float* Cf; long sCf; int ldcf;
  u16* Cb;  long sCb; int ldcb;
  u16* CbT; int ldcT; long sCbT;
  const float* bias;
  float* outB; float* outF;
};

// ---------------------------------------------------------------------------
// gemm_afb: barrier-free LDS-free GEMM. Block 128x128 (2x2 waves of 64x64).
// Both operands in fragment layout: frag f at base + (tile16*KT + kt)*512 +
// lane*8 (lane = (r&15) + 16*koct). Triple-buffered register sets,
// vmcnt(16)-counted (2 steps in flight). R14-proven config: lb(256,2).
// EPI: 1 bf16-LDS-transposed   7 final +biasBig -> f32x4 rows
// ---------------------------------------------------------------------------
template <int EPI>
__global__ __launch_bounds__(256, 2) void gemm_afb(GemmP p) {
  __shared__ u16 smem[(EPI == 1) ? 17408 : 16];
  const int tid = threadIdx.x, lane = tid & 63, wid = tid >> 6;
  const int wm = wid >> 1, wn = wid & 1;
  const int z = blockIdx.z;
  int nT = gridDim.x;
  int nwg = nT * gridDim.y;
  int lin = blockIdx.x + nT * blockIdx.y;
  int q8 = nwg >> 3;
  int sw = (lin & 7) * q8 + (lin >> 3);   // XCD-chunked bijection (nwg%8==0)
  long m0 = (long)(sw / nT) * 128;
  long n0 = (long)(sw % nT) * 128;

  const int KT = p.K >> 5;
  const long mstr = (long)KT * 512;
  const u16* aPf = p.A + (long)z * p.sA + ((m0 >> 4) + wm * 4) * mstr + lane * 8;
  const u16* bPf = p.BT + ((n0 >> 4) + wn * 4) * mstr + lane * 8;

  f32x4 acc[4][4];
  f32x4 zero = {0.f, 0.f, 0.f, 0.f};
#pragma unroll
  for (int i = 0; i < 4; ++i)
#pragma unroll
    for (int j = 0; j < 4; ++j) acc[i][j] = zero;

  bf16x8 a0[4], b0[4], a1[4], b1[4], a2[4], b2[4];
  auto LOAD = [&](bf16x8 (&av)[4], bf16x8 (&bv)[4], int s) {
#pragma unroll
    for (int mi = 0; mi < 4; ++mi) av[mi] = *(const bf16x8*)(aPf + mi * mstr + (long)s * 512);
#pragma unroll
    for (int ni = 0; ni < 4; ++ni) bv[ni] = *(const bf16x8*)(bPf + ni * mstr + (long)s * 512);
  };
  auto MM = [&](bf16x8 (&av)[4], bf16x8 (&bv)[4]) {
#pragma unroll
    for (int mi = 0; mi < 4; ++mi)
#pragma unroll
      for (int ni = 0; ni < 4; ++ni)
        acc[mi][ni] = __builtin_amdgcn_mfma_f32_16x16x32_bf16(av[mi], bv[ni], acc[mi][ni], 0, 0, 0);
  };

  LOAD(a0, b0, 0);
  if (KT > 1) LOAD(a1, b1, 1);
  if (KT > 2) LOAD(a2, b2, 2);
  for (int i = 0; i < KT; i += 3) {
    waitvm<16>(); MM(a0, b0);
    if (i + 3 < KT) LOAD(a0, b0, i + 3);
    if (i + 1 < KT) {
      waitvm<16>(); MM(a1, b1);
      if (i + 4 < KT) LOAD(a1, b1, i + 4);
    }
    if (i + 2 < KT) {
      waitvm<16>(); MM(a2, b2);
      if (i + 5 < KT) LOAD(a2, b2, i + 5);
    }
  }

  if constexpr (EPI == 1) {
    // Stage bf16 tile transposed in LDS, coalesced column writes.
    __syncthreads();
#pragma unroll
    for (int mi = 0; mi < 4; ++mi)
#pragma unroll
      for (int ni = 0; ni < 4; ++ni) {
        int cl = wn * 64 + ni * 16 + (lane & 15);
        int mlb = wm * 64 + mi * 16 + ((lane >> 4) << 2);
#pragma unroll
        for (int r = 0; r < 4; ++r)
          smem[cl * 136 + mlb + r] = f2b(acc[mi][ni][r]);
      }
    __syncthreads();
    int c = tid >> 1, half = tid & 1;
    long bat = m0 >> 11;                  // 2048-row batches
    u16* dst = p.CbT + bat * p.sCbT + (long)(n0 + c) * p.ldcT + (m0 & 2047) + half * 64;
    const u16* srcp = &smem[c * 136 + half * 64];
#pragma unroll
    for (int j = 0; j < 64; j += 8)
      *(u16x8*)(dst + j) = *(const u16x8*)(srcp + j);
    return;
  }

  if constexpr (EPI == 7) {
    // In-register 4x4 transpose -> dwordx4 row stores.
    const int q = lane >> 4, g4 = (lane >> 2) & 3, j = lane & 3;
    const int back = ((int)n0 < 768);
    float* obase = (back ? p.outB : p.outF) - (back ? 0 : 768);
#pragma unroll
    for (int mi = 0; mi < 4; ++mi) {
      long rb0 = m0 + wm * 64 + mi * 16 + q * 4;
#pragma unroll
      for (int ni = 0; ni < 4; ++ni) {
        int cb = (int)n0 + wn * 64 + ni * 16 + g4 * 4;
        f32x4 v = acc[mi][ni];
        float bsv = p.bias[cb + j];
        v[0] += bsv; v[1] += bsv; v[2] += bsv; v[3] += bsv;
#pragma unroll
        for (int d = 1; d <= 2; d <<= 1) {
          f32x4 t;
#pragma unroll
          for (int b = 0; b < 4; ++b) t[b] = __shfl_xor(v[b ^ d], d, 64);
#pragma unroll
          for (int b = 0; b < 4; ++b) if ((lane ^ b) & d) v[b] = t[b];
        }
        *(f32x4*)(obase + (rb0 + j) * 768 + cb) = v;
      }
    }
    return;
  }
}

// ---------------------------------------------------------------------------
// Generic MFMA GEMM (R10): 3-buffer single-barrier depth-2 pipeline.
// EPI: 1 bf16-LDS-transposed-per-2048batch   2 elu->bf16
//      6 time-conv +time_b[col&63] -> bf16   8 relu->bf16   9 plain bf16
// ---------------------------------------------------------------------------
template <int EPI, int WN>
__global__ __launch_bounds__(256, (WN == 1 ? 3 : 2)) void gemm_bf16(GemmP p) {
  constexpr int BUFU  = (WN == 1) ? 8192 : 12288;   // u16 per K-step buffer
  constexpr int SMEMU = 3 * BUFU;                   // 3 buffers (EPI1 17408 fits)
  constexpr int LPW   = (WN == 1) ? 4 : 6;          // loads per wave per stage
  __shared__ u16 smem[SMEMU];
  const int tid  = threadIdx.x;
  const int lane = tid & 63;
  const int wid  = tid >> 6;
  const int wm = wid >> 1, wn = wid & 1;
  const int z = blockIdx.z;

  long m0, n0;
  if (p.swz) {
    int nT = gridDim.x;
    int nwg = nT * gridDim.y;
    int lin = blockIdx.x + nT * blockIdx.y;
    int q = nwg >> 3;                       // nwg % 8 == 0 guaranteed by caller
    int swz = (lin & 7) * q + (lin >> 3);   // XCD-chunked bijection
    m0 = (long)(swz / nT) * 128;
    n0 = (long)(swz % nT) * (128 * WN);
  } else {
    m0 = (long)blockIdx.y * 128;
    n0 = (long)blockIdx.x * (128 * WN);
  }

  const int K = p.K;
  long aBase, bBase;
  if (p.splitK) {
    int kz = z >> 2, ch = z & 3;
    aBase = (long)kz * p.sA + (long)ch * 512;
    bBase = (long)ch * 512;
  } else {
    aBase = (long)z * p.sA;
    bBase = (long)z * p.sB;
  }
  const u16* Ab = p.A + aBase + m0 * p.lda;
  const u16* Bb = p.BT + bBase + n0 * p.ldb;

  const int sk = (((lane & 3) ^ ((lane >> 3) & 3))) * 8;
  const u16* aP0 = Ab + (long)(wid * 32 + (lane >> 2)) * p.lda + sk;
  const u16* aP1 = aP0 + (long)16 * p.lda;
  const u16* bP0 = Bb + (long)(wid * 32 * WN + (lane >> 2)) * p.ldb + sk;
  const u16* bP1 = bP0 + (long)16 * p.ldb;
  const u16* bP2 = bP0 + (long)32 * p.ldb;
  const u16* bP3 = bP0 + (long)48 * p.ldb;
  const int aslot = wid * 1024;
  const int bslot = 4096 + wid * (WN == 1 ? 1024 : 2048);

  auto STAGE = [&](int s, int bi) {
    long ko = (long)s * 32;
    u16* base = smem + bi * BUFU;
    GLOAD16(aP0 + ko, base + aslot);
    GLOAD16(aP1 + ko, base + aslot + 512);
    GLOAD16(bP0 + ko, base + bslot);
    GLOAD16(bP1 + ko, base + bslot + 512);
    if constexpr (WN == 2) {
      GLOAD16(bP2 + ko, base + bslot + 1024);
      GLOAD16(bP3 + ko, base + bslot + 1536);
    }
  };

  f32x4 acc[4][4 * WN];
  f32x4 zero = {0.f, 0.f, 0.f, 0.f};
#pragma unroll
  for (int i = 0; i < 4; ++i)
#pragma unroll
    for (int j = 0; j < 4 * WN; ++j) acc[i][j] = zero;

  const int xorc = (lane >> 1) & 3;
  const int aoff = (wm * 64 + (lane & 15)) * 32 + ((lane >> 4) ^ xorc) * 8;
  const int boff = 4096 + (wn * 64 * WN + (lane & 15)) * 32 + ((lane >> 4) ^ xorc) * 8;

  const int nsteps = K >> 5;   // >= 2 at all call sites

  STAGE(0, 0);
  STAGE(1, 1);
  waitvm<LPW>();
  rawbar();

  int cur = 0;
  for (int i = 0; i < nsteps; ++i) {
    const u16* buf = smem + cur * BUFU;
    bf16x8 av[4], bv[4 * WN];
#pragma unroll
    for (int mi = 0; mi < 4; ++mi) av[mi] = *(const bf16x8*)&buf[aoff + mi * 512];
#pragma unroll
    for (int ni = 0; ni < 4 * WN; ++ni) bv[ni] = *(const bf16x8*)&buf[boff + ni * 512];
#pragma unroll
    for (int mi = 0; mi < 4; ++mi)
#pragma unroll
      for (int ni = 0; ni < 4 * WN; ++ni)
        acc[mi][ni] = __builtin_amdgcn_mfma_f32_16x16x32_bf16(av[mi], bv[ni], acc[mi][ni], 0, 0, 0);
    if (i + 1 < nsteps) {
      if (i + 2 < nsteps) {
        STAGE(i + 2, cur == 0 ? 2 : cur - 1);   // (cur+2)%3
        waitvm<LPW>();                          // stage i+1 landed
      } else {
        waitvm<0>();
      }
      rawbar();
    }
    cur = (cur == 2) ? 0 : cur + 1;
  }
  __syncthreads();  // drain before epilogue smem reuse (EPI1)

  if constexpr (EPI == 1) {
#pragma unroll
    for (int h = 0; h < 2; ++h) {
      if (h == 1) __syncthreads();
      if (WN == 1 || wn == h) {
#pragma unroll
        for (int mi = 0; mi < 4; ++mi)
#pragma unroll
          for (int ni = 0; ni < 4 * WN; ++ni) {
            int cl = (WN == 1 ? wn * 64 : 0) + ni * 16 + (lane & 15);
            int mlb = wm * 64 + mi * 16 + ((lane >> 4) << 2);
#pragma unroll
            for (int r = 0; r < 4; ++r)
              smem[cl * 136 + mlb + r] = f2b(acc[mi][ni][r]);
          }
      }
      __syncthreads();
      int c = tid >> 1, half = tid & 1;
      long bat = m0 >> 11;                  // 2048-row batches
      u16* dst = p.CbT + bat * p.sCbT + (long)(n0 + h * 128 + c) * p.ldcT +
                 (m0 & 2047) + half * 64;
      const u16* srcp = &smem[c * 136 + half * 64];
#pragma unroll
      for (int j = 0; j < 64; j += 8)
        *(u16x8*)(dst + j) = *(const u16x8*)(srcp + j);
      if (WN == 1) break;                   // WN=1 tile is only 128 cols
    }
    return;
  }

#pragma unroll
  for (int mi = 0; mi < 4; ++mi) {
    long rb0 = m0 + wm * 64 + mi * 16 + ((lane >> 4) << 2);
#pragma unroll
    for (int ni = 0; ni < 4 * WN; ++ni) {
      int col = (int)n0 + wn * 64 * WN + ni * 16 + (lane & 15);
#pragma unroll
      for (int r = 0; r < 4; ++r) {
        float v = acc[mi][ni][r];
        long row = rb0 + r;
        if constexpr (EPI == 2) {
          float e = v > 0.f ? v : expm1f(v);
          p.Cb[(long)z * p.sCb + row * p.ldcb + col] = f2b(e);
        } else if constexpr (EPI == 6) {
          p.Cb[row * 768 + col] = f2b(v + p.bias[col & 63]);
        } else if constexpr (EPI == 9) {
          p.Cb[(long)z * p.sCb + row * p.ldcb + col] = f2b(v);
        } else {  // EPI == 8: relu -> bf16
          p.Cb[(long)z * p.sCb + row * p.ldcb + col] = f2b(fmaxf(v, 0.f));
        }
      }
    }
  }
}

// ---------------------------------------------------------------------------
// Small kernels
// ---------------------------------------------------------------------------
__global__ void k_prep(const float* Gamma, const float* U1, const float* U2,
                       const float* back_b, const float* fore_b,
                       float* lhs, float* u1u2, float* biasBig) {
  int o = threadIdx.x;
  if (o < 64) {
    const float cx[3][3] = {{1.f, 0.86602540378443871f, 0.5f},
                            {1.f, 6.123233995736766e-17f, -1.f},
                            {1.f, -0.86602540378443871f, 0.5f}};
    for (int k = 0; k < 3; ++k)
      for (int i = 0; i < 3; ++i) {
        float s = 0;
        for (int j = 0; j < 3; ++j) s += Gamma[(j * 3 + i) * 64 + o] * cx[j][k];
        lhs[(k * 3 + i) * 64 + o] = s;
      }
    float s = 0;
    for (int g = 0; g < 64; ++g) s += U1[o * 64 + g] * U2[g];
    u1u2[o] = s;
    for (int t = 0; t < 12; ++t) {
      biasBig[o * 12 + t] = back_b[o];
      biasBig[768 + o * 12 + t] = fore_b[o];
    }
  }
}

__global__ void k_convert(const float* W_heads, const float* W_out, const float* time_w,
                          const float* back_w, const float* fore_w, const float* xg,
                          u16* WcatT, u16* WoutT, u16* WtBig, u16* WbfBig, u16* xcolT) {
  const int N1 = 589824, NT = 589824, NBF = 1179648, N5 = 786432;
  const int TOT = 2 * N1 + NT + NBF + N5;
  for (int o = blockIdx.x * 256 + threadIdx.x; o < TOT; o += gridDim.x * 256) {
    if (o < N1) {
      // WcatT in B-FRAG layout: frag f = nf*24+kt, slot ln*8+j.
      int f = o >> 9, s = o & 511;
      int ln = s >> 3, j = s & 7;
      int nf = f / 24, kt = f % 24;
      int dcol = nf * 16 + (ln & 15);
      int kk = kt * 32 + (ln >> 4) * 8 + j;
      int hd = dcol / 384, d = dcol % 384;
      WcatT[o] = f2b(W_heads[((long)hd * 768 + kk) * 384 + d]);
    } else if (o < 2 * N1) {
      int o2 = o - N1; int dcol = o2 / 768, kk = o2 % 768;
      WoutT[o2] = f2b(W_out[kk * 768 + dcol]);
    } else if (o < 2 * N1 + NT) {
      // WtBig[t*64+ft][fc*12+tau] K-contiguous (tap-expanded)
      int o3 = o - 2 * N1; int col = o3 / 768, kk = o3 % 768;
      int t = col >> 6, ft = col & 63, fc = kk / 12, tau = kk % 12;
      int r = tau - t + 1;
      WtBig[o3] = f2b((r >= 0 && r < 3) ? time_w[ft * 192 + fc * 3 + r] : 0.f);
    } else if (o < 2 * N1 + NT + NBF) {
      // WbfBig in B-FRAG layout (1536 cols, 96 nf tiles, 24 kt)
      int o4 = o - 2 * N1 - NT;
      int f = o4 >> 9, s = o4 & 511;
      int ln = s >> 3, j = s & 7;
      int nf = f / 24, kt = f % 24;
      int col = nf * 16 + (ln & 15);
      int kk = kt * 32 + (ln >> 4) * 8 + j;
      int rem = (col < 768) ? col : col - 768;
      int c = rem / 12, tt = rem % 12;
      int fc = kk / 12, tau = kk % 12; int r = tau - tt + 1;
      const float* wsrc = (col < 768) ? back_w : fore_w;
      WbfBig[o4] = f2b((r >= 0 && r < 3) ? wsrc[c * 192 + fc * 3 + r] : 0.f);
    } else {
      int o5 = o - 2 * N1 - NT - NBF; int c = o5 / 2048, n = o5 % 2048;
      float v = 0.f;
      if (c < 288) {
        int b = c / 36, r2 = c % 36, i = r2 / 12, t = r2 % 12;
        v = xg[(long)(b * 2048 + n) * 36 + i * 12 + t];
      }
      xcolT[o5] = f2b(v);
    }
  }
}

// chebT[k][m][n] = bf16(cheb[k][n][m])
__global__ void k_chebT(const float* cheb, u16* chebT) {
  __shared__ float ts[32][33];
  int n0 = blockIdx.x * 32, m0 = blockIdx.y * 32, k = blockIdx.z;
  int c = threadIdx.x & 31, rq = threadIdx.x >> 5;  // rq 0..7
  const long base = (long)k * 2048 * 2048;
  for (int q = 0; q < 4; ++q) {
    int n = n0 + rq + q * 8;
    ts[rq + q * 8][c] = cheb[base + (long)n * 2048 + m0 + c];
  }
  __syncthreads();
  for (int q = 0; q < 4; ++q) {
    int m = m0 + rq + q * 8;
    chebT[base + (long)m * 2048 + n0 + c] = f2b(ts[c][rq + q * 8]);
  }
}

// h in A-FRAG layout: row bn -> (mf=bn>>4, m=bn&15); col idx -> (kt,koct,j).
__global__ __launch_bounds__(256) void k_h(const u16* C1, const float* lhs, u16* h) {
  int bn = blockIdx.x; int b = bn >> 11, n = bn & 2047;
  int tid = threadIdx.x;
  __shared__ float c1s[108], ls[576];
  if (tid < 108) {
    int kk = tid / 12, t = tid % 12; int k = kk / 3, i = kk % 3;
    float s = 0;
#pragma unroll
    for (int ch = 0; ch < 4; ++ch)
      s += b2f(C1[((long)(k * 4 + ch) * 2048 + n) * 384 + b * 36 + i * 12 + t]);
    c1s[tid] = s;
  }
  for (int s = tid; s < 576; s += 256) ls[s] = lhs[s];
  __syncthreads();
  const int mf = bn >> 4, m = bn & 15;
  for (int q = 0; q < 3; ++q) {
    int idx = tid + q * 256; int o = idx / 12, t = idx % 12;
    float s = 0;
#pragma unroll
    for (int kk = 0; kk < 9; ++kk) s += c1s[kk * 12 + t] * ls[kk * 64 + o];
    s *= 0.5f;
    if (s < 0.f) s = 0.f;
    int kt = idx >> 5, koct = (idx >> 3) & 3, j = idx & 7;
    h[((long)mf * 24 + kt) * 512 + (m + 16 * koct) * 8 + j] = f2b(s);
  }
}

// f,g from WhT[b][dOff+d][i], a-slices
__global__ __launch_bounds__(256) void k_fg(const u16* WhT, int dOff, int Dlen,
                                            const float* aF, const float* aG,
                                            float* fOut, float* gOut) {
  int b = blockIdx.y;
  int i = blockIdx.x * 256 + threadIdx.x;
  __shared__ float af[768], ag[768];
  for (int s = threadIdx.x; s < Dlen; s += 256) { af[s] = aF[s]; ag[s] = aG[s]; }
  __syncthreads();
  const u16* wp = WhT + ((long)b * 768 + dOff) * 2048 + i;
  float fs = 0, gs = 0;
  for (int d = 0; d < Dlen; ++d) {
    float w = b2f(wp[(long)d * 2048]);
    fs += w * af[d]; gs += w * ag[d];
  }
  fOut[b * 2048 + i] = fs;
  gOut[b * 2048 + i] = gs;
}

// rdenom[b][j] = 1 / sum_i q(f_i + g_j)
__global__ __launch_bounds__(256) void k_denom(const float* f, const float* g, float* rd) {
  int b = blockIdx.y;
  int jl = threadIdx.x & 63, ch = threadIdx.x >> 6;
  int j = blockIdx.x * 64 + jl;
  __shared__ float fl[2048];
  __shared__ float red[256];
  for (int s = threadIdx.x; s < 2048; s += 256) fl[s] = f[b * 2048 + s];
  __syncthreads();
  float gj = g[b * 2048 + j];
  float acc = 0;
  for (int i = ch * 512; i < ch * 512 + 512; ++i) acc += qfun(fl[i] + gj);
  red[threadIdx.x] = acc;
  __syncthreads();
  if (ch == 0) {
    float s = red[jl] + red[jl + 64] + red[jl + 128] + red[jl + 192];
    rd[b * 2048 + j] = 1.f / s;
  }
}

// P[b][i][j] = bf16(q(f_i+g_j) * rdenom_j)
__global__ __launch_bounds__(256) void k_P(const float* f, const float* g,
                                           const float* rd, u16* P) {
  int j = blockIdx.x * 256 + threadIdx.x;
  int i0 = blockIdx.y * 16;
  int b = blockIdx.z;
  __shared__ float fl[16];
  if (threadIdx.x < 16) fl[threadIdx.x] = f[b * 2048 + i0 + threadIdx.x];
  __syncthreads();
  float gj = g[b * 2048 + j], rj = rd[b * 2048 + j];
  u16* Pp = P + ((long)b * 2048 + i0) * 2048 + j;
#pragma unroll
  for (int ii = 0; ii < 16; ++ii) Pp[(long)ii * 2048] = f2b(qfun(fl[ii] + gj) * rj);
}

// lhs_t[b][t][n], rhs_t[b][n][t] from tc_s[bn][t][f] (bf16)
__global__ void k_temporal(const u16* tc, const float* u1u2, const float* U3g,
                           float* lhs_t, float* rhs_t) {
  __shared__ float uu[64], u3[64];
  int tid = threadIdx.x;
  if (tid < 64) { uu[tid] = u1u2[tid]; u3[tid] = U3g[tid]; }
  __syncthreads();
  int gid = blockIdx.x * 256 + tid;  // < 196608
  const u16* p = tc + (long)gid * 64;
  float s1 = 0, s2 = 0;
#pragma unroll
  for (int c = 0; c < 8; ++c) {
    u16x8 vv = *(const u16x8*)(p + c * 8);
#pragma unroll
    for (int j = 0; j < 8; ++j) {
      float v = b2f(vv[j]);
      s1 += v * uu[c * 8 + j]; s2 += v * u3[c * 8 + j];
    }
  }
  int t = gid % 12; long bn = gid / 12;
  int b = (int)(bn >> 11);
  lhs_t[((long)b * 12 + t) * 2048 + (int)(bn & 2047)] = s1;
  rhs_t[gid] = s2;
}

__global__ void k_prod(const float* lhs_t, const float* rhs_t, float* prod) {
  int bi = blockIdx.x;  // < 1152
  int b = bi / 144; int r = bi % 144; int s = r / 12; int u = r % 12;
  int tid = threadIdx.x;
  float acc = 0;
  const float* lp = lhs_t + ((long)b * 12 + s) * 2048;
  const float* rp = rhs_t + (long)b * 2048 * 12 + u;
  for (int n = tid; n < 2048; n += 256) acc += lp[n] * rp[n * 12];
  __shared__ float red[256];
  red[tid] = acc; __syncthreads();
  for (int st = 128; st > 0; st >>= 1) {
    if (tid < st) red[tid] += red[tid + st];
    __syncthreads();
  }
  if (tid == 0) prod[bi] = red[0];
}

__global__ void k_E(const float* prod, const float* be, const float* Ve, float* E) {
  int b = blockIdx.x; int tid = threadIdx.x;
  __shared__ float S0[144], E1[144], mx[12], dn[12];
  if (tid < 144) {
    float v = prod[b * 144 + tid] + be[tid];
    S0[tid] = 1.f / (1.f + __expf(-v));
  }
  __syncthreads();
  if (tid < 144) {
    int i = tid / 12, t = tid % 12;
    float a = 0;
    for (int s = 0; s < 12; ++s) a += Ve[i * 12 + s] * S0[s * 12 + t];
    E1[tid] = a;
  }
  __syncthreads();
  if (tid < 12) {
    float m = -1e30f;
    for (int i = 0; i < 12; ++i) m = fmaxf(m, E1[i * 12 + tid]);
    float d = 0;
    for (int i = 0; i < 12; ++i) d += __expf(E1[i * 12 + tid] - m);
    mx[tid] = m; dn[tid] = d;
  }
  __syncthreads();
  if (tid < 144) {
    int t = tid % 12;
    E[b * 144 + tid] = __expf(E1[tid] - mx[t]) / dn[t];
  }
}

// tcn + residual + relu + layernorm(channel) -> resultB in A-FRAG layout.
__global__ __launch_bounds__(256) void k_res_ln(const u16* tc, const float* E,
                                                const float* xg, const float* res_w,
                                                const float* res_b, const float* ln_g,
                                                const float* ln_b, u16* result) {
  int bn = blockIdx.x; int b = bn >> 11;
  int tid = threadIdx.x;
  __shared__ float tcb[768], Eb[144], xl[36], rw[192], rb[64], lg[64], lb[64], zl[768], mu[12], rs[12];
  for (int s = tid; s < 768; s += 256) tcb[s] = b2f(tc[(long)bn * 768 + s]);
  if (tid < 144) Eb[tid] = E[b * 144 + tid];
  if (tid < 36) xl[tid] = xg[(long)bn * 36 + tid];
  if (tid >= 64 && tid < 256) { int q = tid - 64; if (q < 192) rw[q] = res_w[q]; }
  if (tid < 64) { rb[tid] = res_b[tid]; lg[tid] = ln_g[tid]; lb[tid] = ln_b[tid]; }
  __syncthreads();
  float z[3];
#pragma unroll
  for (int q = 0; q < 3; ++q) {
    int idx = tid + q * 256; int f = idx / 12, s = idx % 12;
    float tcn = 0;
#pragma unroll
    for (int t = 0; t < 12; ++t) tcn += tcb[t * 64 + f] * Eb[t * 12 + s];
    float xr = rb[f];
#pragma unroll
    for (int i = 0; i < 3; ++i) xr += rw[f * 3 + i] * xl[i * 12 + s];
    float v = xr + tcn;
    v = v > 0.f ? v : 0.f;
    z[q] = v; zl[idx] = v;
  }
  __syncthreads();
  if (tid < 12) {
    float m = 0, m2 = 0;
    for (int f = 0; f < 64; ++f) { float v = zl[f * 12 + tid]; m += v; m2 += v * v; }
    m *= (1.f / 64.f); m2 *= (1.f / 64.f);
    mu[tid] = m;
    float var = m2 - m * m;
    rs[tid] = rsqrtf((var > 0.f ? var : 0.f) + 1e-5f);
  }
  __syncthreads();
  const int mf = bn >> 4, m = bn & 15;
#pragma unroll
  for (int q = 0; q < 3; ++q) {
    int idx = tid + q * 256; int f = idx / 12, s = idx % 12;
    int kt = idx >> 5, koct = (idx >> 3) & 3, j = idx & 7;
    result[((long)mf * 24 + kt) * 512 + (m + 16 * koct) * 8 + j] =
        f2b((z[q] - mu[s]) * rs[s] * lg[f] + lb[f]);
  }
}

__global__ void k_sentinel(float* out, long n) {
  long i = (long)blockIdx.x * 256 + threadIdx.x;
  if (i < n) out[i] = 12345.0f;
}

// ---------------------------------------------------------------------------
// Launcher
// ---------------------------------------------------------------------------
extern "C" void kernel_launch(void* const* d_in, const int* in_sizes, int n_in,
                              void* d_out, int out_size, void* d_ws, size_t ws_size,
                              hipStream_t stream) {
  (void)in_sizes; (void)n_in;
  const float* x       = (const float*)d_in[0];
  const float* cheb    = (const float*)d_in[1];
  const float* Gamma   = (const float*)d_in[2];
  const float* W_heads = (const float*)d_in[3];
  const float* a_heads = (const float*)d_in[4];
  const float* W_out   = (const float*)d_in[5];
  const float* a_out   = (const float*)d_in[6];
  const float* U1      = (const float*)d_in[7];
  const float* U2      = (const float*)d_in[8];
  const float* U3      = (const float*)d_in[9];
  const float* be      = (const float*)d_in[10];
  const float* Ve      = (const float*)d_in[11];
  const float* time_w  = (const float*)d_in[12];
  const float* time_b  = (const float*)d_in[13];
  const float* res_w   = (const float*)d_in[14];
  const float* res_b   = (const float*)d_in[15];
  const float* back_w  = (const float*)d_in[16];
  const float* back_b  = (const float*)d_in[17];
  const float* fore_w  = (const float*)d_in[18];
  const float* fore_b  = (const float*)d_in[19];
  const float* ln_g    = (const float*)d_in[20];
  const float* ln_b    = (const float*)d_in[21];
  float* out = (float*)d_out;

  if (ws_size < WS_NEEDED) {  // distinctive failure signature (absmax ~12345)
    k_sentinel<<<(out_size + 255) / 256, 256, 0, stream>>>(out, out_size);
    return;
  }

  char* ws = (char*)d_ws;
  float* lhs     = (float*)(ws + OFF_LHS);
  float* u1u2    = (float*)(ws + OFF_U1U2);
  float* biasBig = (float*)(ws + OFF_BIASBIG);
  float* fH      = (float*)(ws + OFF_FH);
  float* gH      = (float*)(ws + OFF_GH);
  float* rdH     = (float*)(ws + OFF_RDH);
  float* fO      = (float*)(ws + OFF_FO);
  float* gO      = (float*)(ws + OFF_GO);
  float* rdO     = (float*)(ws + OFF_RDO);
  float* lhs_t   = (float*)(ws + OFF_LHST);
  float* rhs_t   = (float*)(ws + OFF_RHST);
  float* prod    = (float*)(ws + OFF_PROD);
  float* Ebuf    = (float*)(ws + OFF_E);
  u16* WcatT   = (u16*)(ws + OFF_WCATT);
  u16* WoutT   = (u16*)(ws + OFF_WOUTT);
  u16* WtBig   = (u16*)(ws + OFF_WTBIG);
  u16* WbfBig  = (u16*)(ws + OFF_WBFBIG);
  u16* xcolT   = (u16*)(ws + OFF_XCOLT);
  u16* chebT   = (u16*)(ws + OFF_CHEBT);
  u16* C1      = (u16*)(ws + OFF_C1);
  u16* hbuf    = (u16*)(ws + OFF_H);
  u16* Pbuf    = (u16*)(ws + OFF_P);
  u16* WhcatT  = (u16*)(ws + OFF_WHCATT);
  u16* hcat    = (u16*)(ws + OFF_HCAT);
  u16* WhoutT  = (u16*)(ws + OFF_WHOUTT);
  u16* gcnB    = (u16*)(ws + OFF_GCNB);
  u16* tcsB    = (u16*)(ws + OFF_TCS);
  u16* resultB = (u16*)(ws + OFF_RESULTB);

  // --- prep ---
  k_prep<<<1, 64, 0, stream>>>(Gamma, U1, U2, back_b, fore_b, lhs, u1u2, biasBig);
  k_convert<<<2048, 256, 0, stream>>>(W_heads, W_out, time_w, back_w, fore_w, x,
                                      WcatT, WoutT, WtBig, WbfBig, xcolT);
  k_chebT<<<dim3(64, 64, 3), 256, 0, stream>>>(cheb, chebT);

  // --- G1: C1 partials (bf16) = chebT @ xcolT^T, split-K x4 (z=k*4+ch, K=512) ---
  {
    GemmP p{}; p.A = chebT; p.BT = xcolT; p.sA = 2048L * 2048; p.sB = 0;
    p.K = 512; p.lda = 2048; p.ldb = 2048; p.splitK = 1; p.swz = 1;
    p.Cb = C1; p.sCb = 2048L * 384; p.ldcb = 384;
    gemm_bf16<9, 1><<<dim3(3, 16, 12), 256, 0, stream>>>(p);
  }
  k_h<<<16384, 256, 0, stream>>>(C1, lhs, hbuf);

  // --- G2: Wh_cat (AFB barrier-free; LDS-transposed out) ---
  {
    GemmP p{}; p.A = hbuf; p.BT = WcatT; p.sA = 0; p.K = 768;
    p.CbT = WhcatT; p.ldcT = 2048; p.sCbT = 768L * 2048;
    gemm_afb<1><<<dim3(6, 128, 1), 256, 0, stream>>>(p);
  }
  // f,g per head
  k_fg<<<dim3(8, 8), 256, 0, stream>>>(WhcatT, 0, 384, a_heads, a_heads + 384, fH, gH);
  k_fg<<<dim3(8, 8), 256, 0, stream>>>(WhcatT, 384, 384, a_heads + 768, a_heads + 1152,
                                       fH + 16384, gH + 16384);
  // heads: denom, P, att GEMM (elu -> hcat half)
  for (int hd = 0; hd < 2; ++hd) {
    const float* f = fH + hd * 16384; const float* g = gH + hd * 16384;
    float* rd = rdH + hd * 16384;
    k_denom<<<dim3(32, 8), 256, 0, stream>>>(f, g, rd);
    k_P<<<dim3(8, 128, 8), 256, 0, stream>>>(f, g, rd, Pbuf);
    GemmP p{}; p.A = Pbuf; p.BT = WhcatT + (long)hd * 384 * 2048;
    p.sA = 2048L * 2048; p.sB = 768L * 2048;
    p.K = 2048; p.lda = 2048; p.ldb = 2048; p.swz = 1;
    p.Cb = hcat + hd * 384; p.sCb = 2048L * 768; p.ldcb = 768;
    gemm_bf16<2, 1><<<dim3(3, 16, 8), 256, 0, stream>>>(p);
  }

  // --- G5: Wh_out (LDS-transposed out) ---
  {
    GemmP p{}; p.A = hcat; p.BT = WoutT; p.sA = 0; p.sB = 0;
    p.K = 768; p.lda = 768; p.ldb = 768; p.swz = 1;
    p.CbT = WhoutT; p.ldcT = 2048; p.sCbT = 768L * 2048;
    gemm_bf16<1, 2><<<dim3(3, 128, 1), 256, 0, stream>>>(p);
  }
  k_fg<<<dim3(8, 8), 256, 0, stream>>>(WhoutT, 0, 768, a_out, a_out + 768, fO, gO);
  k_denom<<<dim3(32, 8), 256, 0, stream>>>(fO, gO, rdO);
  k_P<<<dim3(8, 128, 8), 256, 0, stream>>>(fO, gO, rdO, Pbuf);
  // --- G6: out attention, relu -> gcnB bf16 ---
  {
    GemmP p{}; p.A = Pbuf; p.BT = WhoutT; p.sA = 2048L * 2048; p.sB = 768L * 2048;
    p.K = 2048; p.lda = 2048; p.ldb = 2048; p.swz = 1;
    p.Cb = gcnB; p.sCb = 2048L * 768; p.ldcb = 768;
    gemm_bf16<8, 2><<<dim3(3, 16, 8), 256, 0, stream>>>(p);
  }

  // --- temporal conv as dense GEMM (tap-expanded weights) -> tcsB bf16 ---
  {
    GemmP p{}; p.A = gcnB; p.BT = WtBig; p.sA = 0; p.sB = 0;
    p.K = 768; p.lda = 768; p.ldb = 768; p.swz = 1;
    p.Cb = tcsB; p.bias = time_b;
    gemm_bf16<6, 2><<<dim3(3, 128, 1), 256, 0, stream>>>(p);
  }

  // --- temporal attention ---
  k_temporal<<<768, 256, 0, stream>>>(tcsB, u1u2, U3, lhs_t, rhs_t);
  k_prod<<<1152, 256, 0, stream>>>(lhs_t, rhs_t, prod);
  k_E<<<8, 256, 0, stream>>>(prod, be, Ve, Ebuf);

  // --- residual + LN -> resultB fragments (same per-row structure) ---
  k_res_ln<<<16384, 256, 0, stream>>>(tcsB, Ebuf, x, res_w, res_b, ln_g, ln_b, resultB);

  // --- backcast / forecast convs: AFB barrier-free GEMM, vectorized writes ---
  {
    GemmP p{}; p.A = resultB; p.BT = WbfBig; p.sA = 0; p.K = 768;
    p.bias = biasBig; p.outB = out; p.outF = out + 12582912L;
    gemm_afb<7><<<dim3(12, 128, 1), 256, 0, stream>>>(p);
  }
}

// Round 21
// 699.265 us; speedup vs baseline: 2.1715x; 1.0051x over previous
//
#include <hip/hip_runtime.h>

// ============================================================================
// ASTGCN block for MI355X. Dims: B=8, N=2048, FIN=3, T=12, K=3, FC=FT=64.
// bf16 MFMA (16x16x32) for all big GEMMs, fp32 elsewhere.
// GEMM convention: C[m,n] = sum_k A[m,k] * BT[n,k]; A,BT bf16 K-contiguous.
// R10: 3-buffer single-barrier depth-2 K-loop (best general GEMM, 698us).
// R20: surgical composition of individually-proven pieces:
//      - gemm_afb (R14, lb(256,2), 92 VGPR no-spill) for G2 + final GEMM
//        (final GEMM measured 71 -> 65.6us in R14's counters)
//      - WcatT/WbfBig emitted in B-frag layout (R14 k_convert, proven)
//      - k_h / k_res_ln keep R10 one-row-per-block structure; only the store
//        ADDRESS is remapped to A-frag layout (same scalar-store count).
// ============================================================================

typedef unsigned short u16;
typedef __bf16 bf16x8 __attribute__((ext_vector_type(8)));
typedef float f32x4 __attribute__((ext_vector_type(4)));
typedef u16 u16x8 __attribute__((ext_vector_type(8)));

__device__ __forceinline__ u16 f2b(float f) {
  union { float f; unsigned u; } v; v.f = f;
  unsigned u = v.u;
  u = u + 0x7FFFu + ((u >> 16) & 1u);   // RNE
  return (u16)(u >> 16);
}
__device__ __forceinline__ float b2f(u16 h) {
  union { unsigned u; float f; } v; v.u = ((unsigned)h) << 16; return v.f;
}
// q(x) = exp(sigmoid(leaky_relu(x, 0.1)))
__device__ __forceinline__ float qfun(float x) {
  float e = x > 0.f ? x : 0.1f * x;
  float s = __builtin_amdgcn_rcpf(1.f + __expf(-e));
  return __expf(s);
}

template <int N> __device__ __forceinline__ void waitvm() {
  if constexpr (N == 0)      asm volatile("s_waitcnt vmcnt(0)" ::: "memory");
  else if constexpr (N == 4) asm volatile("s_waitcnt vmcnt(4)" ::: "memory");
  else if constexpr (N == 6) asm volatile("s_waitcnt vmcnt(6)" ::: "memory");
  else                       asm volatile("s_waitcnt vmcnt(16)" ::: "memory");
}
__device__ __forceinline__ void rawbar() { asm volatile("s_barrier" ::: "memory"); }

#define GLOAD16(g, l) __builtin_amdgcn_global_load_lds( \
    (__attribute__((address_space(1))) void*)(g),       \
    (__attribute__((address_space(3))) void*)(l), 16, 0, 0)

// ---------------------------------------------------------------------------
// Workspace layout (byte offsets). High water: 0x8D40000 (= 148 MB).
// ---------------------------------------------------------------------------
constexpr size_t OFF_LHS     = 0x0;        // f32 [3][3][64]
constexpr size_t OFF_U1U2    = 0x1000;     // f32 [64]
constexpr size_t OFF_BIASBIG = 0x1100;     // f32 [1536]
constexpr size_t OFF_FH      = 0x3000;     // f32 [2][8][2048]
constexpr size_t OFF_GH      = 0x23000;
constexpr size_t OFF_RDH     = 0x43000;
constexpr size_t OFF_FO      = 0x63000;    // f32 [8][2048]
constexpr size_t OFF_GO      = 0x73000;
constexpr size_t OFF_RDO     = 0x83000;
constexpr size_t OFF_LHST    = 0x93000;    // f32 [8][12][2048]
constexpr size_t OFF_RHST    = 0x153000;   // f32 [8][2048][12]
constexpr size_t OFF_PROD    = 0x213000;   // f32 [8][12][12]
constexpr size_t OFF_E       = 0x215000;   // f32 [8][12][12]
constexpr size_t OFF_WCATT   = 0x220000;   // bf16 [768][768] B-FRAG layout
constexpr size_t OFF_WOUTT   = 0x340000;   // bf16 [768][768] K-contiguous
constexpr size_t OFF_WTBIG   = 0x460000;   // bf16 [768][768] tap-expanded, K-contig
constexpr size_t OFF_XCOLT   = 0x580000;   // bf16 [384][2048] (rows 288.. zero)
constexpr size_t OFF_CHEBT   = 0x700000;   // bf16 [3][2048][2048]  -> 0x1F00000
constexpr size_t OFF_C1      = 0x1F00000;  // bf16 [12][2048][384]  -> 0x3100000
constexpr size_t OFF_H       = 0x4300000;  // bf16 A-frag [1024][24][512] -> 0x5B00000
constexpr size_t OFF_P       = 0x700000;   // bf16 [8][2048][2048] (cheb/C1/h dead) -> 0x4700000
constexpr size_t OFF_WHCATT  = 0x5B00000;  // bf16 [8][768][2048]   -> 0x7300000
constexpr size_t OFF_HCAT    = 0x7300000;  // bf16 [16384][768]     -> 0x8B00000
constexpr size_t OFF_WHOUTT  = 0x5B00000;  // reuse (WhcatT dead after G4)
constexpr size_t OFF_GCNB    = 0x7300000;  // bf16 [16384][768] (hcat dead) -> 0x8B00000
constexpr size_t OFF_WBFBIG  = 0x8B00000;  // bf16 [1536][768] B-FRAG layout -> 0x8D40000
constexpr size_t OFF_TCS     = 0x700000;   // bf16 [16384][12][64] (P dead) -> 0x1F00000
constexpr size_t OFF_RESULTB = 0x3700000;  // bf16 A-frag [1024][24][512] -> 0x4F00000
constexpr size_t WS_NEEDED   = 0x8D40000;

// ---------------------------------------------------------------------------
struct GemmP {
  const u16* A; const u16* BT;
  long sA, sB;            // per-z batch strides (elements)
  int K, lda, ldb;
  int swz, splitK;
  float* Cf; long sCf; int ldcf;
  u16* Cb;  long sCb; int ldcb;
  u16* CbT; int ldcT; long sCbT;
  const float* bias;
  float* outB; float* outF;
};

// ---------------------------------------------------------------------------
// gemm_afb: barrier-free LDS-free GEMM. Block 128x128 (2x2 waves of 64x64).
// Both operands in fragment layout: frag f at base + (tile16*KT + kt)*512 +
// lane*8 (lane = (r&15) + 16*koct). Triple-buffered register sets,
// vmcnt(16)-counted (2 steps in flight). R14-proven config: lb(256,2).
// EPI: 1 bf16-LDS-transposed   7 final +biasBig -> f32x4 rows
// ---------------------------------------------------------------------------
template <int EPI>
__global__ __launch_bounds__(256, 2) void gemm_afb(GemmP p) {
  __shared__ u16 smem[(EPI == 1) ? 17408 : 16];
  const int tid = threadIdx.x, lane = tid & 63, wid = tid >> 6;
  const int wm = wid >> 1, wn = wid & 1;
  const int z = blockIdx.z;
  int nT = gridDim.x;
  int nwg = nT * gridDim.y;
  int lin = blockIdx.x + nT * blockIdx.y;
  int q8 = nwg >> 3;
  int sw = (lin & 7) * q8 + (lin >> 3);   // XCD-chunked bijection (nwg%8==0)
  long m0 = (long)(sw / nT) * 128;
  long n0 = (long)(sw % nT) * 128;

  const int KT = p.K >> 5;
  const long mstr = (long)KT * 512;
  const u16* aPf = p.A + (long)z * p.sA + ((m0 >> 4) + wm * 4) * mstr + lane * 8;
  const u16* bPf = p.BT + ((n0 >> 4) + wn * 4) * mstr + lane * 8;

  f32x4 acc[4][4];
  f32x4 zero = {0.f, 0.f, 0.f, 0.f};
#pragma unroll
  for (int i = 0; i < 4; ++i)
#pragma unroll
    for (int j = 0; j < 4; ++j) acc[i][j] = zero;

  bf16x8 a0[4], b0[4], a1[4], b1[4], a2[4], b2[4];
  auto LOAD = [&](bf16x8 (&av)[4], bf16x8 (&bv)[4], int s) {
#pragma unroll
    for (int mi = 0; mi < 4; ++mi) av[mi] = *(const bf16x8*)(aPf + mi * mstr + (long)s * 512);
#pragma unroll
    for (int ni = 0; ni < 4; ++ni) bv[ni] = *(const bf16x8*)(bPf + ni * mstr + (long)s * 512);
  };
  auto MM = [&](bf16x8 (&av)[4], bf16x8 (&bv)[4]) {
#pragma unroll
    for (int mi = 0; mi < 4; ++mi)
#pragma unroll
      for (int ni = 0; ni < 4; ++ni)
        acc[mi][ni] = __builtin_amdgcn_mfma_f32_16x16x32_bf16(av[mi], bv[ni], acc[mi][ni], 0, 0, 0);
  };

  LOAD(a0, b0, 0);
  if (KT > 1) LOAD(a1, b1, 1);
  if (KT > 2) LOAD(a2, b2, 2);
  for (int i = 0; i < KT; i += 3) {
    waitvm<16>(); MM(a0, b0);
    if (i + 3 < KT) LOAD(a0, b0, i + 3);
    if (i + 1 < KT) {
      waitvm<16>(); MM(a1, b1);
      if (i + 4 < KT) LOAD(a1, b1, i + 4);
    }
    if (i + 2 < KT) {
      waitvm<16>(); MM(a2, b2);
      if (i + 5 < KT) LOAD(a2, b2, i + 5);
    }
  }

  if constexpr (EPI == 1) {
    // Stage bf16 tile transposed in LDS, coalesced column writes.
    __syncthreads();
#pragma unroll
    for (int mi = 0; mi < 4; ++mi)
#pragma unroll
      for (int ni = 0; ni < 4; ++ni) {
        int cl = wn * 64 + ni * 16 + (lane & 15);
        int mlb = wm * 64 + mi * 16 + ((lane >> 4) << 2);
#pragma unroll
        for (int r = 0; r < 4; ++r)
          smem[cl * 136 + mlb + r] = f2b(acc[mi][ni][r]);
      }
    __syncthreads();
    int c = tid >> 1, half = tid & 1;
    long bat = m0 >> 11;                  // 2048-row batches
    u16* dst = p.CbT + bat * p.sCbT + (long)(n0 + c) * p.ldcT + (m0 & 2047) + half * 64;
    const u16* srcp = &smem[c * 136 + half * 64];
#pragma unroll
    for (int j = 0; j < 64; j += 8)
      *(u16x8*)(dst + j) = *(const u16x8*)(srcp + j);
    return;
  }

  if constexpr (EPI == 7) {
    // In-register 4x4 transpose -> dwordx4 row stores.
    const int q = lane >> 4, g4 = (lane >> 2) & 3, j = lane & 3;
    const int back = ((int)n0 < 768);
    float* obase = (back ? p.outB : p.outF) - (back ? 0 : 768);
#pragma unroll
    for (int mi = 0; mi < 4; ++mi) {
      long rb0 = m0 + wm * 64 + mi * 16 + q * 4;
#pragma unroll
      for (int ni = 0; ni < 4; ++ni) {
        int cb = (int)n0 + wn * 64 + ni * 16 + g4 * 4;
        f32x4 v = acc[mi][ni];
        float bsv = p.bias[cb + j];
        v[0] += bsv; v[1] += bsv; v[2] += bsv; v[3] += bsv;
#pragma unroll
        for (int d = 1; d <= 2; d <<= 1) {
          f32x4 t;
#pragma unroll
          for (int b = 0; b < 4; ++b) t[b] = __shfl_xor(v[b ^ d], d, 64);
#pragma unroll
          for (int b = 0; b < 4; ++b) if ((lane ^ b) & d) v[b] = t[b];
        }
        *(f32x4*)(obase + (rb0 + j) * 768 + cb) = v;
      }
    }
    return;
  }
}

// ---------------------------------------------------------------------------
// Generic MFMA GEMM (R10): 3-buffer single-barrier depth-2 pipeline.
// EPI: 1 bf16-LDS-transposed-per-2048batch   2 elu->bf16
//      6 time-conv +time_b[col&63] -> bf16   8 relu->bf16   9 plain bf16
// ---------------------------------------------------------------------------
template <int EPI, int WN>
__global__ __launch_bounds__(256, (WN == 1 ? 3 : 2)) void gemm_bf16(GemmP p) {
  constexpr int BUFU  = (WN == 1) ? 8192 : 12288;   // u16 per K-step buffer
  constexpr int SMEMU = 3 * BUFU;                   // 3 buffers (EPI1 17408 fits)
  constexpr int LPW   = (WN == 1) ? 4 : 6;          // loads per wave per stage
  __shared__ u16 smem[SMEMU];
  const int tid  = threadIdx.x;
  const int lane = tid & 63;
  const int wid  = tid >> 6;
  const int wm = wid >> 1, wn = wid & 1;
  const int z = blockIdx.z;

  long m0, n0;
  if (p.swz) {
    int nT = gridDim.x;
    int nwg = nT * gridDim.y;
    int lin = blockIdx.x + nT * blockIdx.y;
    int q = nwg >> 3;                       // nwg % 8 == 0 guaranteed by caller
    int swz = (lin & 7) * q + (lin >> 3);   // XCD-chunked bijection
    m0 = (long)(swz / nT) * 128;
    n0 = (long)(swz % nT) * (128 * WN);
  } else {
    m0 = (long)blockIdx.y * 128;
    n0 = (long)blockIdx.x * (128 * WN);
  }

  const int K = p.K;
  long aBase, bBase;
  if (p.splitK) {
    int kz = z >> 2, ch = z & 3;
    aBase = (long)kz * p.sA + (long)ch * 512;
    bBase = (long)ch * 512;
  } else {
    aBase = (long)z * p.sA;
    bBase = (long)z * p.sB;
  }
  const u16* Ab = p.A + aBase + m0 * p.lda;
  const u16* Bb = p.BT + bBase + n0 * p.ldb;

  const int sk = (((lane & 3) ^ ((lane >> 3) & 3))) * 8;
  const u16* aP0 = Ab + (long)(wid * 32 + (lane >> 2)) * p.lda + sk;
  const u16* aP1 = aP0 + (long)16 * p.lda;
  const u16* bP0 = Bb + (long)(wid * 32 * WN + (lane >> 2)) * p.ldb + sk;
  const u16* bP1 = bP0 + (long)16 * p.ldb;
  const u16* bP2 = bP0 + (long)32 * p.ldb;
  const u16* bP3 = bP0 + (long)48 * p.ldb;
  const int aslot = wid * 1024;
  const int bslot = 4096 + wid * (WN == 1 ? 1024 : 2048);

  auto STAGE = [&](int s, int bi) {
    long ko = (long)s * 32;
    u16* base = smem + bi * BUFU;
    GLOAD16(aP0 + ko, base + aslot);
    GLOAD16(aP1 + ko, base + aslot + 512);
    GLOAD16(bP0 + ko, base + bslot);
    GLOAD16(bP1 + ko, base + bslot + 512);
    if constexpr (WN == 2) {
      GLOAD16(bP2 + ko, base + bslot + 1024);
      GLOAD16(bP3 + ko, base + bslot + 1536);
    }
  };

  f32x4 acc[4][4 * WN];
  f32x4 zero = {0.f, 0.f, 0.f, 0.f};
#pragma unroll
  for (int i = 0; i < 4; ++i)
#pragma unroll
    for (int j = 0; j < 4 * WN; ++j) acc[i][j] = zero;

  const int xorc = (lane >> 1) & 3;
  const int aoff = (wm * 64 + (lane & 15)) * 32 + ((lane >> 4) ^ xorc) * 8;
  const int boff = 4096 + (wn * 64 * WN + (lane & 15)) * 32 + ((lane >> 4) ^ xorc) * 8;

  const int nsteps = K >> 5;   // >= 2 at all call sites

  STAGE(0, 0);
  STAGE(1, 1);
  waitvm<LPW>();
  rawbar();

  int cur = 0;
  for (int i = 0; i < nsteps; ++i) {
    const u16* buf = smem + cur * BUFU;
    bf16x8 av[4], bv[4 * WN];
#pragma unroll
    for (int mi = 0; mi < 4; ++mi) av[mi] = *(const bf16x8*)&buf[aoff + mi * 512];
#pragma unroll
    for (int ni = 0; ni < 4 * WN; ++ni) bv[ni] = *(const bf16x8*)&buf[boff + ni * 512];
#pragma unroll
    for (int mi = 0; mi < 4; ++mi)
#pragma unroll
      for (int ni = 0; ni < 4 * WN; ++ni)
        acc[mi][ni] = __builtin_amdgcn_mfma_f32_16x16x32_bf16(av[mi], bv[ni], acc[mi][ni], 0, 0, 0);
    if (i + 1 < nsteps) {
      if (i + 2 < nsteps) {
        STAGE(i + 2, cur == 0 ? 2 : cur - 1);   // (cur+2)%3
        waitvm<LPW>();                          // stage i+1 landed
      } else {
        waitvm<0>();
      }
      rawbar();
    }
    cur = (cur == 2) ? 0 : cur + 1;
  }
  __syncthreads();  // drain before epilogue smem reuse (EPI1)

  if constexpr (EPI == 1) {
#pragma unroll
    for (int h = 0; h < 2; ++h) {
      if (h == 1) __syncthreads();
      if (WN == 1 || wn == h) {
#pragma unroll
        for (int mi = 0; mi < 4; ++mi)
#pragma unroll
          for (int ni = 0; ni < 4 * WN; ++ni) {
            int cl = (WN == 1 ? wn * 64 : 0) + ni * 16 + (lane & 15);
            int mlb = wm * 64 + mi * 16 + ((lane >> 4) << 2);
#pragma unroll
            for (int r = 0; r < 4; ++r)
              smem[cl * 136 + mlb + r] = f2b(acc[mi][ni][r]);
          }
      }
      __syncthreads();
      int c = tid >> 1, half = tid & 1;
      long bat = m0 >> 11;                  // 2048-row batches
      u16* dst = p.CbT + bat * p.sCbT + (long)(n0 + h * 128 + c) * p.ldcT +
                 (m0 & 2047) + half * 64;
      const u16* srcp = &smem[c * 136 + half * 64];
#pragma unroll
      for (int j = 0; j < 64; j += 8)
        *(u16x8*)(dst + j) = *(const u16x8*)(srcp + j);
      if (WN == 1) break;                   // WN=1 tile is only 128 cols
    }
    return;
  }

#pragma unroll
  for (int mi = 0; mi < 4; ++mi) {
    long rb0 = m0 + wm * 64 + mi * 16 + ((lane >> 4) << 2);
#pragma unroll
    for (int ni = 0; ni < 4 * WN; ++ni) {
      int col = (int)n0 + wn * 64 * WN + ni * 16 + (lane & 15);
#pragma unroll
      for (int r = 0; r < 4; ++r) {
        float v = acc[mi][ni][r];
        long row = rb0 + r;
        if constexpr (EPI == 2) {
          float e = v > 0.f ? v : expm1f(v);
          p.Cb[(long)z * p.sCb + row * p.ldcb + col] = f2b(e);
        } else if constexpr (EPI == 6) {
          p.Cb[row * 768 + col] = f2b(v + p.bias[col & 63]);
        } else if constexpr (EPI == 9) {
          p.Cb[(long)z * p.sCb + row * p.ldcb + col] = f2b(v);
        } else {  // EPI == 8: relu -> bf16
          p.Cb[(long)z * p.sCb + row * p.ldcb + col] = f2b(fmaxf(v, 0.f));
        }
      }
    }
  }
}

// ---------------------------------------------------------------------------
// Small kernels
// ---------------------------------------------------------------------------
__global__ void k_prep(const float* Gamma, const float* U1, const float* U2,
                       const float* back_b, const float* fore_b,
                       float* lhs, float* u1u2, float* biasBig) {
  int o = threadIdx.x;
  if (o < 64) {
    const float cx[3][3] = {{1.f, 0.86602540378443871f, 0.5f},
                            {1.f, 6.123233995736766e-17f, -1.f},
                            {1.f, -0.86602540378443871f, 0.5f}};
    for (int k = 0; k < 3; ++k)
      for (int i = 0; i < 3; ++i) {
        float s = 0;
        for (int j = 0; j < 3; ++j) s += Gamma[(j * 3 + i) * 64 + o] * cx[j][k];
        lhs[(k * 3 + i) * 64 + o] = s;
      }
    float s = 0;
    for (int g = 0; g < 64; ++g) s += U1[o * 64 + g] * U2[g];
    u1u2[o] = s;
    for (int t = 0; t < 12; ++t) {
      biasBig[o * 12 + t] = back_b[o];
      biasBig[768 + o * 12 + t] = fore_b[o];
    }
  }
}

__global__ void k_convert(const float* W_heads, const float* W_out, const float* time_w,
                          const float* back_w, const float* fore_w, const float* xg,
                          u16* WcatT, u16* WoutT, u16* WtBig, u16* WbfBig, u16* xcolT) {
  const int N1 = 589824, NT = 589824, NBF = 1179648, N5 = 786432;
  const int TOT = 2 * N1 + NT + NBF + N5;
  for (int o = blockIdx.x * 256 + threadIdx.x; o < TOT; o += gridDim.x * 256) {
    if (o < N1) {
      // WcatT in B-FRAG layout: frag f = nf*24+kt, slot ln*8+j.
      int f = o >> 9, s = o & 511;
      int ln = s >> 3, j = s & 7;
      int nf = f / 24, kt = f % 24;
      int dcol = nf * 16 + (ln & 15);
      int kk = kt * 32 + (ln >> 4) * 8 + j;
      int hd = dcol / 384, d = dcol % 384;
      WcatT[o] = f2b(W_heads[((long)hd * 768 + kk) * 384 + d]);
    } else if (o < 2 * N1) {
      int o2 = o - N1; int dcol = o2 / 768, kk = o2 % 768;
      WoutT[o2] = f2b(W_out[kk * 768 + dcol]);
    } else if (o < 2 * N1 + NT) {
      // WtBig[t*64+ft][fc*12+tau] K-contiguous (tap-expanded)
      int o3 = o - 2 * N1; int col = o3 / 768, kk = o3 % 768;
      int t = col >> 6, ft = col & 63, fc = kk / 12, tau = kk % 12;
      int r = tau - t + 1;
      WtBig[o3] = f2b((r >= 0 && r < 3) ? time_w[ft * 192 + fc * 3 + r] : 0.f);
    } else if (o < 2 * N1 + NT + NBF) {
      // WbfBig in B-FRAG layout (1536 cols, 96 nf tiles, 24 kt)
      int o4 = o - 2 * N1 - NT;
      int f = o4 >> 9, s = o4 & 511;
      int ln = s >> 3, j = s & 7;
      int nf = f / 24, kt = f % 24;
      int col = nf * 16 + (ln & 15);
      int kk = kt * 32 + (ln >> 4) * 8 + j;
      int rem = (col < 768) ? col : col - 768;
      int c = rem / 12, tt = rem % 12;
      int fc = kk / 12, tau = kk % 12; int r = tau - tt + 1;
      const float* wsrc = (col < 768) ? back_w : fore_w;
      WbfBig[o4] = f2b((r >= 0 && r < 3) ? wsrc[c * 192 + fc * 3 + r] : 0.f);
    } else {
      int o5 = o - 2 * N1 - NT - NBF; int c = o5 / 2048, n = o5 % 2048;
      float v = 0.f;
      if (c < 288) {
        int b = c / 36, r2 = c % 36, i = r2 / 12, t = r2 % 12;
        v = xg[(long)(b * 2048 + n) * 36 + i * 12 + t];
      }
      xcolT[o5] = f2b(v);
    }
  }
}

// chebT[k][m][n] = bf16(cheb[k][n][m])
__global__ void k_chebT(const float* cheb, u16* chebT) {
  __shared__ float ts[32][33];
  int n0 = blockIdx.x * 32, m0 = blockIdx.y * 32, k = blockIdx.z;
  int c = threadIdx.x & 31, rq = threadIdx.x >> 5;  // rq 0..7
  const long base = (long)k * 2048 * 2048;
  for (int q = 0; q < 4; ++q) {
    int n = n0 + rq + q * 8;
    ts[rq + q * 8][c] = cheb[base + (long)n * 2048 + m0 + c];
  }
  __syncthreads();
  for (int q = 0; q < 4; ++q) {
    int m = m0 + rq + q * 8;
    chebT[base + (long)m * 2048 + n0 + c] = f2b(ts[c][rq + q * 8]);
  }
}

// h in A-FRAG layout: row bn -> (mf=bn>>4, m=bn&15); col idx -> (kt,koct,j).
__global__ __launch_bounds__(256) void k_h(const u16* C1, const float* lhs, u16* h) {
  int bn = blockIdx.x; int b = bn >> 11, n = bn & 2047;
  int tid = threadIdx.x;
  __shared__ float c1s[108], ls[576];
  if (tid < 108) {
    int kk = tid / 12, t = tid % 12; int k = kk / 3, i = kk % 3;
    float s = 0;
#pragma unroll
    for (int ch = 0; ch < 4; ++ch)
      s += b2f(C1[((long)(k * 4 + ch) * 2048 + n) * 384 + b * 36 + i * 12 + t]);
    c1s[tid] = s;
  }
  for (int s = tid; s < 576; s += 256) ls[s] = lhs[s];
  __syncthreads();
  const int mf = bn >> 4, m = bn & 15;
  for (int q = 0; q < 3; ++q) {
    int idx = tid + q * 256; int o = idx / 12, t = idx % 12;
    float s = 0;
#pragma unroll
    for (int kk = 0; kk < 9; ++kk) s += c1s[kk * 12 + t] * ls[kk * 64 + o];
    s *= 0.5f;
    if (s < 0.f) s = 0.f;
    int kt = idx >> 5, koct = (idx >> 3) & 3, j = idx & 7;
    h[((long)mf * 24 + kt) * 512 + (m + 16 * koct) * 8 + j] = f2b(s);
  }
}

// f,g from WhT[b][dOff+d][i], a-slices
__global__ __launch_bounds__(256) void k_fg(const u16* WhT, int dOff, int Dlen,
                                            const float* aF, const float* aG,
                                            float* fOut, float* gOut) {
  int b = blockIdx.y;
  int i = blockIdx.x * 256 + threadIdx.x;
  __shared__ float af[768], ag[768];
  for (int s = threadIdx.x; s < Dlen; s += 256) { af[s] = aF[s]; ag[s] = aG[s]; }
  __syncthreads();
  const u16* wp = WhT + ((long)b * 768 + dOff) * 2048 + i;
  float fs = 0, gs = 0;
  for (int d = 0; d < Dlen; ++d) {
    float w = b2f(wp[(long)d * 2048]);
    fs += w * af[d]; gs += w * ag[d];
  }
  fOut[b * 2048 + i] = fs;
  gOut[b * 2048 + i] = gs;
}

// rdenom[b][j] = 1 / sum_i q(f_i + g_j)
__global__ __launch_bounds__(256) void k_denom(const float* f, const float* g, float* rd) {
  int b = blockIdx.y;
  int jl = threadIdx.x & 63, ch = threadIdx.x >> 6;
  int j = blockIdx.x * 64 + jl;
  __shared__ float fl[2048];
  __shared__ float red[256];
  for (int s = threadIdx.x; s < 2048; s += 256) fl[s] = f[b * 2048 + s];
  __syncthreads();
  float gj = g[b * 2048 + j];
  float acc = 0;
  for (int i = ch * 512; i < ch * 512 + 512; ++i) acc += qfun(fl[i] + gj);
  red[threadIdx.x] = acc;
  __syncthreads();
  if (ch == 0) {
    float s = red[jl] + red[jl + 64] + red[jl + 128] + red[jl + 192];
    rd[b * 2048 + j] = 1.f / s;
  }
}

// P[b][i][j] = bf16(q(f_i+g_j) * rdenom_j)
__global__ __launch_bounds__(256) void k_P(const float* f, const float* g,
                                           const float* rd, u16* P) {
  int j = blockIdx.x * 256 + threadIdx.x;
  int i0 = blockIdx.y * 16;
  int b = blockIdx.z;
  __shared__ float fl[16];
  if (threadIdx.x < 16) fl[threadIdx.x] = f[b * 2048 + i0 + threadIdx.x];
  __syncthreads();
  float gj = g[b * 2048 + j], rj = rd[b * 2048 + j];
  u16* Pp = P + ((long)b * 2048 + i0) * 2048 + j;
#pragma unroll
  for (int ii = 0; ii < 16; ++ii) Pp[(long)ii * 2048] = f2b(qfun(fl[ii] + gj) * rj);
}

// lhs_t[b][t][n], rhs_t[b][n][t] from tc_s[bn][t][f] (bf16)
__global__ void k_temporal(const u16* tc, const float* u1u2, const float* U3g,
                           float* lhs_t, float* rhs_t) {
  __shared__ float uu[64], u3[64];
  int tid = threadIdx.x;
  if (tid < 64) { uu[tid] = u1u2[tid]; u3[tid] = U3g[tid]; }
  __syncthreads();
  int gid = blockIdx.x * 256 + tid;  // < 196608
  const u16* p = tc + (long)gid * 64;
  float s1 = 0, s2 = 0;
#pragma unroll
  for (int c = 0; c < 8; ++c) {
    u16x8 vv = *(const u16x8*)(p + c * 8);
#pragma unroll
    for (int j = 0; j < 8; ++j) {
      float v = b2f(vv[j]);
      s1 += v * uu[c * 8 + j]; s2 += v * u3[c * 8 + j];
    }
  }
  int t = gid % 12; long bn = gid / 12;
  int b = (int)(bn >> 11);
  lhs_t[((long)b * 12 + t) * 2048 + (int)(bn & 2047)] = s1;
  rhs_t[gid] = s2;
}

__global__ void k_prod(const float* lhs_t, const float* rhs_t, float* prod) {
  int bi = blockIdx.x;  // < 1152
  int b = bi / 144; int r = bi % 144; int s = r / 12; int u = r % 12;
  int tid = threadIdx.x;
  float acc = 0;
  const float* lp = lhs_t + ((long)b * 12 + s) * 2048;
  const float* rp = rhs_t + (long)b * 2048 * 12 + u;
  for (int n = tid; n < 2048; n += 256) acc += lp[n] * rp[n * 12];
  __shared__ float red[256];
  red[tid] = acc; __syncthreads();
  for (int st = 128; st > 0; st >>= 1) {
    if (tid < st) red[tid] += red[tid + st];
    __syncthreads();
  }
  if (tid == 0) prod[bi] = red[0];
}

__global__ void k_E(const float* prod, const float* be, const float* Ve, float* E) {
  int b = blockIdx.x; int tid = threadIdx.x;
  __shared__ float S0[144], E1[144], mx[12], dn[12];
  if (tid < 144) {
    float v = prod[b * 144 + tid] + be[tid];
    S0[tid] = 1.f / (1.f + __expf(-v));
  }
  __syncthreads();
  if (tid < 144) {
    int i = tid / 12, t = tid % 12;
    float a = 0;
    for (int s = 0; s < 12; ++s) a += Ve[i * 12 + s] * S0[s * 12 + t];
    E1[tid] = a;
  }
  __syncthreads();
  if (tid < 12) {
    float m = -1e30f;
    for (int i = 0; i < 12; ++i) m = fmaxf(m, E1[i * 12 + tid]);
    float d = 0;
    for (int i = 0; i < 12; ++i) d += __expf(E1[i * 12 + tid] - m);
    mx[tid] = m; dn[tid] = d;
  }
  __syncthreads();
  if (tid < 144) {
    int t = tid % 12;
    E[b * 144 + tid] = __expf(E1[tid] - mx[t]) / dn[t];
  }
}

// tcn + residual + relu + layernorm(channel) -> resultB in A-FRAG layout.
__global__ __launch_bounds__(256) void k_res_ln(const u16* tc, const float* E,
                                                const float* xg, const float* res_w,
                                                const float* res_b, const float* ln_g,
                                                const float* ln_b, u16* result) {
  int bn = blockIdx.x; int b = bn >> 11;
  int tid = threadIdx.x;
  __shared__ float tcb[768], Eb[144], xl[36], rw[192], rb[64], lg[64], lb[64], zl[768], mu[12], rs[12];
  for (int s = tid; s < 768; s += 256) tcb[s] = b2f(tc[(long)bn * 768 + s]);
  if (tid < 144) Eb[tid] = E[b * 144 + tid];
  if (tid < 36) xl[tid] = xg[(long)bn * 36 + tid];
  if (tid >= 64 && tid < 256) { int q = tid - 64; if (q < 192) rw[q] = res_w[q]; }
  if (tid < 64) { rb[tid] = res_b[tid]; lg[tid] = ln_g[tid]; lb[tid] = ln_b[tid]; }
  __syncthreads();
  float z[3];
#pragma unroll
  for (int q = 0; q < 3; ++q) {
    int idx = tid + q * 256; int f = idx / 12, s = idx % 12;
    float tcn = 0;
#pragma unroll
    for (int t = 0; t < 12; ++t) tcn += tcb[t * 64 + f] * Eb[t * 12 + s];
    float xr = rb[f];
#pragma unroll
    for (int i = 0; i < 3; ++i) xr += rw[f * 3 + i] * xl[i * 12 + s];
    float v = xr + tcn;
    v = v > 0.f ? v : 0.f;
    z[q] = v; zl[idx] = v;
  }
  __syncthreads();
  if (tid < 12) {
    float m = 0, m2 = 0;
    for (int f = 0; f < 64; ++f) { float v = zl[f * 12 + tid]; m += v; m2 += v * v; }
    m *= (1.f / 64.f); m2 *= (1.f / 64.f);
    mu[tid] = m;
    float var = m2 - m * m;
    rs[tid] = rsqrtf((var > 0.f ? var : 0.f) + 1e-5f);
  }
  __syncthreads();
  const int mf = bn >> 4, m = bn & 15;
#pragma unroll
  for (int q = 0; q < 3; ++q) {
    int idx = tid + q * 256; int f = idx / 12, s = idx % 12;
    int kt = idx >> 5, koct = (idx >> 3) & 3, j = idx & 7;
    result[((long)mf * 24 + kt) * 512 + (m + 16 * koct) * 8 + j] =
        f2b((z[q] - mu[s]) * rs[s] * lg[f] + lb[f]);
  }
}

__global__ void k_sentinel(float* out, long n) {
  long i = (long)blockIdx.x * 256 + threadIdx.x;
  if (i < n) out[i] = 12345.0f;
}

// ---------------------------------------------------------------------------
// Launcher
// ---------------------------------------------------------------------------
extern "C" void kernel_launch(void* const* d_in, const int* in_sizes, int n_in,
                              void* d_out, int out_size, void* d_ws, size_t ws_size,
                              hipStream_t stream) {
  (void)in_sizes; (void)n_in;
  const float* x       = (const float*)d_in[0];
  const float* cheb    = (const float*)d_in[1];
  const float* Gamma   = (const float*)d_in[2];
  const float* W_heads = (const float*)d_in[3];
  const float* a_heads = (const float*)d_in[4];
  const float* W_out   = (const float*)d_in[5];
  const float* a_out   = (const float*)d_in[6];
  const float* U1      = (const float*)d_in[7];
  const float* U2      = (const float*)d_in[8];
  const float* U3      = (const float*)d_in[9];
  const float* be      = (const float*)d_in[10];
  const float* Ve      = (const float*)d_in[11];
  const float* time_w  = (const float*)d_in[12];
  const float* time_b  = (const float*)d_in[13];
  const float* res_w   = (const float*)d_in[14];
  const float* res_b   = (const float*)d_in[15];
  const float* back_w  = (const float*)d_in[16];
  const float* back_b  = (const float*)d_in[17];
  const float* fore_w  = (const float*)d_in[18];
  const float* fore_b  = (const float*)d_in[19];
  const float* ln_g    = (const float*)d_in[20];
  const float* ln_b    = (const float*)d_in[21];
  float* out = (float*)d_out;

  if (ws_size < WS_NEEDED) {  // distinctive failure signature (absmax ~12345)
    k_sentinel<<<(out_size + 255) / 256, 256, 0, stream>>>(out, out_size);
    return;
  }

  char* ws = (char*)d_ws;
  float* lhs     = (float*)(ws + OFF_LHS);
  float* u1u2    = (float*)(ws + OFF_U1U2);
  float* biasBig = (float*)(ws + OFF_BIASBIG);
  float* fH      = (float*)(ws + OFF_FH);
  float* gH      = (float*)(ws + OFF_GH);
  float* rdH     = (float*)(ws + OFF_RDH);
  float* fO      = (float*)(ws + OFF_FO);
  float* gO      = (float*)(ws + OFF_GO);
  float* rdO     = (float*)(ws + OFF_RDO);
  float* lhs_t   = (float*)(ws + OFF_LHST);
  float* rhs_t   = (float*)(ws + OFF_RHST);
  float* prod    = (float*)(ws + OFF_PROD);
  float* Ebuf    = (float*)(ws + OFF_E);
  u16* WcatT   = (u16*)(ws + OFF_WCATT);
  u16* WoutT   = (u16*)(ws + OFF_WOUTT);
  u16* WtBig   = (u16*)(ws + OFF_WTBIG);
  u16* WbfBig  = (u16*)(ws + OFF_WBFBIG);
  u16* xcolT   = (u16*)(ws + OFF_XCOLT);
  u16* chebT   = (u16*)(ws + OFF_CHEBT);
  u16* C1      = (u16*)(ws + OFF_C1);
  u16* hbuf    = (u16*)(ws + OFF_H);
  u16* Pbuf    = (u16*)(ws + OFF_P);
  u16* WhcatT  = (u16*)(ws + OFF_WHCATT);
  u16* hcat    = (u16*)(ws + OFF_HCAT);
  u16* WhoutT  = (u16*)(ws + OFF_WHOUTT);
  u16* gcnB    = (u16*)(ws + OFF_GCNB);
  u16* tcsB    = (u16*)(ws + OFF_TCS);
  u16* resultB = (u16*)(ws + OFF_RESULTB);

  // --- prep ---
  k_prep<<<1, 64, 0, stream>>>(Gamma, U1, U2, back_b, fore_b, lhs, u1u2, biasBig);
  k_convert<<<2048, 256, 0, stream>>>(W_heads, W_out, time_w, back_w, fore_w, x,
                                      WcatT, WoutT, WtBig, WbfBig, xcolT);
  k_chebT<<<dim3(64, 64, 3), 256, 0, stream>>>(cheb, chebT);

  // --- G1: C1 partials (bf16) = chebT @ xcolT^T, split-K x4 (z=k*4+ch, K=512) ---
  {
    GemmP p{}; p.A = chebT; p.BT = xcolT; p.sA = 2048L * 2048; p.sB = 0;
    p.K = 512; p.lda = 2048; p.ldb = 2048; p.splitK = 1; p.swz = 1;
    p.Cb = C1; p.sCb = 2048L * 384; p.ldcb = 384;
    gemm_bf16<9, 1><<<dim3(3, 16, 12), 256, 0, stream>>>(p);
  }
  k_h<<<16384, 256, 0, stream>>>(C1, lhs, hbuf);

  // --- G2: Wh_cat (AFB barrier-free; LDS-transposed out) ---
  {
    GemmP p{}; p.A = hbuf; p.BT = WcatT; p.sA = 0; p.K = 768;
    p.CbT = WhcatT; p.ldcT = 2048; p.sCbT = 768L * 2048;
    gemm_afb<1><<<dim3(6, 128, 1), 256, 0, stream>>>(p);
  }
  // f,g per head
  k_fg<<<dim3(8, 8), 256, 0, stream>>>(WhcatT, 0, 384, a_heads, a_heads + 384, fH, gH);
  k_fg<<<dim3(8, 8), 256, 0, stream>>>(WhcatT, 384, 384, a_heads + 768, a_heads + 1152,
                                       fH + 16384, gH + 16384);
  // heads: denom, P, att GEMM (elu -> hcat half)
  for (int hd = 0; hd < 2; ++hd) {
    const float* f = fH + hd * 16384; const float* g = gH + hd * 16384;
    float* rd = rdH + hd * 16384;
    k_denom<<<dim3(32, 8), 256, 0, stream>>>(f, g, rd);
    k_P<<<dim3(8, 128, 8), 256, 0, stream>>>(f, g, rd, Pbuf);
    GemmP p{}; p.A = Pbuf; p.BT = WhcatT + (long)hd * 384 * 2048;
    p.sA = 2048L * 2048; p.sB = 768L * 2048;
    p.K = 2048; p.lda = 2048; p.ldb = 2048; p.swz = 1;
    p.Cb = hcat + hd * 384; p.sCb = 2048L * 768; p.ldcb = 768;
    gemm_bf16<2, 1><<<dim3(3, 16, 8), 256, 0, stream>>>(p);
  }

  // --- G5: Wh_out (LDS-transposed out) ---
  {
    GemmP p{}; p.A = hcat; p.BT = WoutT; p.sA = 0; p.sB = 0;
    p.K = 768; p.lda = 768; p.ldb = 768; p.swz = 1;
    p.CbT = WhoutT; p.ldcT = 2048; p.sCbT = 768L * 2048;
    gemm_bf16<1, 2><<<dim3(3, 128, 1), 256, 0, stream>>>(p);
  }
  k_fg<<<dim3(8, 8), 256, 0, stream>>>(WhoutT, 0, 768, a_out, a_out + 768, fO, gO);
  k_denom<<<dim3(32, 8), 256, 0, stream>>>(fO, gO, rdO);
  k_P<<<dim3(8, 128, 8), 256, 0, stream>>>(fO, gO, rdO, Pbuf);
  // --- G6: out attention, relu -> gcnB bf16 ---
  {
    GemmP p{}; p.A = Pbuf; p.BT = WhoutT; p.sA = 2048L * 2048; p.sB = 768L * 2048;
    p.K = 2048; p.lda = 2048; p.ldb = 2048; p.swz = 1;
    p.Cb = gcnB; p.sCb = 2048L * 768; p.ldcb = 768;
    gemm_bf16<8, 2><<<dim3(3, 16, 8), 256, 0, stream>>>(p);
  }

  // --- temporal conv as dense GEMM (tap-expanded weights) -> tcsB bf16 ---
  {
    GemmP p{}; p.A = gcnB; p.BT = WtBig; p.sA = 0; p.sB = 0;
    p.K = 768; p.lda = 768; p.ldb = 768; p.swz = 1;
    p.Cb = tcsB; p.bias = time_b;
    gemm_bf16<6, 2><<<dim3(3, 128, 1), 256, 0, stream>>>(p);
  }

  // --- temporal attention ---
  k_temporal<<<768, 256, 0, stream>>>(tcsB, u1u2, U3, lhs_t, rhs_t);
  k_prod<<<1152, 256, 0, stream>>>(lhs_t, rhs_t, prod);
  k_E<<<8, 256, 0, stream>>>(prod, be, Ve, Ebuf);

  // --- residual + LN -> resultB fragments (same per-row structure) ---
  k_res_ln<<<16384, 256, 0, stream>>>(tcsB, Ebuf, x, res_w, res_b, ln_g, ln_b, resultB);

  // --- backcast / forecast convs: AFB barrier-free GEMM, vectorized writes ---
  {
    GemmP p{}; p.A = resultB; p.BT = WbfBig; p.sA = 0; p.K = 768;
    p.bias = biasBig; p.outB = out; p.outF = out + 12582912L;
    gemm_afb<7><<<dim3(12, 128, 1), 256, 0, stream>>>(p);
  }
}

// Round 22
// 694.798 us; speedup vs baseline: 2.1854x; 1.0064x over previous
//
#include <hip/hip_runtime.h>

// ============================================================================
// ASTGCN block for MI355X. Dims: B=8, N=2048, FIN=3, T=12, K=3, FC=FT=64.
// bf16 MFMA (16x16x32) for all big GEMMs, fp32 elsewhere.
// GEMM convention: C[m,n] = sum_k A[m,k] * BT[n,k]; A,BT bf16 K-contiguous.
// R10: 3-buffer single-barrier depth-2 K-loop. R20: gemm_afb (barrier-free,
//      both operands reg-fragments) for G2 + final GEMM; frag-layout
//      producers (address remap only).
// R21: re-add z-fold XCD swizzle (swz=2, one z-batch per XCD) for the three
//      P-GEMMs — R20 counters show them HBM-bound with FETCH 141MB vs ~88MB
//      ideal (z-interleaving thrashes per-XCD L2, diagnosed in R12).
// ============================================================================

typedef unsigned short u16;
typedef __bf16 bf16x8 __attribute__((ext_vector_type(8)));
typedef float f32x4 __attribute__((ext_vector_type(4)));
typedef u16 u16x8 __attribute__((ext_vector_type(8)));

__device__ __forceinline__ u16 f2b(float f) {
  union { float f; unsigned u; } v; v.f = f;
  unsigned u = v.u;
  u = u + 0x7FFFu + ((u >> 16) & 1u);   // RNE
  return (u16)(u >> 16);
}
__device__ __forceinline__ float b2f(u16 h) {
  union { unsigned u; float f; } v; v.u = ((unsigned)h) << 16; return v.f;
}
// q(x) = exp(sigmoid(leaky_relu(x, 0.1)))
__device__ __forceinline__ float qfun(float x) {
  float e = x > 0.f ? x : 0.1f * x;
  float s = __builtin_amdgcn_rcpf(1.f + __expf(-e));
  return __expf(s);
}

template <int N> __device__ __forceinline__ void waitvm() {
  if constexpr (N == 0)      asm volatile("s_waitcnt vmcnt(0)" ::: "memory");
  else if constexpr (N == 4) asm volatile("s_waitcnt vmcnt(4)" ::: "memory");
  else if constexpr (N == 6) asm volatile("s_waitcnt vmcnt(6)" ::: "memory");
  else                       asm volatile("s_waitcnt vmcnt(16)" ::: "memory");
}
__device__ __forceinline__ void rawbar() { asm volatile("s_barrier" ::: "memory"); }

#define GLOAD16(g, l) __builtin_amdgcn_global_load_lds( \
    (__attribute__((address_space(1))) void*)(g),       \
    (__attribute__((address_space(3))) void*)(l), 16, 0, 0)

// ---------------------------------------------------------------------------
// Workspace layout (byte offsets). High water: 0x8D40000 (= 148 MB).
// ---------------------------------------------------------------------------
constexpr size_t OFF_LHS     = 0x0;        // f32 [3][3][64]
constexpr size_t OFF_U1U2    = 0x1000;     // f32 [64]
constexpr size_t OFF_BIASBIG = 0x1100;     // f32 [1536]
constexpr size_t OFF_FH      = 0x3000;     // f32 [2][8][2048]
constexpr size_t OFF_GH      = 0x23000;
constexpr size_t OFF_RDH     = 0x43000;
constexpr size_t OFF_FO      = 0x63000;    // f32 [8][2048]
constexpr size_t OFF_GO      = 0x73000;
constexpr size_t OFF_RDO     = 0x83000;
constexpr size_t OFF_LHST    = 0x93000;    // f32 [8][12][2048]
constexpr size_t OFF_RHST    = 0x153000;   // f32 [8][2048][12]
constexpr size_t OFF_PROD    = 0x213000;   // f32 [8][12][12]
constexpr size_t OFF_E       = 0x215000;   // f32 [8][12][12]
constexpr size_t OFF_WCATT   = 0x220000;   // bf16 [768][768] B-FRAG layout
constexpr size_t OFF_WOUTT   = 0x340000;   // bf16 [768][768] K-contiguous
constexpr size_t OFF_WTBIG   = 0x460000;   // bf16 [768][768] tap-expanded, K-contig
constexpr size_t OFF_XCOLT   = 0x580000;   // bf16 [384][2048] (rows 288.. zero)
constexpr size_t OFF_CHEBT   = 0x700000;   // bf16 [3][2048][2048]  -> 0x1F00000
constexpr size_t OFF_C1      = 0x1F00000;  // bf16 [12][2048][384]  -> 0x3100000
constexpr size_t OFF_H       = 0x4300000;  // bf16 A-frag [1024][24][512] -> 0x5B00000
constexpr size_t OFF_P       = 0x700000;   // bf16 [8][2048][2048] (cheb/C1/h dead) -> 0x4700000
constexpr size_t OFF_WHCATT  = 0x5B00000;  // bf16 [8][768][2048]   -> 0x7300000
constexpr size_t OFF_HCAT    = 0x7300000;  // bf16 [16384][768]     -> 0x8B00000
constexpr size_t OFF_WHOUTT  = 0x5B00000;  // reuse (WhcatT dead after G4)
constexpr size_t OFF_GCNB    = 0x7300000;  // bf16 [16384][768] (hcat dead) -> 0x8B00000
constexpr size_t OFF_WBFBIG  = 0x8B00000;  // bf16 [1536][768] B-FRAG layout -> 0x8D40000
constexpr size_t OFF_TCS     = 0x700000;   // bf16 [16384][12][64] (P dead) -> 0x1F00000
constexpr size_t OFF_RESULTB = 0x3700000;  // bf16 A-frag [1024][24][512] -> 0x4F00000
constexpr size_t WS_NEEDED   = 0x8D40000;

// ---------------------------------------------------------------------------
struct GemmP {
  const u16* A; const u16* BT;
  long sA, sB;            // per-z batch strides (elements)
  int K, lda, ldb;
  int swz, splitK;
  float* Cf; long sCf; int ldcf;
  u16* Cb;  long sCb; int ldcb;
  u16* CbT; int ldcT; long sCbT;
  const float* bias;
  float* outB; float* outF;
};

// ---------------------------------------------------------------------------
// gemm_afb: barrier-free LDS-free GEMM. Block 128x128 (2x2 waves of 64x64).
// Both operands in fragment layout: frag f at base + (tile16*KT + kt)*512 +
// lane*8 (lane = (r&15) + 16*koct). Triple-buffered register sets,
// vmcnt(16)-counted (2 steps in flight). R14-proven config: lb(256,2).
// EPI: 1 bf16-LDS-transposed   7 final +biasBig -> f32x4 rows
// ---------------------------------------------------------------------------
template <int EPI>
__global__ __launch_bounds__(256, 2) void gemm_afb(GemmP p) {
  __shared__ u16 smem[(EPI == 1) ? 17408 : 16];
  const int tid = threadIdx.x, lane = tid & 63, wid = tid >> 6;
  const int wm = wid >> 1, wn = wid & 1;
  const int z = blockIdx.z;
  int nT = gridDim.x;
  int nwg = nT * gridDim.y;
  int lin = blockIdx.x + nT * blockIdx.y;
  int q8 = nwg >> 3;
  int sw = (lin & 7) * q8 + (lin >> 3);   // XCD-chunked bijection (nwg%8==0)
  long m0 = (long)(sw / nT) * 128;
  long n0 = (long)(sw % nT) * 128;

  const int KT = p.K >> 5;
  const long mstr = (long)KT * 512;
  const u16* aPf = p.A + (long)z * p.sA + ((m0 >> 4) + wm * 4) * mstr + lane * 8;
  const u16* bPf = p.BT + ((n0 >> 4) + wn * 4) * mstr + lane * 8;

  f32x4 acc[4][4];
  f32x4 zero = {0.f, 0.f, 0.f, 0.f};
#pragma unroll
  for (int i = 0; i < 4; ++i)
#pragma unroll
    for (int j = 0; j < 4; ++j) acc[i][j] = zero;

  bf16x8 a0[4], b0[4], a1[4], b1[4], a2[4], b2[4];
  auto LOAD = [&](bf16x8 (&av)[4], bf16x8 (&bv)[4], int s) {
#pragma unroll
    for (int mi = 0; mi < 4; ++mi) av[mi] = *(const bf16x8*)(aPf + mi * mstr + (long)s * 512);
#pragma unroll
    for (int ni = 0; ni < 4; ++ni) bv[ni] = *(const bf16x8*)(bPf + ni * mstr + (long)s * 512);
  };
  auto MM = [&](bf16x8 (&av)[4], bf16x8 (&bv)[4]) {
#pragma unroll
    for (int mi = 0; mi < 4; ++mi)
#pragma unroll
      for (int ni = 0; ni < 4; ++ni)
        acc[mi][ni] = __builtin_amdgcn_mfma_f32_16x16x32_bf16(av[mi], bv[ni], acc[mi][ni], 0, 0, 0);
  };

  LOAD(a0, b0, 0);
  if (KT > 1) LOAD(a1, b1, 1);
  if (KT > 2) LOAD(a2, b2, 2);
  for (int i = 0; i < KT; i += 3) {
    waitvm<16>(); MM(a0, b0);
    if (i + 3 < KT) LOAD(a0, b0, i + 3);
    if (i + 1 < KT) {
      waitvm<16>(); MM(a1, b1);
      if (i + 4 < KT) LOAD(a1, b1, i + 4);
    }
    if (i + 2 < KT) {
      waitvm<16>(); MM(a2, b2);
      if (i + 5 < KT) LOAD(a2, b2, i + 5);
    }
  }

  if constexpr (EPI == 1) {
    // Stage bf16 tile transposed in LDS, coalesced column writes.
    __syncthreads();
#pragma unroll
    for (int mi = 0; mi < 4; ++mi)
#pragma unroll
      for (int ni = 0; ni < 4; ++ni) {
        int cl = wn * 64 + ni * 16 + (lane & 15);
        int mlb = wm * 64 + mi * 16 + ((lane >> 4) << 2);
#pragma unroll
        for (int r = 0; r < 4; ++r)
          smem[cl * 136 + mlb + r] = f2b(acc[mi][ni][r]);
      }
    __syncthreads();
    int c = tid >> 1, half = tid & 1;
    long bat = m0 >> 11;                  // 2048-row batches
    u16* dst = p.CbT + bat * p.sCbT + (long)(n0 + c) * p.ldcT + (m0 & 2047) + half * 64;
    const u16* srcp = &smem[c * 136 + half * 64];
#pragma unroll
    for (int j = 0; j < 64; j += 8)
      *(u16x8*)(dst + j) = *(const u16x8*)(srcp + j);
    return;
  }

  if constexpr (EPI == 7) {
    // In-register 4x4 transpose -> dwordx4 row stores.
    const int q = lane >> 4, g4 = (lane >> 2) & 3, j = lane & 3;
    const int back = ((int)n0 < 768);
    float* obase = (back ? p.outB : p.outF) - (back ? 0 : 768);
#pragma unroll
    for (int mi = 0; mi < 4; ++mi) {
      long rb0 = m0 + wm * 64 + mi * 16 + q * 4;
#pragma unroll
      for (int ni = 0; ni < 4; ++ni) {
        int cb = (int)n0 + wn * 64 + ni * 16 + g4 * 4;
        f32x4 v = acc[mi][ni];
        float bsv = p.bias[cb + j];
        v[0] += bsv; v[1] += bsv; v[2] += bsv; v[3] += bsv;
#pragma unroll
        for (int d = 1; d <= 2; d <<= 1) {
          f32x4 t;
#pragma unroll
          for (int b = 0; b < 4; ++b) t[b] = __shfl_xor(v[b ^ d], d, 64);
#pragma unroll
          for (int b = 0; b < 4; ++b) if ((lane ^ b) & d) v[b] = t[b];
        }
        *(f32x4*)(obase + (rb0 + j) * 768 + cb) = v;
      }
    }
    return;
  }
}

// ---------------------------------------------------------------------------
// Generic MFMA GEMM (R10): 3-buffer single-barrier depth-2 pipeline.
// swz=1: XCD-chunk remap of (x,y).  swz=2: z-fold (gridDim.z==8, one z/XCD).
// EPI: 1 bf16-LDS-transposed-per-2048batch   2 elu->bf16
//      6 time-conv +time_b[col&63] -> bf16   8 relu->bf16   9 plain bf16
// ---------------------------------------------------------------------------
template <int EPI, int WN>
__global__ __launch_bounds__(256, (WN == 1 ? 3 : 2)) void gemm_bf16(GemmP p) {
  constexpr int BUFU  = (WN == 1) ? 8192 : 12288;   // u16 per K-step buffer
  constexpr int SMEMU = 3 * BUFU;                   // 3 buffers (EPI1 17408 fits)
  constexpr int LPW   = (WN == 1) ? 4 : 6;          // loads per wave per stage
  __shared__ u16 smem[SMEMU];
  const int tid  = threadIdx.x;
  const int lane = tid & 63;
  const int wid  = tid >> 6;
  const int wm = wid >> 1, wn = wid & 1;

  long m0, n0;
  int z = blockIdx.z;
  if (p.swz == 2) {
    // z-fold: gridDim.z == 8 required. One z-batch per XCD; m-major within.
    int nT = gridDim.x;
    int nwg = nT * gridDim.y;
    long L = (long)blockIdx.z * nwg + blockIdx.x + (long)nT * blockIdx.y;
    z = (int)(L & 7);
    long r = L >> 3;
    m0 = (r / nT) * 128;
    n0 = (r % nT) * (128 * WN);
  } else if (p.swz) {
    int nT = gridDim.x;
    int nwg = nT * gridDim.y;
    int lin = blockIdx.x + nT * blockIdx.y;
    int q = nwg >> 3;                       // nwg % 8 == 0 guaranteed by caller
    int swz = (lin & 7) * q + (lin >> 3);   // XCD-chunked bijection
    m0 = (long)(swz / nT) * 128;
    n0 = (long)(swz % nT) * (128 * WN);
  } else {
    m0 = (long)blockIdx.y * 128;
    n0 = (long)blockIdx.x * (128 * WN);
  }

  const int K = p.K;
  long aBase, bBase;
  if (p.splitK) {
    int kz = z >> 2, ch = z & 3;
    aBase = (long)kz * p.sA + (long)ch * 512;
    bBase = (long)ch * 512;
  } else {
    aBase = (long)z * p.sA;
    bBase = (long)z * p.sB;
  }
  const u16* Ab = p.A + aBase + m0 * p.lda;
  const u16* Bb = p.BT + bBase + n0 * p.ldb;

  const int sk = (((lane & 3) ^ ((lane >> 3) & 3))) * 8;
  const u16* aP0 = Ab + (long)(wid * 32 + (lane >> 2)) * p.lda + sk;
  const u16* aP1 = aP0 + (long)16 * p.lda;
  const u16* bP0 = Bb + (long)(wid * 32 * WN + (lane >> 2)) * p.ldb + sk;
  const u16* bP1 = bP0 + (long)16 * p.ldb;
  const u16* bP2 = bP0 + (long)32 * p.ldb;
  const u16* bP3 = bP0 + (long)48 * p.ldb;
  const int aslot = wid * 1024;
  const int bslot = 4096 + wid * (WN == 1 ? 1024 : 2048);

  auto STAGE = [&](int s, int bi) {
    long ko = (long)s * 32;
    u16* base = smem + bi * BUFU;
    GLOAD16(aP0 + ko, base + aslot);
    GLOAD16(aP1 + ko, base + aslot + 512);
    GLOAD16(bP0 + ko, base + bslot);
    GLOAD16(bP1 + ko, base + bslot + 512);
    if constexpr (WN == 2) {
      GLOAD16(bP2 + ko, base + bslot + 1024);
      GLOAD16(bP3 + ko, base + bslot + 1536);
    }
  };

  f32x4 acc[4][4 * WN];
  f32x4 zero = {0.f, 0.f, 0.f, 0.f};
#pragma unroll
  for (int i = 0; i < 4; ++i)
#pragma unroll
    for (int j = 0; j < 4 * WN; ++j) acc[i][j] = zero;

  const int xorc = (lane >> 1) & 3;
  const int aoff = (wm * 64 + (lane & 15)) * 32 + ((lane >> 4) ^ xorc) * 8;
  const int boff = 4096 + (wn * 64 * WN + (lane & 15)) * 32 + ((lane >> 4) ^ xorc) * 8;

  const int nsteps = K >> 5;   // >= 2 at all call sites

  STAGE(0, 0);
  STAGE(1, 1);
  waitvm<LPW>();
  rawbar();

  int cur = 0;
  for (int i = 0; i < nsteps; ++i) {
    const u16* buf = smem + cur * BUFU;
    bf16x8 av[4], bv[4 * WN];
#pragma unroll
    for (int mi = 0; mi < 4; ++mi) av[mi] = *(const bf16x8*)&buf[aoff + mi * 512];
#pragma unroll
    for (int ni = 0; ni < 4 * WN; ++ni) bv[ni] = *(const bf16x8*)&buf[boff + ni * 512];
#pragma unroll
    for (int mi = 0; mi < 4; ++mi)
#pragma unroll
      for (int ni = 0; ni < 4 * WN; ++ni)
        acc[mi][ni] = __builtin_amdgcn_mfma_f32_16x16x32_bf16(av[mi], bv[ni], acc[mi][ni], 0, 0, 0);
    if (i + 1 < nsteps) {
      if (i + 2 < nsteps) {
        STAGE(i + 2, cur == 0 ? 2 : cur - 1);   // (cur+2)%3
        waitvm<LPW>();                          // stage i+1 landed
      } else {
        waitvm<0>();
      }
      rawbar();
    }
    cur = (cur == 2) ? 0 : cur + 1;
  }
  __syncthreads();  // drain before epilogue smem reuse (EPI1)

  if constexpr (EPI == 1) {
#pragma unroll
    for (int h = 0; h < 2; ++h) {
      if (h == 1) __syncthreads();
      if (WN == 1 || wn == h) {
#pragma unroll
        for (int mi = 0; mi < 4; ++mi)
#pragma unroll
          for (int ni = 0; ni < 4 * WN; ++ni) {
            int cl = (WN == 1 ? wn * 64 : 0) + ni * 16 + (lane & 15);
            int mlb = wm * 64 + mi * 16 + ((lane >> 4) << 2);
#pragma unroll
            for (int r = 0; r < 4; ++r)
              smem[cl * 136 + mlb + r] = f2b(acc[mi][ni][r]);
          }
      }
      __syncthreads();
      int c = tid >> 1, half = tid & 1;
      long bat = m0 >> 11;                  // 2048-row batches
      u16* dst = p.CbT + bat * p.sCbT + (long)(n0 + h * 128 + c) * p.ldcT +
                 (m0 & 2047) + half * 64;
      const u16* srcp = &smem[c * 136 + half * 64];
#pragma unroll
      for (int j = 0; j < 64; j += 8)
        *(u16x8*)(dst + j) = *(const u16x8*)(srcp + j);
      if (WN == 1) break;                   // WN=1 tile is only 128 cols
    }
    return;
  }

#pragma unroll
  for (int mi = 0; mi < 4; ++mi) {
    long rb0 = m0 + wm * 64 + mi * 16 + ((lane >> 4) << 2);
#pragma unroll
    for (int ni = 0; ni < 4 * WN; ++ni) {
      int col = (int)n0 + wn * 64 * WN + ni * 16 + (lane & 15);
#pragma unroll
      for (int r = 0; r < 4; ++r) {
        float v = acc[mi][ni][r];
        long row = rb0 + r;
        if constexpr (EPI == 2) {
          float e = v > 0.f ? v : expm1f(v);
          p.Cb[(long)z * p.sCb + row * p.ldcb + col] = f2b(e);
        } else if constexpr (EPI == 6) {
          p.Cb[row * 768 + col] = f2b(v + p.bias[col & 63]);
        } else if constexpr (EPI == 9) {
          p.Cb[(long)z * p.sCb + row * p.ldcb + col] = f2b(v);
        } else {  // EPI == 8: relu -> bf16
          p.Cb[(long)z * p.sCb + row * p.ldcb + col] = f2b(fmaxf(v, 0.f));
        }
      }
    }
  }
}

// ---------------------------------------------------------------------------
// Small kernels
// ---------------------------------------------------------------------------
__global__ void k_prep(const float* Gamma, const float* U1, const float* U2,
                       const float* back_b, const float* fore_b,
                       float* lhs, float* u1u2, float* biasBig) {
  int o = threadIdx.x;
  if (o < 64) {
    const float cx[3][3] = {{1.f, 0.86602540378443871f, 0.5f},
                            {1.f, 6.123233995736766e-17f, -1.f},
                            {1.f, -0.86602540378443871f, 0.5f}};
    for (int k = 0; k < 3; ++k)
      for (int i = 0; i < 3; ++i) {
        float s = 0;
        for (int j = 0; j < 3; ++j) s += Gamma[(j * 3 + i) * 64 + o] * cx[j][k];
        lhs[(k * 3 + i) * 64 + o] = s;
      }
    float s = 0;
    for (int g = 0; g < 64; ++g) s += U1[o * 64 + g] * U2[g];
    u1u2[o] = s;
    for (int t = 0; t < 12; ++t) {
      biasBig[o * 12 + t] = back_b[o];
      biasBig[768 + o * 12 + t] = fore_b[o];
    }
  }
}

__global__ void k_convert(const float* W_heads, const float* W_out, const float* time_w,
                          const float* back_w, const float* fore_w, const float* xg,
                          u16* WcatT, u16* WoutT, u16* WtBig, u16* WbfBig, u16* xcolT) {
  const int N1 = 589824, NT = 589824, NBF = 1179648, N5 = 786432;
  const int TOT = 2 * N1 + NT + NBF + N5;
  for (int o = blockIdx.x * 256 + threadIdx.x; o < TOT; o += gridDim.x * 256) {
    if (o < N1) {
      // WcatT in B-FRAG layout: frag f = nf*24+kt, slot ln*8+j.
      int f = o >> 9, s = o & 511;
      int ln = s >> 3, j = s & 7;
      int nf = f / 24, kt = f % 24;
      int dcol = nf * 16 + (ln & 15);
      int kk = kt * 32 + (ln >> 4) * 8 + j;
      int hd = dcol / 384, d = dcol % 384;
      WcatT[o] = f2b(W_heads[((long)hd * 768 + kk) * 384 + d]);
    } else if (o < 2 * N1) {
      int o2 = o - N1; int dcol = o2 / 768, kk = o2 % 768;
      WoutT[o2] = f2b(W_out[kk * 768 + dcol]);
    } else if (o < 2 * N1 + NT) {
      // WtBig[t*64+ft][fc*12+tau] K-contiguous (tap-expanded)
      int o3 = o - 2 * N1; int col = o3 / 768, kk = o3 % 768;
      int t = col >> 6, ft = col & 63, fc = kk / 12, tau = kk % 12;
      int r = tau - t + 1;
      WtBig[o3] = f2b((r >= 0 && r < 3) ? time_w[ft * 192 + fc * 3 + r] : 0.f);
    } else if (o < 2 * N1 + NT + NBF) {
      // WbfBig in B-FRAG layout (1536 cols, 96 nf tiles, 24 kt)
      int o4 = o - 2 * N1 - NT;
      int f = o4 >> 9, s = o4 & 511;
      int ln = s >> 3, j = s & 7;
      int nf = f / 24, kt = f % 24;
      int col = nf * 16 + (ln & 15);
      int kk = kt * 32 + (ln >> 4) * 8 + j;
      int rem = (col < 768) ? col : col - 768;
      int c = rem / 12, tt = rem % 12;
      int fc = kk / 12, tau = kk % 12; int r = tau - tt + 1;
      const float* wsrc = (col < 768) ? back_w : fore_w;
      WbfBig[o4] = f2b((r >= 0 && r < 3) ? wsrc[c * 192 + fc * 3 + r] : 0.f);
    } else {
      int o5 = o - 2 * N1 - NT - NBF; int c = o5 / 2048, n = o5 % 2048;
      float v = 0.f;
      if (c < 288) {
        int b = c / 36, r2 = c % 36, i = r2 / 12, t = r2 % 12;
        v = xg[(long)(b * 2048 + n) * 36 + i * 12 + t];
      }
      xcolT[o5] = f2b(v);
    }
  }
}

// chebT[k][m][n] = bf16(cheb[k][n][m])
__global__ void k_chebT(const float* cheb, u16* chebT) {
  __shared__ float ts[32][33];
  int n0 = blockIdx.x * 32, m0 = blockIdx.y * 32, k = blockIdx.z;
  int c = threadIdx.x & 31, rq = threadIdx.x >> 5;  // rq 0..7
  const long base = (long)k * 2048 * 2048;
  for (int q = 0; q < 4; ++q) {
    int n = n0 + rq + q * 8;
    ts[rq + q * 8][c] = cheb[base + (long)n * 2048 + m0 + c];
  }
  __syncthreads();
  for (int q = 0; q < 4; ++q) {
    int m = m0 + rq + q * 8;
    chebT[base + (long)m * 2048 + n0 + c] = f2b(ts[c][rq + q * 8]);
  }
}

// h in A-FRAG layout: row bn -> (mf=bn>>4, m=bn&15); col idx -> (kt,koct,j).
__global__ __launch_bounds__(256) void k_h(const u16* C1, const float* lhs, u16* h) {
  int bn = blockIdx.x; int b = bn >> 11, n = bn & 2047;
  int tid = threadIdx.x;
  __shared__ float c1s[108], ls[576];
  if (tid < 108) {
    int kk = tid / 12, t = tid % 12; int k = kk / 3, i = kk % 3;
    float s = 0;
#pragma unroll
    for (int ch = 0; ch < 4; ++ch)
      s += b2f(C1[((long)(k * 4 + ch) * 2048 + n) * 384 + b * 36 + i * 12 + t]);
    c1s[tid] = s;
  }
  for (int s = tid; s < 576; s += 256) ls[s] = lhs[s];
  __syncthreads();
  const int mf = bn >> 4, m = bn & 15;
  for (int q = 0; q < 3; ++q) {
    int idx = tid + q * 256; int o = idx / 12, t = idx % 12;
    float s = 0;
#pragma unroll
    for (int kk = 0; kk < 9; ++kk) s += c1s[kk * 12 + t] * ls[kk * 64 + o];
    s *= 0.5f;
    if (s < 0.f) s = 0.f;
    int kt = idx >> 5, koct = (idx >> 3) & 3, j = idx & 7;
    h[((long)mf * 24 + kt) * 512 + (m + 16 * koct) * 8 + j] = f2b(s);
  }
}

// f,g from WhT[b][dOff+d][i], a-slices
__global__ __launch_bounds__(256) void k_fg(const u16* WhT, int dOff, int Dlen,
                                            const float* aF, const float* aG,
                                            float* fOut, float* gOut) {
  int b = blockIdx.y;
  int i = blockIdx.x * 256 + threadIdx.x;
  __shared__ float af[768], ag[768];
  for (int s = threadIdx.x; s < Dlen; s += 256) { af[s] = aF[s]; ag[s] = aG[s]; }
  __syncthreads();
  const u16* wp = WhT + ((long)b * 768 + dOff) * 2048 + i;
  float fs = 0, gs = 0;
  for (int d = 0; d < Dlen; ++d) {
    float w = b2f(wp[(long)d * 2048]);
    fs += w * af[d]; gs += w * ag[d];
  }
  fOut[b * 2048 + i] = fs;
  gOut[b * 2048 + i] = gs;
}

// rdenom[b][j] = 1 / sum_i q(f_i + g_j)
__global__ __launch_bounds__(256) void k_denom(const float* f, const float* g, float* rd) {
  int b = blockIdx.y;
  int jl = threadIdx.x & 63, ch = threadIdx.x >> 6;
  int j = blockIdx.x * 64 + jl;
  __shared__ float fl[2048];
  __shared__ float red[256];
  for (int s = threadIdx.x; s < 2048; s += 256) fl[s] = f[b * 2048 + s];
  __syncthreads();
  float gj = g[b * 2048 + j];
  float acc = 0;
  for (int i = ch * 512; i < ch * 512 + 512; ++i) acc += qfun(fl[i] + gj);
  red[threadIdx.x] = acc;
  __syncthreads();
  if (ch == 0) {
    float s = red[jl] + red[jl + 64] + red[jl + 128] + red[jl + 192];
    rd[b * 2048 + j] = 1.f / s;
  }
}

// P[b][i][j] = bf16(q(f_i+g_j) * rdenom_j)
__global__ __launch_bounds__(256) void k_P(const float* f, const float* g,
                                           const float* rd, u16* P) {
  int j = blockIdx.x * 256 + threadIdx.x;
  int i0 = blockIdx.y * 16;
  int b = blockIdx.z;
  __shared__ float fl[16];
  if (threadIdx.x < 16) fl[threadIdx.x] = f[b * 2048 + i0 + threadIdx.x];
  __syncthreads();
  float gj = g[b * 2048 + j], rj = rd[b * 2048 + j];
  u16* Pp = P + ((long)b * 2048 + i0) * 2048 + j;
#pragma unroll
  for (int ii = 0; ii < 16; ++ii) Pp[(long)ii * 2048] = f2b(qfun(fl[ii] + gj) * rj);
}

// lhs_t[b][t][n], rhs_t[b][n][t] from tc_s[bn][t][f] (bf16)
__global__ void k_temporal(const u16* tc, const float* u1u2, const float* U3g,
                           float* lhs_t, float* rhs_t) {
  __shared__ float uu[64], u3[64];
  int tid = threadIdx.x;
  if (tid < 64) { uu[tid] = u1u2[tid]; u3[tid] = U3g[tid]; }
  __syncthreads();
  int gid = blockIdx.x * 256 + tid;  // < 196608
  const u16* p = tc + (long)gid * 64;
  float s1 = 0, s2 = 0;
#pragma unroll
  for (int c = 0; c < 8; ++c) {
    u16x8 vv = *(const u16x8*)(p + c * 8);
#pragma unroll
    for (int j = 0; j < 8; ++j) {
      float v = b2f(vv[j]);
      s1 += v * uu[c * 8 + j]; s2 += v * u3[c * 8 + j];
    }
  }
  int t = gid % 12; long bn = gid / 12;
  int b = (int)(bn >> 11);
  lhs_t[((long)b * 12 + t) * 2048 + (int)(bn & 2047)] = s1;
  rhs_t[gid] = s2;
}

__global__ void k_prod(const float* lhs_t, const float* rhs_t, float* prod) {
  int bi = blockIdx.x;  // < 1152
  int b = bi / 144; int r = bi % 144; int s = r / 12; int u = r % 12;
  int tid = threadIdx.x;
  float acc = 0;
  const float* lp = lhs_t + ((long)b * 12 + s) * 2048;
  const float* rp = rhs_t + (long)b * 2048 * 12 + u;
  for (int n = tid; n < 2048; n += 256) acc += lp[n] * rp[n * 12];
  __shared__ float red[256];
  red[tid] = acc; __syncthreads();
  for (int st = 128; st > 0; st >>= 1) {
    if (tid < st) red[tid] += red[tid + st];
    __syncthreads();
  }
  if (tid == 0) prod[bi] = red[0];
}

__global__ void k_E(const float* prod, const float* be, const float* Ve, float* E) {
  int b = blockIdx.x; int tid = threadIdx.x;
  __shared__ float S0[144], E1[144], mx[12], dn[12];
  if (tid < 144) {
    float v = prod[b * 144 + tid] + be[tid];
    S0[tid] = 1.f / (1.f + __expf(-v));
  }
  __syncthreads();
  if (tid < 144) {
    int i = tid / 12, t = tid % 12;
    float a = 0;
    for (int s = 0; s < 12; ++s) a += Ve[i * 12 + s] * S0[s * 12 + t];
    E1[tid] = a;
  }
  __syncthreads();
  if (tid < 12) {
    float m = -1e30f;
    for (int i = 0; i < 12; ++i) m = fmaxf(m, E1[i * 12 + tid]);
    float d = 0;
    for (int i = 0; i < 12; ++i) d += __expf(E1[i * 12 + tid] - m);
    mx[tid] = m; dn[tid] = d;
  }
  __syncthreads();
  if (tid < 144) {
    int t = tid % 12;
    E[b * 144 + tid] = __expf(E1[tid] - mx[t]) / dn[t];
  }
}

// tcn + residual + relu + layernorm(channel) -> resultB in A-FRAG layout.
__global__ __launch_bounds__(256) void k_res_ln(const u16* tc, const float* E,
                                                const float* xg, const float* res_w,
                                                const float* res_b, const float* ln_g,
                                                const float* ln_b, u16* result) {
  int bn = blockIdx.x; int b = bn >> 11;
  int tid = threadIdx.x;
  __shared__ float tcb[768], Eb[144], xl[36], rw[192], rb[64], lg[64], lb[64], zl[768], mu[12], rs[12];
  for (int s = tid; s < 768; s += 256) tcb[s] = b2f(tc[(long)bn * 768 + s]);
  if (tid < 144) Eb[tid] = E[b * 144 + tid];
  if (tid < 36) xl[tid] = xg[(long)bn * 36 + tid];
  if (tid >= 64 && tid < 256) { int q = tid - 64; if (q < 192) rw[q] = res_w[q]; }
  if (tid < 64) { rb[tid] = res_b[tid]; lg[tid] = ln_g[tid]; lb[tid] = ln_b[tid]; }
  __syncthreads();
  float z[3];
#pragma unroll
  for (int q = 0; q < 3; ++q) {
    int idx = tid + q * 256; int f = idx / 12, s = idx % 12;
    float tcn = 0;
#pragma unroll
    for (int t = 0; t < 12; ++t) tcn += tcb[t * 64 + f] * Eb[t * 12 + s];
    float xr = rb[f];
#pragma unroll
    for (int i = 0; i < 3; ++i) xr += rw[f * 3 + i] * xl[i * 12 + s];
    float v = xr + tcn;
    v = v > 0.f ? v : 0.f;
    z[q] = v; zl[idx] = v;
  }
  __syncthreads();
  if (tid < 12) {
    float m = 0, m2 = 0;
    for (int f = 0; f < 64; ++f) { float v = zl[f * 12 + tid]; m += v; m2 += v * v; }
    m *= (1.f / 64.f); m2 *= (1.f / 64.f);
    mu[tid] = m;
    float var = m2 - m * m;
    rs[tid] = rsqrtf((var > 0.f ? var : 0.f) + 1e-5f);
  }
  __syncthreads();
  const int mf = bn >> 4, m = bn & 15;
#pragma unroll
  for (int q = 0; q < 3; ++q) {
    int idx = tid + q * 256; int f = idx / 12, s = idx % 12;
    int kt = idx >> 5, koct = (idx >> 3) & 3, j = idx & 7;
    result[((long)mf * 24 + kt) * 512 + (m + 16 * koct) * 8 + j] =
        f2b((z[q] - mu[s]) * rs[s] * lg[f] + lb[f]);
  }
}

__global__ void k_sentinel(float* out, long n) {
  long i = (long)blockIdx.x * 256 + threadIdx.x;
  if (i < n) out[i] = 12345.0f;
}

// ---------------------------------------------------------------------------
// Launcher
// ---------------------------------------------------------------------------
extern "C" void kernel_launch(void* const* d_in, const int* in_sizes, int n_in,
                              void* d_out, int out_size, void* d_ws, size_t ws_size,
                              hipStream_t stream) {
  (void)in_sizes; (void)n_in;
  const float* x       = (const float*)d_in[0];
  const float* cheb    = (const float*)d_in[1];
  const float* Gamma   = (const float*)d_in[2];
  const float* W_heads = (const float*)d_in[3];
  const float* a_heads = (const float*)d_in[4];
  const float* W_out   = (const float*)d_in[5];
  const float* a_out   = (const float*)d_in[6];
  const float* U1      = (const float*)d_in[7];
  const float* U2      = (const float*)d_in[8];
  const float* U3      = (const float*)d_in[9];
  const float* be      = (const float*)d_in[10];
  const float* Ve      = (const float*)d_in[11];
  const float* time_w  = (const float*)d_in[12];
  const float* time_b  = (const float*)d_in[13];
  const float* res_w   = (const float*)d_in[14];
  const float* res_b   = (const float*)d_in[15];
  const float* back_w  = (const float*)d_in[16];
  const float* back_b  = (const float*)d_in[17];
  const float* fore_w  = (const float*)d_in[18];
  const float* fore_b  = (const float*)d_in[19];
  const float* ln_g    = (const float*)d_in[20];
  const float* ln_b    = (const float*)d_in[21];
  float* out = (float*)d_out;

  if (ws_size < WS_NEEDED) {  // distinctive failure signature (absmax ~12345)
    k_sentinel<<<(out_size + 255) / 256, 256, 0, stream>>>(out, out_size);
    return;
  }

  char* ws = (char*)d_ws;
  float* lhs     = (float*)(ws + OFF_LHS);
  float* u1u2    = (float*)(ws + OFF_U1U2);
  float* biasBig = (float*)(ws + OFF_BIASBIG);
  float* fH      = (float*)(ws + OFF_FH);
  float* gH      = (float*)(ws + OFF_GH);
  float* rdH     = (float*)(ws + OFF_RDH);
  float* fO      = (float*)(ws + OFF_FO);
  float* gO      = (float*)(ws + OFF_GO);
  float* rdO     = (float*)(ws + OFF_RDO);
  float* lhs_t   = (float*)(ws + OFF_LHST);
  float* rhs_t   = (float*)(ws + OFF_RHST);
  float* prod    = (float*)(ws + OFF_PROD);
  float* Ebuf    = (float*)(ws + OFF_E);
  u16* WcatT   = (u16*)(ws + OFF_WCATT);
  u16* WoutT   = (u16*)(ws + OFF_WOUTT);
  u16* WtBig   = (u16*)(ws + OFF_WTBIG);
  u16* WbfBig  = (u16*)(ws + OFF_WBFBIG);
  u16* xcolT   = (u16*)(ws + OFF_XCOLT);
  u16* chebT   = (u16*)(ws + OFF_CHEBT);
  u16* C1      = (u16*)(ws + OFF_C1);
  u16* hbuf    = (u16*)(ws + OFF_H);
  u16* Pbuf    = (u16*)(ws + OFF_P);
  u16* WhcatT  = (u16*)(ws + OFF_WHCATT);
  u16* hcat    = (u16*)(ws + OFF_HCAT);
  u16* WhoutT  = (u16*)(ws + OFF_WHOUTT);
  u16* gcnB    = (u16*)(ws + OFF_GCNB);
  u16* tcsB    = (u16*)(ws + OFF_TCS);
  u16* resultB = (u16*)(ws + OFF_RESULTB);

  // --- prep ---
  k_prep<<<1, 64, 0, stream>>>(Gamma, U1, U2, back_b, fore_b, lhs, u1u2, biasBig);
  k_convert<<<2048, 256, 0, stream>>>(W_heads, W_out, time_w, back_w, fore_w, x,
                                      WcatT, WoutT, WtBig, WbfBig, xcolT);
  k_chebT<<<dim3(64, 64, 3), 256, 0, stream>>>(cheb, chebT);

  // --- G1: C1 partials (bf16) = chebT @ xcolT^T, split-K x4 (z=k*4+ch, K=512) ---
  {
    GemmP p{}; p.A = chebT; p.BT = xcolT; p.sA = 2048L * 2048; p.sB = 0;
    p.K = 512; p.lda = 2048; p.ldb = 2048; p.splitK = 1; p.swz = 1;
    p.Cb = C1; p.sCb = 2048L * 384; p.ldcb = 384;
    gemm_bf16<9, 1><<<dim3(3, 16, 12), 256, 0, stream>>>(p);
  }
  k_h<<<16384, 256, 0, stream>>>(C1, lhs, hbuf);

  // --- G2: Wh_cat (AFB barrier-free; LDS-transposed out) ---
  {
    GemmP p{}; p.A = hbuf; p.BT = WcatT; p.sA = 0; p.K = 768;
    p.CbT = WhcatT; p.ldcT = 2048; p.sCbT = 768L * 2048;
    gemm_afb<1><<<dim3(6, 128, 1), 256, 0, stream>>>(p);
  }
  // f,g per head
  k_fg<<<dim3(8, 8), 256, 0, stream>>>(WhcatT, 0, 384, a_heads, a_heads + 384, fH, gH);
  k_fg<<<dim3(8, 8), 256, 0, stream>>>(WhcatT, 384, 384, a_heads + 768, a_heads + 1152,
                                       fH + 16384, gH + 16384);
  // heads: denom, P, att GEMM (elu -> hcat half) — z-fold swizzle
  for (int hd = 0; hd < 2; ++hd) {
    const float* f = fH + hd * 16384; const float* g = gH + hd * 16384;
    float* rd = rdH + hd * 16384;
    k_denom<<<dim3(32, 8), 256, 0, stream>>>(f, g, rd);
    k_P<<<dim3(8, 128, 8), 256, 0, stream>>>(f, g, rd, Pbuf);
    GemmP p{}; p.A = Pbuf; p.BT = WhcatT + (long)hd * 384 * 2048;
    p.sA = 2048L * 2048; p.sB = 768L * 2048;
    p.K = 2048; p.lda = 2048; p.ldb = 2048; p.swz = 2;
    p.Cb = hcat + hd * 384; p.sCb = 2048L * 768; p.ldcb = 768;
    gemm_bf16<2, 1><<<dim3(3, 16, 8), 256, 0, stream>>>(p);
  }

  // --- G5: Wh_out (LDS-transposed out) ---
  {
    GemmP p{}; p.A = hcat; p.BT = WoutT; p.sA = 0; p.sB = 0;
    p.K = 768; p.lda = 768; p.ldb = 768; p.swz = 1;
    p.CbT = WhoutT; p.ldcT = 2048; p.sCbT = 768L * 2048;
    gemm_bf16<1, 2><<<dim3(3, 128, 1), 256, 0, stream>>>(p);
  }
  k_fg<<<dim3(8, 8), 256, 0, stream>>>(WhoutT, 0, 768, a_out, a_out + 768, fO, gO);
  k_denom<<<dim3(32, 8), 256, 0, stream>>>(fO, gO, rdO);
  k_P<<<dim3(8, 128, 8), 256, 0, stream>>>(fO, gO, rdO, Pbuf);
  // --- G6: out attention (z-fold), relu -> gcnB bf16 ---
  {
    GemmP p{}; p.A = Pbuf; p.BT = WhoutT; p.sA = 2048L * 2048; p.sB = 768L * 2048;
    p.K = 2048; p.lda = 2048; p.ldb = 2048; p.swz = 2;
    p.Cb = gcnB; p.sCb = 2048L * 768; p.ldcb = 768;
    gemm_bf16<8, 2><<<dim3(3, 16, 8), 256, 0, stream>>>(p);
  }

  // --- temporal conv as dense GEMM (tap-expanded weights) -> tcsB bf16 ---
  {
    GemmP p{}; p.A = gcnB; p.BT = WtBig; p.sA = 0; p.sB = 0;
    p.K = 768; p.lda = 768; p.ldb = 768; p.swz = 1;
    p.Cb = tcsB; p.bias = time_b;
    gemm_bf16<6, 2><<<dim3(3, 128, 1), 256, 0, stream>>>(p);
  }

  // --- temporal attention ---
  k_temporal<<<768, 256, 0, stream>>>(tcsB, u1u2, U3, lhs_t, rhs_t);
  k_prod<<<1152, 256, 0, stream>>>(lhs_t, rhs_t, prod);
  k_E<<<8, 256, 0, stream>>>(prod, be, Ve, Ebuf);

  // --- residual + LN -> resultB fragments (same per-row structure) ---
  k_res_ln<<<16384, 256, 0, stream>>>(tcsB, Ebuf, x, res_w, res_b, ln_g, ln_b, resultB);

  // --- backcast / forecast convs: AFB barrier-free GEMM, vectorized writes ---
  {
    GemmP p{}; p.A = resultB; p.BT = WbfBig; p.sA = 0; p.K = 768;
    p.bias = biasBig; p.outB = out; p.outF = out + 12582912L;
    gemm_afb<7><<<dim3(12, 128, 1), 256, 0, stream>>>(p);
  }
}